// Round 1
// baseline (1843.024 us; speedup 1.0000x reference)
//
#include <hip/hip_runtime.h>
#include <hip/hip_bf16.h>

// Problem constants (verified against in_sizes at launch where cheap)
#define NN 50000
#define EE 400000
#define F_IN 128
#define HH 8
#define CC 64
#define HC 512
#define GG 64
#define NCLS 10
#define NEG_SLOPE 0.2f
#define EPS_ 1e-16f

// ---------------------------------------------------------------------------
// CSR build: histogram of dst, prefix scan, scatter edge ids
// ---------------------------------------------------------------------------
__global__ void hist_kernel(const int* __restrict__ ei, int* __restrict__ counts,
                            int E_, int EP_) {
    int e = blockIdx.x * 256 + threadIdx.x;
    if (e >= EP_) return;
    int d = (e < E_) ? ei[E_ + e] : (e - E_);   // self-loop edges e>=E: dst = e-E
    atomicAdd(&counts[d], 1);
}

__global__ void scan_kernel(const int* __restrict__ counts, int* __restrict__ row_start, int n) {
    __shared__ int buf[1024];
    int tid = threadIdx.x;
    int carry = 0;
    for (int base = 0; base < n; base += 1024) {
        int idx = base + tid;
        int v = (idx < n) ? counts[idx] : 0;
        buf[tid] = v;
        __syncthreads();
        for (int off = 1; off < 1024; off <<= 1) {
            int t = (tid >= off) ? buf[tid - off] : 0;
            __syncthreads();
            buf[tid] += t;
            __syncthreads();
        }
        int incl = buf[tid];
        int total = buf[1023];
        if (idx < n) row_start[idx + 1] = carry + incl;
        carry += total;
        __syncthreads();
    }
    if (tid == 0) row_start[0] = 0;
}

__global__ void scatter_kernel(const int* __restrict__ ei, const int* __restrict__ row_start,
                               int* __restrict__ cursor, int* __restrict__ perm,
                               int E_, int EP_) {
    int e = blockIdx.x * 256 + threadIdx.x;
    if (e >= EP_) return;
    int d = (e < E_) ? ei[E_ + e] : (e - E_);
    int pos = row_start[d] + atomicAdd(&cursor[d], 1);
    perm[pos] = e;
}

// ---------------------------------------------------------------------------
// fp32 tiled GEMM: C[M,Nc] = A[M,K] @ B[K,Nc], row-major. BM=BN=64, BK=16.
// 256 threads, 4x4 per thread.
// ---------------------------------------------------------------------------
__global__ __launch_bounds__(256) void gemm64(const float* __restrict__ A,
                                              const float* __restrict__ B,
                                              float* __restrict__ C,
                                              int M, int K, int Nc) {
    __shared__ float As[16][68];   // transposed: As[k][m], padded for alignment
    __shared__ float Bs[16][68];
    const int tid = threadIdx.x;
    const int tx = tid & 15;       // 0..15 -> output cols tx*4..+3
    const int ty = tid >> 4;       // 0..15 -> output rows ty*4..+3
    const int brow = blockIdx.y * 64;
    const int bcol = blockIdx.x * 64;
    float acc[4][4] = {};

    for (int k0 = 0; k0 < K; k0 += 16) {
        // A tile: 64 rows x 16 cols; thread loads float4
        int ar = tid >> 2;             // 0..63
        int ac = (tid & 3) * 4;        // 0,4,8,12
        float4 av = make_float4(0.f, 0.f, 0.f, 0.f);
        if (brow + ar < M)
            av = *reinterpret_cast<const float4*>(A + (size_t)(brow + ar) * K + k0 + ac);
        As[ac + 0][ar] = av.x; As[ac + 1][ar] = av.y;
        As[ac + 2][ar] = av.z; As[ac + 3][ar] = av.w;
        // B tile: 16 rows x 64 cols
        int br = tid >> 4;             // 0..15
        int bc = (tid & 15) * 4;
        float4 bv = *reinterpret_cast<const float4*>(B + (size_t)(k0 + br) * Nc + bcol + bc);
        Bs[br][bc + 0] = bv.x; Bs[br][bc + 1] = bv.y;
        Bs[br][bc + 2] = bv.z; Bs[br][bc + 3] = bv.w;
        __syncthreads();
#pragma unroll
        for (int kk = 0; kk < 16; ++kk) {
            float a_[4], b_[4];
#pragma unroll
            for (int i = 0; i < 4; ++i) a_[i] = As[kk][ty * 4 + i];
#pragma unroll
            for (int j = 0; j < 4; ++j) b_[j] = Bs[kk][tx * 4 + j];
#pragma unroll
            for (int i = 0; i < 4; ++i)
#pragma unroll
                for (int j = 0; j < 4; ++j)
                    acc[i][j] += a_[i] * b_[j];
        }
        __syncthreads();
    }
#pragma unroll
    for (int i = 0; i < 4; ++i) {
        int r = brow + ty * 4 + i;
        if (r < M) {
#pragma unroll
            for (int j = 0; j < 4; ++j)
                C[(size_t)r * Nc + bcol + tx * 4 + j] = acc[i][j];
        }
    }
}

// ---------------------------------------------------------------------------
// Attention coefficients: a_src[n,h] = sum_c h[n,h,c]*att_src[h,c]; same for dst
// One wave per node.
// ---------------------------------------------------------------------------
__global__ __launch_bounds__(256) void attn_coef(const float* __restrict__ h,
                                                 const float* __restrict__ as,
                                                 const float* __restrict__ ad,
                                                 float* __restrict__ a_src,
                                                 float* __restrict__ a_dst, int n) {
    int node = blockIdx.x * 4 + (threadIdx.x >> 6);
    int lane = threadIdx.x & 63;
    if (node >= n) return;
    const float* hp = h + (size_t)node * HC;
    float ps[8], pd[8];
#pragma unroll
    for (int k = 0; k < 8; ++k) {
        float hv = hp[k * 64 + lane];
        ps[k] = hv * as[k * 64 + lane];
        pd[k] = hv * ad[k * 64 + lane];
    }
#pragma unroll
    for (int off = 1; off < 64; off <<= 1) {
#pragma unroll
        for (int k = 0; k < 8; ++k) {
            ps[k] += __shfl_xor(ps[k], off);
            pd[k] += __shfl_xor(pd[k], off);
        }
    }
    if (lane < 8) {
        float vs = ps[0], vd = pd[0];
#pragma unroll
        for (int k = 1; k < 8; ++k) {
            if (lane == k) { vs = ps[k]; vd = pd[k]; }
        }
        a_src[node * 8 + lane] = vs;
        a_dst[node * 8 + lane] = vd;
    }
}

// ---------------------------------------------------------------------------
// Aggregation: per destination node, segment softmax over its incoming edges
// then weighted sum of h[src]. One wave per node; lane = channel c.
// MODE 0: concat (out[N,512] = relu(acc + bias512))
// MODE 1: mean over heads (out[N,64] = relu(mean_h + bias64))
// ---------------------------------------------------------------------------
template <int MODE>
__global__ __launch_bounds__(256) void agg_kernel(const float* __restrict__ h,
                                                  const float* __restrict__ a_src,
                                                  const float* __restrict__ a_dst,
                                                  const float* __restrict__ bias,
                                                  const int* __restrict__ ei,
                                                  const int* __restrict__ row_start,
                                                  const int* __restrict__ perm,
                                                  float* __restrict__ out,
                                                  int n, int E_) {
    int d = blockIdx.x * 4 + (threadIdx.x >> 6);
    int lane = threadIdx.x & 63;
    if (d >= n) return;
    int base = row_start[d];
    int end = row_start[d + 1];
    int head = lane & 7;
    int eslot = lane >> 3;
    float adh = a_dst[d * 8 + head];

    // per-head max over edges (8 edge-slots x 8 heads across the wave)
    float mx = -1e30f;
    for (int i = base + eslot; i < end; i += 8) {
        int e = perm[i];
        int s = (e < E_) ? ei[e] : (e - E_);
        float al = a_src[s * 8 + head] + adh;
        al = (al > 0.f) ? al : NEG_SLOPE * al;
        mx = fmaxf(mx, al);
    }
    mx = fmaxf(mx, __shfl_xor(mx, 8));
    mx = fmaxf(mx, __shfl_xor(mx, 16));
    mx = fmaxf(mx, __shfl_xor(mx, 32));

    float sm = 0.f;
    for (int i = base + eslot; i < end; i += 8) {
        int e = perm[i];
        int s = (e < E_) ? ei[e] : (e - E_);
        float al = a_src[s * 8 + head] + adh;
        al = (al > 0.f) ? al : NEG_SLOPE * al;
        sm += expf(al - mx);
    }
    sm += __shfl_xor(sm, 8);
    sm += __shfl_xor(sm, 16);
    sm += __shfl_xor(sm, 32);
    float inv = 1.0f / (sm + EPS_);   // lane k<8 holds head k's mx/inv

    float acc[8] = {};
    for (int i = base; i < end; ++i) {
        int e = perm[i];
        int s = (e < E_) ? ei[e] : (e - E_);
        float w = 0.f;
        if (lane < 8) {
            float al = a_src[s * 8 + lane] + a_dst[d * 8 + lane];
            al = (al > 0.f) ? al : NEG_SLOPE * al;
            w = expf(al - mx) * inv;
        }
        const float* hs = h + (size_t)s * HC;
#pragma unroll
        for (int k = 0; k < 8; ++k)
            acc[k] += __shfl(w, k) * hs[k * 64 + lane];
    }

    if (MODE == 0) {
        float* op = out + (size_t)d * HC;
#pragma unroll
        for (int k = 0; k < 8; ++k) {
            float v = acc[k] + bias[k * 64 + lane];
            op[k * 64 + lane] = fmaxf(v, 0.f);
        }
    } else {
        float s8 = 0.f;
#pragma unroll
        for (int k = 0; k < 8; ++k) s8 += acc[k];
        float v = s8 * 0.125f + bias[lane];
        out[(size_t)d * 64 + lane] = fmaxf(v, 0.f);
    }
}

// ---------------------------------------------------------------------------
// Global mean pool (atomics) + classifier
// ---------------------------------------------------------------------------
__global__ __launch_bounds__(256) void pool_kernel(const float* __restrict__ h3,
                                                   const int* __restrict__ batch,
                                                   float* __restrict__ pooled,
                                                   int* __restrict__ cnt, int n) {
    int d = blockIdx.x * 4 + (threadIdx.x >> 6);
    int lane = threadIdx.x & 63;
    if (d >= n) return;
    int g = batch[d];
    atomicAdd(&pooled[g * 64 + lane], h3[(size_t)d * 64 + lane]);
    if (lane == 0) atomicAdd(&cnt[g], 1);
}

__global__ void classify_kernel(const float* __restrict__ pooled,
                                const int* __restrict__ cnt,
                                const float* __restrict__ fcw,
                                const float* __restrict__ fcb,
                                float* __restrict__ out) {
    int g = blockIdx.x;
    int lane = threadIdx.x & 63;
    float c = (float)cnt[g];
    c = fmaxf(c, 1.0f);
    float p = pooled[g * 64 + lane] / c;
    float logit[NCLS];
#pragma unroll
    for (int j = 0; j < NCLS; ++j) {
        float t = p * fcw[lane * NCLS + j];
#pragma unroll
        for (int off = 1; off < 64; off <<= 1) t += __shfl_xor(t, off);
        logit[j] = t + fcb[j];
    }
    float m = logit[0];
#pragma unroll
    for (int j = 1; j < NCLS; ++j) m = fmaxf(m, logit[j]);
    float s = 0.f;
#pragma unroll
    for (int j = 0; j < NCLS; ++j) s += expf(logit[j] - m);
    float lse = logf(s);
    if (lane < NCLS) {
        float v = logit[0];
#pragma unroll
        for (int j = 1; j < NCLS; ++j)
            if (lane == j) v = logit[j];
        out[g * NCLS + lane] = v - m - lse;
    }
}

// ---------------------------------------------------------------------------
extern "C" void kernel_launch(void* const* d_in, const int* in_sizes, int n_in,
                              void* d_out, int out_size, void* d_ws, size_t ws_size,
                              hipStream_t stream) {
    const float* x   = (const float*)d_in[0];
    const int*   ei  = (const int*)d_in[1];
    const int*   batch = (const int*)d_in[2];
    const float* W1  = (const float*)d_in[3];
    const float* a1s = (const float*)d_in[4];
    const float* a1d = (const float*)d_in[5];
    const float* b1  = (const float*)d_in[6];
    const float* W2  = (const float*)d_in[7];
    const float* a2s = (const float*)d_in[8];
    const float* a2d = (const float*)d_in[9];
    const float* b2  = (const float*)d_in[10];
    const float* W3  = (const float*)d_in[11];
    const float* a3s = (const float*)d_in[12];
    const float* a3d = (const float*)d_in[13];
    const float* b3  = (const float*)d_in[14];
    const float* fcw = (const float*)d_in[15];
    const float* fcb = (const float*)d_in[16];

    const int n  = in_sizes[0] / F_IN;       // 50000
    const int E_ = in_sizes[1] / 2;          // 400000
    const int EP = E_ + n;                   // 450000 (with self loops)

    // workspace carve-up
    float* hbuf   = (float*)d_ws;                      // n*512
    float* buf2   = hbuf + (size_t)n * HC;             // n*512
    float* asrc   = buf2 + (size_t)n * HC;             // n*8
    float* adst   = asrc + (size_t)n * 8;              // n*8
    float* h3     = adst + (size_t)n * 8;              // n*64
    float* pooled = h3 + (size_t)n * 64;               // G*64
    int*   cnt    = (int*)(pooled + GG * 64);          // G
    int*   counts = cnt + GG;                          // n
    int*   row_start = counts + n;                     // n+1
    int*   perm   = row_start + n + 1;                 // EP

    const int edge_blocks = (EP + 255) / 256;
    const int node_blocks = (n + 3) / 4;

    // ---- CSR build ----
    hipMemsetAsync(counts, 0, (size_t)n * sizeof(int), stream);
    hist_kernel<<<edge_blocks, 256, 0, stream>>>(ei, counts, E_, EP);
    scan_kernel<<<1, 1024, 0, stream>>>(counts, row_start, n);
    hipMemsetAsync(counts, 0, (size_t)n * sizeof(int), stream);
    scatter_kernel<<<edge_blocks, 256, 0, stream>>>(ei, row_start, counts, perm, E_, EP);

    dim3 gemm_grid(HC / 64, (n + 63) / 64);

    // ---- Layer 1 ----
    gemm64<<<gemm_grid, 256, 0, stream>>>(x, W1, hbuf, n, F_IN, HC);
    attn_coef<<<node_blocks, 256, 0, stream>>>(hbuf, a1s, a1d, asrc, adst, n);
    agg_kernel<0><<<node_blocks, 256, 0, stream>>>(hbuf, asrc, adst, b1, ei, row_start, perm, buf2, n, E_);

    // ---- Layer 2 ----
    gemm64<<<gemm_grid, 256, 0, stream>>>(buf2, W2, hbuf, n, HC, HC);
    attn_coef<<<node_blocks, 256, 0, stream>>>(hbuf, a2s, a2d, asrc, adst, n);
    agg_kernel<0><<<node_blocks, 256, 0, stream>>>(hbuf, asrc, adst, b2, ei, row_start, perm, buf2, n, E_);

    // ---- Layer 3 (mean over heads) ----
    gemm64<<<gemm_grid, 256, 0, stream>>>(buf2, W3, hbuf, n, HC, HC);
    attn_coef<<<node_blocks, 256, 0, stream>>>(hbuf, a3s, a3d, asrc, adst, n);
    agg_kernel<1><<<node_blocks, 256, 0, stream>>>(hbuf, asrc, adst, b3, ei, row_start, perm, h3, n, E_);

    // ---- Pool + classify ----
    hipMemsetAsync(pooled, 0, (size_t)(GG * 64) * sizeof(float) + GG * sizeof(int), stream);
    pool_kernel<<<node_blocks, 256, 0, stream>>>(h3, batch, pooled, cnt, n);
    classify_kernel<<<GG, 64, 0, stream>>>(pooled, cnt, fcw, fcb, (float*)d_out);
}

// Round 2
// 1037.289 us; speedup vs baseline: 1.7768x; 1.7768x over previous
//
#include <hip/hip_runtime.h>
#include <hip/hip_bf16.h>

#define HH 8
#define CC 64
#define HC 512
#define GG 64
#define NCLS 10
#define F_IN 128
#define NEG_SLOPE 0.2f
#define EPS_ 1e-16f

typedef float f32x4 __attribute__((ext_vector_type(4)));
typedef __bf16 bf16x8 __attribute__((ext_vector_type(8)));

__device__ __forceinline__ unsigned short f2bf(float f) {
    unsigned u = __builtin_bit_cast(unsigned, f);
    u += 0x7fffu + ((u >> 16) & 1u);          // RNE
    return (unsigned short)(u >> 16);
}
__device__ __forceinline__ float bf2f(unsigned short s) {
    unsigned u = ((unsigned)s) << 16;
    return __builtin_bit_cast(float, u);
}

// async global->LDS, 16B per lane. lds ptr must be wave-uniform base.
__device__ __forceinline__ void gload16(const unsigned short* g, unsigned short* l) {
    __builtin_amdgcn_global_load_lds(
        (const __attribute__((address_space(1))) unsigned int*)g,
        (__attribute__((address_space(3))) unsigned int*)l,
        16, 0, 0);
}

// ---------------------------------------------------------------------------
// CSR build
// ---------------------------------------------------------------------------
__global__ void hist_kernel(const int* __restrict__ ei, int* __restrict__ counts,
                            int E_, int EP_) {
    int e = blockIdx.x * 256 + threadIdx.x;
    if (e >= EP_) return;
    int d = (e < E_) ? ei[E_ + e] : (e - E_);
    atomicAdd(&counts[d], 1);
}

__global__ void scan1(const int* __restrict__ counts, int* __restrict__ partial,
                      int* __restrict__ bsum, int n) {
    __shared__ int buf[256];
    int idx = blockIdx.x * 256 + threadIdx.x;
    int v = (idx < n) ? counts[idx] : 0;
    buf[threadIdx.x] = v;
    __syncthreads();
    for (int off = 1; off < 256; off <<= 1) {
        int t = (threadIdx.x >= off) ? buf[threadIdx.x - off] : 0;
        __syncthreads();
        buf[threadIdx.x] += t;
        __syncthreads();
    }
    if (idx < n) partial[idx] = buf[threadIdx.x];
    if (threadIdx.x == 255) bsum[blockIdx.x] = buf[255];
}

__global__ void scan2(int* __restrict__ bsum, int nb) {
    __shared__ int buf[1024];
    int t = threadIdx.x;
    buf[t] = (t < nb) ? bsum[t] : 0;
    __syncthreads();
    for (int off = 1; off < 1024; off <<= 1) {
        int v = (t >= off) ? buf[t - off] : 0;
        __syncthreads();
        buf[t] += v;
        __syncthreads();
    }
    if (t < nb) bsum[t] = buf[t];
}

__global__ void scan3(const int* __restrict__ partial, const int* __restrict__ bsum,
                      int* __restrict__ row_start, int n) {
    int idx = blockIdx.x * 256 + threadIdx.x;
    if (idx >= n) return;
    int add = (blockIdx.x > 0) ? bsum[blockIdx.x - 1] : 0;
    row_start[idx + 1] = partial[idx] + add;
    if (idx == 0) row_start[0] = 0;
}

__global__ void scatter_kernel(const int* __restrict__ ei, const int* __restrict__ row_start,
                               int* __restrict__ cursor, int* __restrict__ perm,
                               int E_, int EP_) {
    int e = blockIdx.x * 256 + threadIdx.x;
    if (e >= EP_) return;
    int d = (e < E_) ? ei[E_ + e] : (e - E_);
    int pos = row_start[d] + atomicAdd(&cursor[d], 1);
    perm[pos] = e;
}

__global__ void build_src(const int* __restrict__ ei, const int* __restrict__ perm,
                          int* __restrict__ src_sorted, int E_, int EP_) {
    int i = blockIdx.x * 256 + threadIdx.x;
    if (i >= EP_) return;
    int e = perm[i];
    src_sorted[i] = (e < E_) ? ei[e] : (e - E_);
}

// ---------------------------------------------------------------------------
// fp32 -> bf16 conversions
// ---------------------------------------------------------------------------
__global__ void conv_bf16(const float* __restrict__ in, unsigned short* __restrict__ out,
                          int n4) {
    int i = blockIdx.x * 256 + threadIdx.x;
    if (i >= n4) return;
    float4 v = reinterpret_cast<const float4*>(in)[i];
    reinterpret_cast<ushort4*>(out)[i] =
        make_ushort4(f2bf(v.x), f2bf(v.y), f2bf(v.z), f2bf(v.w));
}

// W [K][Nc] fp32 -> WT [Nc][K] bf16
__global__ void transpose_w(const float* __restrict__ W, unsigned short* __restrict__ WT,
                            int K, int Nc) {
    __shared__ float t[32][33];
    int bx = blockIdx.x * 32;   // n
    int by = blockIdx.y * 32;   // k
    int x = threadIdx.x, y = threadIdx.y;
    for (int i = y; i < 32; i += 8)
        t[i][x] = W[(size_t)(by + i) * Nc + bx + x];   // t[k_local][n_local]
    __syncthreads();
    for (int i = y; i < 32; i += 8)
        WT[(size_t)(bx + i) * K + by + x] = f2bf(t[x][i]);
}

// ---------------------------------------------------------------------------
// bf16 MFMA GEMM: C[M,Nc](bf16) = A[M,K](bf16) @ BT[Nc,K](bf16)^T
// BM=BN=128, BK=64, 256 threads = 4 waves (2x2), each wave 64x64 out.
// ---------------------------------------------------------------------------
__global__ __launch_bounds__(256) void gemm_bf16(const unsigned short* __restrict__ A,
                                                 const unsigned short* __restrict__ BT,
                                                 unsigned short* __restrict__ C,
                                                 int M, int K, int Nc) {
    __shared__ __align__(16) unsigned short As[128 * 64];  // [m][k], 16 KB
    __shared__ __align__(16) unsigned short Bs[128 * 64];  // [n][k], 16 KB
    const int tid = threadIdx.x;
    const int lane = tid & 63;
    const int wave = tid >> 6;
    const int wr = wave >> 1, wc = wave & 1;
    const int brow = blockIdx.y * 128;
    const int bcol = blockIdx.x * 128;

    f32x4 acc[4][4];
#pragma unroll
    for (int i = 0; i < 4; ++i)
#pragma unroll
        for (int j = 0; j < 4; ++j) acc[i][j] = (f32x4)0.f;

    const int lrow = lane >> 3;        // 0..7 (row within 8-row chunk)
    const int lcol = (lane & 7) * 8;   // k element offset (8 bf16 = 16B)
    const int arow0 = brow + wave * 32 + lrow;
    const int brow0 = bcol + wave * 32 + lrow;

    const int kb = (lane >> 4) * 8;
    const int rowa = wr * 64 + (lane & 15);
    const int rowb = wc * 64 + (lane & 15);

    for (int k0 = 0; k0 < K; k0 += 64) {
#pragma unroll
        for (int it = 0; it < 4; ++it) {
            const int c = wave * 4 + it;
            int ar = arow0 + it * 8;
            if (ar >= M) ar = M - 1;                       // clamp: rows >=M never stored
            gload16(A + (size_t)ar * K + k0 + lcol, &As[c * 512]);
            int br = brow0 + it * 8;
            gload16(BT + (size_t)br * K + k0 + lcol, &Bs[c * 512]);
        }
        __syncthreads();
#pragma unroll
        for (int kk = 0; kk < 64; kk += 32) {
            bf16x8 a[4], b[4];
#pragma unroll
            for (int m = 0; m < 4; ++m)
                a[m] = *(const bf16x8*)&As[(rowa + m * 16) * 64 + kk + kb];
#pragma unroll
            for (int nn = 0; nn < 4; ++nn)
                b[nn] = *(const bf16x8*)&Bs[(rowb + nn * 16) * 64 + kk + kb];
#pragma unroll
            for (int m = 0; m < 4; ++m)
#pragma unroll
                for (int nn = 0; nn < 4; ++nn)
                    acc[m][nn] = __builtin_amdgcn_mfma_f32_16x16x32_bf16(
                        a[m], b[nn], acc[m][nn], 0, 0, 0);
        }
        __syncthreads();
    }

    const int r0 = brow + wr * 64 + (lane >> 4) * 4;
    const int c0 = bcol + wc * 64 + (lane & 15);
#pragma unroll
    for (int m = 0; m < 4; ++m)
#pragma unroll
        for (int j = 0; j < 4; ++j) {
            int r = r0 + m * 16 + j;
            if (r < M) {
#pragma unroll
                for (int nn = 0; nn < 4; ++nn)
                    C[(size_t)r * Nc + c0 + nn * 16] = f2bf(acc[m][nn][j]);
            }
        }
}

// ---------------------------------------------------------------------------
// Attention coefficients from bf16 h
// ---------------------------------------------------------------------------
__global__ __launch_bounds__(256) void attn_coef(const unsigned short* __restrict__ h,
                                                 const float* __restrict__ as,
                                                 const float* __restrict__ ad,
                                                 float* __restrict__ a_src,
                                                 float* __restrict__ a_dst, int n) {
    int node = blockIdx.x * 4 + (threadIdx.x >> 6);
    int lane = threadIdx.x & 63;
    if (node >= n) return;
    const unsigned short* hp = h + (size_t)node * HC;
    float ps[8], pd[8];
#pragma unroll
    for (int k = 0; k < 8; ++k) {
        float hv = bf2f(hp[k * 64 + lane]);
        ps[k] = hv * as[k * 64 + lane];
        pd[k] = hv * ad[k * 64 + lane];
    }
#pragma unroll
    for (int off = 1; off < 64; off <<= 1) {
#pragma unroll
        for (int k = 0; k < 8; ++k) {
            ps[k] += __shfl_xor(ps[k], off);
            pd[k] += __shfl_xor(pd[k], off);
        }
    }
    if (lane < 8) {
        float vs = ps[0], vd = pd[0];
#pragma unroll
        for (int k = 1; k < 8; ++k) {
            if (lane == k) { vs = ps[k]; vd = pd[k]; }
        }
        a_src[node * 8 + lane] = vs;
        a_dst[node * 8 + lane] = vd;
    }
}

// ---------------------------------------------------------------------------
// Aggregation. h bf16; MODE 0: out bf16 [n][512] relu(acc+bias512)
//                      MODE 1: out fp32 [n][64]  relu(mean_h+bias64)
// ---------------------------------------------------------------------------
template <int MODE>
__global__ __launch_bounds__(256) void agg_kernel(const unsigned short* __restrict__ h,
                                                  const float* __restrict__ a_src,
                                                  const float* __restrict__ a_dst,
                                                  const float* __restrict__ bias,
                                                  const int* __restrict__ row_start,
                                                  const int* __restrict__ src_sorted,
                                                  void* __restrict__ outv, int n) {
    int d = blockIdx.x * 4 + (threadIdx.x >> 6);
    int lane = threadIdx.x & 63;
    if (d >= n) return;
    int base = row_start[d];
    int end = row_start[d + 1];
    int head = lane & 7;
    int eslot = lane >> 3;
    float adh = a_dst[d * 8 + head];

    float mx = -1e30f;
    for (int i = base + eslot; i < end; i += 8) {
        int s = src_sorted[i];
        float al = a_src[s * 8 + head] + adh;
        al = (al > 0.f) ? al : NEG_SLOPE * al;
        mx = fmaxf(mx, al);
    }
    mx = fmaxf(mx, __shfl_xor(mx, 8));
    mx = fmaxf(mx, __shfl_xor(mx, 16));
    mx = fmaxf(mx, __shfl_xor(mx, 32));

    float sm = 0.f;
    for (int i = base + eslot; i < end; i += 8) {
        int s = src_sorted[i];
        float al = a_src[s * 8 + head] + adh;
        al = (al > 0.f) ? al : NEG_SLOPE * al;
        sm += expf(al - mx);
    }
    sm += __shfl_xor(sm, 8);
    sm += __shfl_xor(sm, 16);
    sm += __shfl_xor(sm, 32);
    float inv = 1.0f / (sm + EPS_);     // lane k<8 holds head k's mx/inv

    float acc[8] = {};
    for (int i = base; i < end; ++i) {
        int s = src_sorted[i];
        float w = 0.f;
        if (lane < 8) {
            float al = a_src[s * 8 + lane] + a_dst[d * 8 + lane];
            al = (al > 0.f) ? al : NEG_SLOPE * al;
            w = expf(al - mx) * inv;
        }
        const unsigned short* hs = h + (size_t)s * HC;
#pragma unroll
        for (int k = 0; k < 8; ++k)
            acc[k] += __shfl(w, k) * bf2f(hs[k * 64 + lane]);
    }

    if (MODE == 0) {
        unsigned short* op = (unsigned short*)outv + (size_t)d * HC;
#pragma unroll
        for (int k = 0; k < 8; ++k) {
            float v = acc[k] + bias[k * 64 + lane];
            op[k * 64 + lane] = f2bf(fmaxf(v, 0.f));
        }
    } else {
        float s8 = 0.f;
#pragma unroll
        for (int k = 0; k < 8; ++k) s8 += acc[k];
        float v = s8 * 0.125f + bias[lane];
        ((float*)outv)[(size_t)d * 64 + lane] = fmaxf(v, 0.f);
    }
}

// ---------------------------------------------------------------------------
// Pool + classify
// ---------------------------------------------------------------------------
__global__ __launch_bounds__(256) void pool_kernel(const float* __restrict__ h3,
                                                   const int* __restrict__ batch,
                                                   float* __restrict__ pooled,
                                                   int* __restrict__ cnt, int n) {
    int d = blockIdx.x * 4 + (threadIdx.x >> 6);
    int lane = threadIdx.x & 63;
    if (d >= n) return;
    int g = batch[d];
    atomicAdd(&pooled[g * 64 + lane], h3[(size_t)d * 64 + lane]);
    if (lane == 0) atomicAdd(&cnt[g], 1);
}

__global__ void classify_kernel(const float* __restrict__ pooled,
                                const int* __restrict__ cnt,
                                const float* __restrict__ fcw,
                                const float* __restrict__ fcb,
                                float* __restrict__ out) {
    int g = blockIdx.x;
    int lane = threadIdx.x & 63;
    float c = (float)cnt[g];
    c = fmaxf(c, 1.0f);
    float p = pooled[g * 64 + lane] / c;
    float logit[NCLS];
#pragma unroll
    for (int j = 0; j < NCLS; ++j) {
        float t = p * fcw[lane * NCLS + j];
#pragma unroll
        for (int off = 1; off < 64; off <<= 1) t += __shfl_xor(t, off);
        logit[j] = t + fcb[j];
    }
    float m = logit[0];
#pragma unroll
    for (int j = 1; j < NCLS; ++j) m = fmaxf(m, logit[j]);
    float s = 0.f;
#pragma unroll
    for (int j = 0; j < NCLS; ++j) s += expf(logit[j] - m);
    float lse = logf(s);
    if (lane < NCLS) {
        float v = logit[0];
#pragma unroll
        for (int j = 1; j < NCLS; ++j)
            if (lane == j) v = logit[j];
        out[g * NCLS + lane] = v - m - lse;
    }
}

// ---------------------------------------------------------------------------
extern "C" void kernel_launch(void* const* d_in, const int* in_sizes, int n_in,
                              void* d_out, int out_size, void* d_ws, size_t ws_size,
                              hipStream_t stream) {
    const float* x    = (const float*)d_in[0];
    const int*   ei   = (const int*)d_in[1];
    const int*   batch = (const int*)d_in[2];
    const float* W1  = (const float*)d_in[3];
    const float* a1s = (const float*)d_in[4];
    const float* a1d = (const float*)d_in[5];
    const float* b1  = (const float*)d_in[6];
    const float* W2  = (const float*)d_in[7];
    const float* a2s = (const float*)d_in[8];
    const float* a2d = (const float*)d_in[9];
    const float* b2  = (const float*)d_in[10];
    const float* W3  = (const float*)d_in[11];
    const float* a3s = (const float*)d_in[12];
    const float* a3d = (const float*)d_in[13];
    const float* b3  = (const float*)d_in[14];
    const float* fcw = (const float*)d_in[15];
    const float* fcb = (const float*)d_in[16];

    const int n  = in_sizes[0] / F_IN;     // 50000
    const int E_ = in_sizes[1] / 2;        // 400000
    const int EP = E_ + n;                 // 450000

    // ---- workspace carve-up ----
    char* p = (char*)d_ws;
    unsigned short* xb   = (unsigned short*)p; p += (size_t)n * F_IN * 2;
    unsigned short* w1t  = (unsigned short*)p; p += (size_t)HC * F_IN * 2;
    unsigned short* w2t  = (unsigned short*)p; p += (size_t)HC * HC * 2;
    unsigned short* w3t  = (unsigned short*)p; p += (size_t)HC * HC * 2;
    unsigned short* hbuf = (unsigned short*)p; p += (size_t)n * HC * 2;
    unsigned short* buf2 = (unsigned short*)p; p += (size_t)n * HC * 2;
    float* asrc   = (float*)p; p += (size_t)n * 8 * 4;
    float* adst   = (float*)p; p += (size_t)n * 8 * 4;
    float* h3     = (float*)p; p += (size_t)n * 64 * 4;
    float* pooled = (float*)p; p += (size_t)GG * 64 * 4;
    int* cnt      = (int*)p;   p += (size_t)GG * 4;
    int* counts   = (int*)p;   p += (size_t)n * 4;
    int* row_start= (int*)p;   p += (size_t)(n + 1) * 4;
    int* perm     = (int*)p;   p += (size_t)EP * 4;
    int* src_sorted=(int*)p;   p += (size_t)EP * 4;
    int* partial  = (int*)p;   p += (size_t)n * 4;
    int* bsum     = (int*)p;   p += 1024 * 4;

    const int edge_blocks = (EP + 255) / 256;
    const int node_blocks = (n + 3) / 4;
    const int scan_blocks = (n + 255) / 256;

    // ---- CSR build ----
    hipMemsetAsync(counts, 0, (size_t)n * sizeof(int), stream);
    hist_kernel<<<edge_blocks, 256, 0, stream>>>(ei, counts, E_, EP);
    scan1<<<scan_blocks, 256, 0, stream>>>(counts, partial, bsum, n);
    scan2<<<1, 1024, 0, stream>>>(bsum, scan_blocks);
    scan3<<<scan_blocks, 256, 0, stream>>>(partial, bsum, row_start, n);
    hipMemsetAsync(counts, 0, (size_t)n * sizeof(int), stream);
    scatter_kernel<<<edge_blocks, 256, 0, stream>>>(ei, row_start, counts, perm, E_, EP);
    build_src<<<edge_blocks, 256, 0, stream>>>(ei, perm, src_sorted, E_, EP);

    // ---- conversions ----
    conv_bf16<<<((n * F_IN / 4) + 255) / 256, 256, 0, stream>>>(x, xb, n * F_IN / 4);
    transpose_w<<<dim3(HC / 32, F_IN / 32), dim3(32, 8), 0, stream>>>(W1, w1t, F_IN, HC);
    transpose_w<<<dim3(HC / 32, HC / 32), dim3(32, 8), 0, stream>>>(W2, w2t, HC, HC);
    transpose_w<<<dim3(HC / 32, HC / 32), dim3(32, 8), 0, stream>>>(W3, w3t, HC, HC);

    dim3 gemm_grid(HC / 128, (n + 127) / 128);

    // ---- Layer 1 ----
    gemm_bf16<<<gemm_grid, 256, 0, stream>>>(xb, w1t, hbuf, n, F_IN, HC);
    attn_coef<<<node_blocks, 256, 0, stream>>>(hbuf, a1s, a1d, asrc, adst, n);
    agg_kernel<0><<<node_blocks, 256, 0, stream>>>(hbuf, asrc, adst, b1, row_start, src_sorted, buf2, n);

    // ---- Layer 2 ----
    gemm_bf16<<<gemm_grid, 256, 0, stream>>>(buf2, w2t, hbuf, n, HC, HC);
    attn_coef<<<node_blocks, 256, 0, stream>>>(hbuf, a2s, a2d, asrc, adst, n);
    agg_kernel<0><<<node_blocks, 256, 0, stream>>>(hbuf, asrc, adst, b2, row_start, src_sorted, buf2, n);

    // ---- Layer 3 ----
    gemm_bf16<<<gemm_grid, 256, 0, stream>>>(buf2, w3t, hbuf, n, HC, HC);
    attn_coef<<<node_blocks, 256, 0, stream>>>(hbuf, a3s, a3d, asrc, adst, n);
    agg_kernel<1><<<node_blocks, 256, 0, stream>>>(hbuf, asrc, adst, b3, row_start, src_sorted, h3, n);

    // ---- Pool + classify ----
    hipMemsetAsync(pooled, 0, (size_t)(GG * 64) * sizeof(float) + GG * sizeof(int), stream);
    pool_kernel<<<node_blocks, 256, 0, stream>>>(h3, batch, pooled, cnt, n);
    classify_kernel<<<GG, 64, 0, stream>>>(pooled, cnt, fcw, fcb, (float*)d_out);
}

// Round 3
// 737.342 us; speedup vs baseline: 2.4996x; 1.4068x over previous
//
#include <hip/hip_runtime.h>
#include <hip/hip_bf16.h>

#define HH 8
#define CC 64
#define HC 512
#define GG 64
#define NCLS 10
#define F_IN 128
#define NEG_SLOPE 0.2f
#define EPS_ 1e-16f

typedef float f32x4 __attribute__((ext_vector_type(4)));
typedef __bf16 bf16x8 __attribute__((ext_vector_type(8)));

__device__ __forceinline__ unsigned short f2bf(float f) {
    unsigned u = __builtin_bit_cast(unsigned, f);
    u += 0x7fffu + ((u >> 16) & 1u);          // RNE
    return (unsigned short)(u >> 16);
}
__device__ __forceinline__ float bf2f(unsigned short s) {
    unsigned u = ((unsigned)s) << 16;
    return __builtin_bit_cast(float, u);
}

// async global->LDS, 16B per lane. lds ptr must be wave-uniform base.
__device__ __forceinline__ void gload16(const unsigned short* g, unsigned short* l) {
    __builtin_amdgcn_global_load_lds(
        (const __attribute__((address_space(1))) unsigned int*)g,
        (__attribute__((address_space(3))) unsigned int*)l,
        16, 0, 0);
}

// ---------------------------------------------------------------------------
// CSR build
// ---------------------------------------------------------------------------
__global__ void hist_kernel(const int* __restrict__ ei, int* __restrict__ counts,
                            int E_, int EP_) {
    int e = blockIdx.x * 256 + threadIdx.x;
    if (e >= EP_) return;
    int d = (e < E_) ? ei[E_ + e] : (e - E_);
    atomicAdd(&counts[d], 1);
}

__global__ void scan1(const int* __restrict__ counts, int* __restrict__ partial,
                      int* __restrict__ bsum, int n) {
    __shared__ int buf[256];
    int idx = blockIdx.x * 256 + threadIdx.x;
    int v = (idx < n) ? counts[idx] : 0;
    buf[threadIdx.x] = v;
    __syncthreads();
    for (int off = 1; off < 256; off <<= 1) {
        int t = (threadIdx.x >= off) ? buf[threadIdx.x - off] : 0;
        __syncthreads();
        buf[threadIdx.x] += t;
        __syncthreads();
    }
    if (idx < n) partial[idx] = buf[threadIdx.x];
    if (threadIdx.x == 255) bsum[blockIdx.x] = buf[255];
}

__global__ void scan2(int* __restrict__ bsum, int nb) {
    __shared__ int buf[1024];
    int t = threadIdx.x;
    buf[t] = (t < nb) ? bsum[t] : 0;
    __syncthreads();
    for (int off = 1; off < 1024; off <<= 1) {
        int v = (t >= off) ? buf[t - off] : 0;
        __syncthreads();
        buf[t] += v;
        __syncthreads();
    }
    if (t < nb) bsum[t] = buf[t];
}

__global__ void scan3(const int* __restrict__ partial, const int* __restrict__ bsum,
                      int* __restrict__ row_start, int n) {
    int idx = blockIdx.x * 256 + threadIdx.x;
    if (idx >= n) return;
    int add = (blockIdx.x > 0) ? bsum[blockIdx.x - 1] : 0;
    row_start[idx + 1] = partial[idx] + add;
    if (idx == 0) row_start[0] = 0;
}

__global__ void scatter_kernel(const int* __restrict__ ei, const int* __restrict__ row_start,
                               int* __restrict__ cursor, int* __restrict__ perm,
                               int E_, int EP_) {
    int e = blockIdx.x * 256 + threadIdx.x;
    if (e >= EP_) return;
    int d = (e < E_) ? ei[E_ + e] : (e - E_);
    int pos = row_start[d] + atomicAdd(&cursor[d], 1);
    perm[pos] = e;
}

__global__ void build_src(const int* __restrict__ ei, const int* __restrict__ perm,
                          int* __restrict__ src_sorted, int E_, int EP_) {
    int i = blockIdx.x * 256 + threadIdx.x;
    if (i >= EP_) return;
    int e = perm[i];
    src_sorted[i] = (e < E_) ? ei[e] : (e - E_);
}

// ---------------------------------------------------------------------------
// fp32 -> bf16 conversions
// ---------------------------------------------------------------------------
__global__ void conv_bf16(const float* __restrict__ in, unsigned short* __restrict__ out,
                          int n4) {
    int i = blockIdx.x * 256 + threadIdx.x;
    if (i >= n4) return;
    float4 v = reinterpret_cast<const float4*>(in)[i];
    reinterpret_cast<ushort4*>(out)[i] =
        make_ushort4(f2bf(v.x), f2bf(v.y), f2bf(v.z), f2bf(v.w));
}

// W [K][Nc] fp32 -> WT [Nc][K] bf16
__global__ void transpose_w(const float* __restrict__ W, unsigned short* __restrict__ WT,
                            int K, int Nc) {
    __shared__ float t[32][33];
    int bx = blockIdx.x * 32;   // n
    int by = blockIdx.y * 32;   // k
    int x = threadIdx.x, y = threadIdx.y;
    for (int i = y; i < 32; i += 8)
        t[i][x] = W[(size_t)(by + i) * Nc + bx + x];   // t[k_local][n_local]
    __syncthreads();
    for (int i = y; i < 32; i += 8)
        WT[(size_t)(bx + i) * K + by + x] = f2bf(t[x][i]);
}

// ---------------------------------------------------------------------------
// bf16 MFMA GEMM: C[M,Nc](bf16) = A[M,K](bf16) @ BT[Nc,K](bf16)^T
// BM=BN=128, BK=64, 256 threads = 4 waves (2x2), each wave 64x64 out.
// ---------------------------------------------------------------------------
__global__ __launch_bounds__(256) void gemm_bf16(const unsigned short* __restrict__ A,
                                                 const unsigned short* __restrict__ BT,
                                                 unsigned short* __restrict__ C,
                                                 int M, int K, int Nc) {
    __shared__ __align__(16) unsigned short As[128 * 64];  // [m][k], 16 KB
    __shared__ __align__(16) unsigned short Bs[128 * 64];  // [n][k], 16 KB
    const int tid = threadIdx.x;
    const int lane = tid & 63;
    const int wave = tid >> 6;
    const int wr = wave >> 1, wc = wave & 1;
    const int brow = blockIdx.y * 128;
    const int bcol = blockIdx.x * 128;

    f32x4 acc[4][4];
#pragma unroll
    for (int i = 0; i < 4; ++i)
#pragma unroll
        for (int j = 0; j < 4; ++j) acc[i][j] = (f32x4)0.f;

    const int lrow = lane >> 3;        // 0..7 (row within 8-row chunk)
    const int lcol = (lane & 7) * 8;   // k element offset (8 bf16 = 16B)
    const int arow0 = brow + wave * 32 + lrow;
    const int brow0 = bcol + wave * 32 + lrow;

    const int kb = (lane >> 4) * 8;
    const int rowa = wr * 64 + (lane & 15);
    const int rowb = wc * 64 + (lane & 15);

    for (int k0 = 0; k0 < K; k0 += 64) {
#pragma unroll
        for (int it = 0; it < 4; ++it) {
            const int c = wave * 4 + it;
            int ar = arow0 + it * 8;
            if (ar >= M) ar = M - 1;                       // clamp: rows >=M never stored
            gload16(A + (size_t)ar * K + k0 + lcol, &As[c * 512]);
            int br = brow0 + it * 8;
            gload16(BT + (size_t)br * K + k0 + lcol, &Bs[c * 512]);
        }
        __syncthreads();
#pragma unroll
        for (int kk = 0; kk < 64; kk += 32) {
            bf16x8 a[4], b[4];
#pragma unroll
            for (int m = 0; m < 4; ++m)
                a[m] = *(const bf16x8*)&As[(rowa + m * 16) * 64 + kk + kb];
#pragma unroll
            for (int nn = 0; nn < 4; ++nn)
                b[nn] = *(const bf16x8*)&Bs[(rowb + nn * 16) * 64 + kk + kb];
#pragma unroll
            for (int m = 0; m < 4; ++m)
#pragma unroll
                for (int nn = 0; nn < 4; ++nn)
                    acc[m][nn] = __builtin_amdgcn_mfma_f32_16x16x32_bf16(
                        a[m], b[nn], acc[m][nn], 0, 0, 0);
        }
        __syncthreads();
    }

    const int r0 = brow + wr * 64 + (lane >> 4) * 4;
    const int c0 = bcol + wc * 64 + (lane & 15);
#pragma unroll
    for (int m = 0; m < 4; ++m)
#pragma unroll
        for (int j = 0; j < 4; ++j) {
            int r = r0 + m * 16 + j;
            if (r < M) {
#pragma unroll
                for (int nn = 0; nn < 4; ++nn)
                    C[(size_t)r * Nc + c0 + nn * 16] = f2bf(acc[m][nn][j]);
            }
        }
}

// ---------------------------------------------------------------------------
// Attention coefficients from bf16 h
// ---------------------------------------------------------------------------
__global__ __launch_bounds__(256) void attn_coef(const unsigned short* __restrict__ h,
                                                 const float* __restrict__ as,
                                                 const float* __restrict__ ad,
                                                 float* __restrict__ a_src,
                                                 float* __restrict__ a_dst, int n) {
    int node = blockIdx.x * 4 + (threadIdx.x >> 6);
    int lane = threadIdx.x & 63;
    if (node >= n) return;
    const unsigned short* hp = h + (size_t)node * HC;
    float ps[8], pd[8];
#pragma unroll
    for (int k = 0; k < 8; ++k) {
        float hv = bf2f(hp[k * 64 + lane]);
        ps[k] = hv * as[k * 64 + lane];
        pd[k] = hv * ad[k * 64 + lane];
    }
#pragma unroll
    for (int off = 1; off < 64; off <<= 1) {
#pragma unroll
        for (int k = 0; k < 8; ++k) {
            ps[k] += __shfl_xor(ps[k], off);
            pd[k] += __shfl_xor(pd[k], off);
        }
    }
    if (lane < 8) {
        float vs = ps[0], vd = pd[0];
#pragma unroll
        for (int k = 1; k < 8; ++k) {
            if (lane == k) { vs = ps[k]; vd = pd[k]; }
        }
        a_src[node * 8 + lane] = vs;
        a_dst[node * 8 + lane] = vd;
    }
}

// ---------------------------------------------------------------------------
// Aggregation. h bf16; MODE 0: out bf16 [n][512] relu(acc+bias512)
//                      MODE 1: out fp32 [n][64]  relu(mean_h+bias64)
// ---------------------------------------------------------------------------
template <int MODE>
__global__ __launch_bounds__(256) void agg_kernel(const unsigned short* __restrict__ h,
                                                  const float* __restrict__ a_src,
                                                  const float* __restrict__ a_dst,
                                                  const float* __restrict__ bias,
                                                  const int* __restrict__ row_start,
                                                  const int* __restrict__ src_sorted,
                                                  void* __restrict__ outv, int n) {
    int d = blockIdx.x * 4 + (threadIdx.x >> 6);
    int lane = threadIdx.x & 63;
    if (d >= n) return;
    int base = row_start[d];
    int end = row_start[d + 1];
    int head = lane & 7;
    int eslot = lane >> 3;
    float adh = a_dst[d * 8 + head];

    float mx = -1e30f;
    for (int i = base + eslot; i < end; i += 8) {
        int s = src_sorted[i];
        float al = a_src[s * 8 + head] + adh;
        al = (al > 0.f) ? al : NEG_SLOPE * al;
        mx = fmaxf(mx, al);
    }
    mx = fmaxf(mx, __shfl_xor(mx, 8));
    mx = fmaxf(mx, __shfl_xor(mx, 16));
    mx = fmaxf(mx, __shfl_xor(mx, 32));

    float sm = 0.f;
    for (int i = base + eslot; i < end; i += 8) {
        int s = src_sorted[i];
        float al = a_src[s * 8 + head] + adh;
        al = (al > 0.f) ? al : NEG_SLOPE * al;
        sm += expf(al - mx);
    }
    sm += __shfl_xor(sm, 8);
    sm += __shfl_xor(sm, 16);
    sm += __shfl_xor(sm, 32);
    float inv = 1.0f / (sm + EPS_);     // lane k<8 holds head k's mx/inv

    float acc[8] = {};
    for (int i = base; i < end; ++i) {
        int s = src_sorted[i];
        float w = 0.f;
        if (lane < 8) {
            float al = a_src[s * 8 + lane] + a_dst[d * 8 + lane];
            al = (al > 0.f) ? al : NEG_SLOPE * al;
            w = expf(al - mx) * inv;
        }
        const unsigned short* hs = h + (size_t)s * HC;
#pragma unroll
        for (int k = 0; k < 8; ++k)
            acc[k] += __shfl(w, k) * bf2f(hs[k * 64 + lane]);
    }

    if (MODE == 0) {
        unsigned short* op = (unsigned short*)outv + (size_t)d * HC;
#pragma unroll
        for (int k = 0; k < 8; ++k) {
            float v = acc[k] + bias[k * 64 + lane];
            op[k * 64 + lane] = f2bf(fmaxf(v, 0.f));
        }
    } else {
        float s8 = 0.f;
#pragma unroll
        for (int k = 0; k < 8; ++k) s8 += acc[k];
        float v = s8 * 0.125f + bias[lane];
        ((float*)outv)[(size_t)d * 64 + lane] = fmaxf(v, 0.f);
    }
}

// ---------------------------------------------------------------------------
// Pool: batch is SORTED -> one block per graph, binary search boundaries,
// coalesced segment sum. No atomics.
// ---------------------------------------------------------------------------
__global__ __launch_bounds__(256) void pool_seg(const float* __restrict__ h3,
                                                const int* __restrict__ batch,
                                                float* __restrict__ pooled,
                                                int* __restrict__ cnt, int n) {
    int g = blockIdx.x;
    __shared__ int s_lo, s_hi;
    if (threadIdx.x == 0) {
        int lo = 0, hi = n;
        while (lo < hi) { int mid = (lo + hi) >> 1; if (batch[mid] < g) lo = mid + 1; else hi = mid; }
        s_lo = lo;
        int lo2 = lo, hi2 = n;
        while (lo2 < hi2) { int mid = (lo2 + hi2) >> 1; if (batch[mid] < g + 1) lo2 = mid + 1; else hi2 = mid; }
        s_hi = lo2;
    }
    __syncthreads();
    int lo = s_lo, hi = s_hi;
    int lane = threadIdx.x & 63;
    int slot = threadIdx.x >> 6;
    float acc = 0.f;
    for (int i = lo + slot; i < hi; i += 4)
        acc += h3[(size_t)i * 64 + lane];
    __shared__ float red[4][64];
    red[slot][lane] = acc;
    __syncthreads();
    if (slot == 0) {
        float v = red[0][lane] + red[1][lane] + red[2][lane] + red[3][lane];
        pooled[g * 64 + lane] = v;
        if (lane == 0) cnt[g] = hi - lo;
    }
}

__global__ void classify_kernel(const float* __restrict__ pooled,
                                const int* __restrict__ cnt,
                                const float* __restrict__ fcw,
                                const float* __restrict__ fcb,
                                float* __restrict__ out) {
    int g = blockIdx.x;
    int lane = threadIdx.x & 63;
    float c = (float)cnt[g];
    c = fmaxf(c, 1.0f);
    float p = pooled[g * 64 + lane] / c;
    float logit[NCLS];
#pragma unroll
    for (int j = 0; j < NCLS; ++j) {
        float t = p * fcw[lane * NCLS + j];
#pragma unroll
        for (int off = 1; off < 64; off <<= 1) t += __shfl_xor(t, off);
        logit[j] = t + fcb[j];
    }
    float m = logit[0];
#pragma unroll
    for (int j = 1; j < NCLS; ++j) m = fmaxf(m, logit[j]);
    float s = 0.f;
#pragma unroll
    for (int j = 0; j < NCLS; ++j) s += expf(logit[j] - m);
    float lse = logf(s);
    if (lane < NCLS) {
        float v = logit[0];
#pragma unroll
        for (int j = 1; j < NCLS; ++j)
            if (lane == j) v = logit[j];
        out[g * NCLS + lane] = v - m - lse;
    }
}

// ---------------------------------------------------------------------------
extern "C" void kernel_launch(void* const* d_in, const int* in_sizes, int n_in,
                              void* d_out, int out_size, void* d_ws, size_t ws_size,
                              hipStream_t stream) {
    const float* x    = (const float*)d_in[0];
    const int*   ei   = (const int*)d_in[1];
    const int*   batch = (const int*)d_in[2];
    const float* W1  = (const float*)d_in[3];
    const float* a1s = (const float*)d_in[4];
    const float* a1d = (const float*)d_in[5];
    const float* b1  = (const float*)d_in[6];
    const float* W2  = (const float*)d_in[7];
    const float* a2s = (const float*)d_in[8];
    const float* a2d = (const float*)d_in[9];
    const float* b2  = (const float*)d_in[10];
    const float* W3  = (const float*)d_in[11];
    const float* a3s = (const float*)d_in[12];
    const float* a3d = (const float*)d_in[13];
    const float* b3  = (const float*)d_in[14];
    const float* fcw = (const float*)d_in[15];
    const float* fcb = (const float*)d_in[16];

    const int n  = in_sizes[0] / F_IN;     // 50000
    const int E_ = in_sizes[1] / 2;        // 400000
    const int EP = E_ + n;                 // 450000

    // ---- workspace carve-up ----
    char* p = (char*)d_ws;
    unsigned short* xb   = (unsigned short*)p; p += (size_t)n * F_IN * 2;
    unsigned short* w1t  = (unsigned short*)p; p += (size_t)HC * F_IN * 2;
    unsigned short* w2t  = (unsigned short*)p; p += (size_t)HC * HC * 2;
    unsigned short* w3t  = (unsigned short*)p; p += (size_t)HC * HC * 2;
    unsigned short* hbuf = (unsigned short*)p; p += (size_t)n * HC * 2;
    unsigned short* buf2 = (unsigned short*)p; p += (size_t)n * HC * 2;
    float* asrc   = (float*)p; p += (size_t)n * 8 * 4;
    float* adst   = (float*)p; p += (size_t)n * 8 * 4;
    float* h3     = (float*)p; p += (size_t)n * 64 * 4;
    float* pooled = (float*)p; p += (size_t)GG * 64 * 4;
    int* cnt      = (int*)p;   p += (size_t)GG * 4;
    int* counts   = (int*)p;   p += (size_t)n * 4;
    int* row_start= (int*)p;   p += (size_t)(n + 1) * 4;
    int* perm     = (int*)p;   p += (size_t)EP * 4;
    int* src_sorted=(int*)p;   p += (size_t)EP * 4;
    int* partial  = (int*)p;   p += (size_t)n * 4;
    int* bsum     = (int*)p;   p += 1024 * 4;

    const int edge_blocks = (EP + 255) / 256;
    const int node_blocks = (n + 3) / 4;
    const int scan_blocks = (n + 255) / 256;

    // ---- CSR build ----
    hipMemsetAsync(counts, 0, (size_t)n * sizeof(int), stream);
    hist_kernel<<<edge_blocks, 256, 0, stream>>>(ei, counts, E_, EP);
    scan1<<<scan_blocks, 256, 0, stream>>>(counts, partial, bsum, n);
    scan2<<<1, 1024, 0, stream>>>(bsum, scan_blocks);
    scan3<<<scan_blocks, 256, 0, stream>>>(partial, bsum, row_start, n);
    hipMemsetAsync(counts, 0, (size_t)n * sizeof(int), stream);
    scatter_kernel<<<edge_blocks, 256, 0, stream>>>(ei, row_start, counts, perm, E_, EP);
    build_src<<<edge_blocks, 256, 0, stream>>>(ei, perm, src_sorted, E_, EP);

    // ---- conversions ----
    conv_bf16<<<((n * F_IN / 4) + 255) / 256, 256, 0, stream>>>(x, xb, n * F_IN / 4);
    transpose_w<<<dim3(HC / 32, F_IN / 32), dim3(32, 8), 0, stream>>>(W1, w1t, F_IN, HC);
    transpose_w<<<dim3(HC / 32, HC / 32), dim3(32, 8), 0, stream>>>(W2, w2t, HC, HC);
    transpose_w<<<dim3(HC / 32, HC / 32), dim3(32, 8), 0, stream>>>(W3, w3t, HC, HC);

    dim3 gemm_grid(HC / 128, (n + 127) / 128);

    // ---- Layer 1 ----
    gemm_bf16<<<gemm_grid, 256, 0, stream>>>(xb, w1t, hbuf, n, F_IN, HC);
    attn_coef<<<node_blocks, 256, 0, stream>>>(hbuf, a1s, a1d, asrc, adst, n);
    agg_kernel<0><<<node_blocks, 256, 0, stream>>>(hbuf, asrc, adst, b1, row_start, src_sorted, buf2, n);

    // ---- Layer 2 ----
    gemm_bf16<<<gemm_grid, 256, 0, stream>>>(buf2, w2t, hbuf, n, HC, HC);
    attn_coef<<<node_blocks, 256, 0, stream>>>(hbuf, a2s, a2d, asrc, adst, n);
    agg_kernel<0><<<node_blocks, 256, 0, stream>>>(hbuf, asrc, adst, b2, row_start, src_sorted, buf2, n);

    // ---- Layer 3 ----
    gemm_bf16<<<gemm_grid, 256, 0, stream>>>(buf2, w3t, hbuf, n, HC, HC);
    attn_coef<<<node_blocks, 256, 0, stream>>>(hbuf, a3s, a3d, asrc, adst, n);
    agg_kernel<1><<<node_blocks, 256, 0, stream>>>(hbuf, asrc, adst, b3, row_start, src_sorted, h3, n);

    // ---- Pool + classify ----
    pool_seg<<<GG, 256, 0, stream>>>(h3, batch, pooled, cnt, n);
    classify_kernel<<<GG, 64, 0, stream>>>(pooled, cnt, fcw, fcb, (float*)d_out);
}

// Round 4
// 526.216 us; speedup vs baseline: 3.5024x; 1.4012x over previous
//
#include <hip/hip_runtime.h>
#include <hip/hip_bf16.h>

#define HH 8
#define CC 64
#define HC 512
#define GG 64
#define NCLS 10
#define F_IN 128
#define NEG_SLOPE 0.2f
#define EPS_ 1e-16f
#define MAXD 32

typedef float f32x4 __attribute__((ext_vector_type(4)));
typedef __bf16 bf16x8 __attribute__((ext_vector_type(8)));

__device__ __forceinline__ unsigned short f2bf(float f) {
    unsigned u = __builtin_bit_cast(unsigned, f);
    u += 0x7fffu + ((u >> 16) & 1u);          // RNE
    return (unsigned short)(u >> 16);
}
__device__ __forceinline__ float bf2f(unsigned short s) {
    unsigned u = ((unsigned)s) << 16;
    return __builtin_bit_cast(float, u);
}
__device__ __forceinline__ float bflo(unsigned u) {   // low bf16 of a packed u32
    return __builtin_bit_cast(float, u << 16);
}
__device__ __forceinline__ float bfhi(unsigned u) {   // high bf16
    return __builtin_bit_cast(float, u & 0xffff0000u);
}

// async global->LDS, 16B per lane. lds ptr must be wave-uniform base.
__device__ __forceinline__ void gload16(const unsigned short* g, unsigned short* l) {
    __builtin_amdgcn_global_load_lds(
        (const __attribute__((address_space(1))) unsigned int*)g,
        (__attribute__((address_space(3))) unsigned int*)l,
        16, 0, 0);
}

// ---------------------------------------------------------------------------
// CSR build
// ---------------------------------------------------------------------------
__global__ void hist_kernel(const int* __restrict__ ei, int* __restrict__ counts,
                            int E_, int EP_) {
    int e = blockIdx.x * 256 + threadIdx.x;
    if (e >= EP_) return;
    int d = (e < E_) ? ei[E_ + e] : (e - E_);
    atomicAdd(&counts[d], 1);
}

__global__ void scan1(const int* __restrict__ counts, int* __restrict__ partial,
                      int* __restrict__ bsum, int n) {
    __shared__ int buf[256];
    int idx = blockIdx.x * 256 + threadIdx.x;
    int v = (idx < n) ? counts[idx] : 0;
    buf[threadIdx.x] = v;
    __syncthreads();
    for (int off = 1; off < 256; off <<= 1) {
        int t = (threadIdx.x >= off) ? buf[threadIdx.x - off] : 0;
        __syncthreads();
        buf[threadIdx.x] += t;
        __syncthreads();
    }
    if (idx < n) partial[idx] = buf[threadIdx.x];
    if (threadIdx.x == 255) bsum[blockIdx.x] = buf[255];
}

__global__ void scan2(int* __restrict__ bsum, int nb) {
    __shared__ int buf[1024];
    int t = threadIdx.x;
    buf[t] = (t < nb) ? bsum[t] : 0;
    __syncthreads();
    for (int off = 1; off < 1024; off <<= 1) {
        int v = (t >= off) ? buf[t - off] : 0;
        __syncthreads();
        buf[t] += v;
        __syncthreads();
    }
    if (t < nb) bsum[t] = buf[t];
}

__global__ void scan3(const int* __restrict__ partial, const int* __restrict__ bsum,
                      int* __restrict__ row_start, int n) {
    int idx = blockIdx.x * 256 + threadIdx.x;
    if (idx >= n) return;
    int add = (blockIdx.x > 0) ? bsum[blockIdx.x - 1] : 0;
    row_start[idx + 1] = partial[idx] + add;
    if (idx == 0) row_start[0] = 0;
}

__global__ void scatter_kernel(const int* __restrict__ ei, const int* __restrict__ row_start,
                               int* __restrict__ cursor, int* __restrict__ perm,
                               int E_, int EP_) {
    int e = blockIdx.x * 256 + threadIdx.x;
    if (e >= EP_) return;
    int d = (e < E_) ? ei[E_ + e] : (e - E_);
    int pos = row_start[d] + atomicAdd(&cursor[d], 1);
    perm[pos] = e;
}

__global__ void build_src(const int* __restrict__ ei, const int* __restrict__ perm,
                          int* __restrict__ src_sorted, int E_, int EP_) {
    int i = blockIdx.x * 256 + threadIdx.x;
    if (i >= EP_) return;
    int e = perm[i];
    src_sorted[i] = (e < E_) ? ei[e] : (e - E_);
}

// ---------------------------------------------------------------------------
// fp32 -> bf16 conversions
// ---------------------------------------------------------------------------
__global__ void conv_bf16(const float* __restrict__ in, unsigned short* __restrict__ out,
                          int n4) {
    int i = blockIdx.x * 256 + threadIdx.x;
    if (i >= n4) return;
    float4 v = reinterpret_cast<const float4*>(in)[i];
    reinterpret_cast<ushort4*>(out)[i] =
        make_ushort4(f2bf(v.x), f2bf(v.y), f2bf(v.z), f2bf(v.w));
}

// W [K][Nc] fp32 -> WT [Nc][K] bf16
__global__ void transpose_w(const float* __restrict__ W, unsigned short* __restrict__ WT,
                            int K, int Nc) {
    __shared__ float t[32][33];
    int bx = blockIdx.x * 32;   // n
    int by = blockIdx.y * 32;   // k
    int x = threadIdx.x, y = threadIdx.y;
    for (int i = y; i < 32; i += 8)
        t[i][x] = W[(size_t)(by + i) * Nc + bx + x];   // t[k_local][n_local]
    __syncthreads();
    for (int i = y; i < 32; i += 8)
        WT[(size_t)(bx + i) * K + by + x] = f2bf(t[x][i]);
}

// ---------------------------------------------------------------------------
// bf16 MFMA GEMM: C[M,Nc](bf16) = A[M,K](bf16) @ BT[Nc,K](bf16)^T
// BM=BN=128, BK=64, 256 threads = 4 waves (2x2), each wave 64x64 out.
// ---------------------------------------------------------------------------
__global__ __launch_bounds__(256) void gemm_bf16(const unsigned short* __restrict__ A,
                                                 const unsigned short* __restrict__ BT,
                                                 unsigned short* __restrict__ C,
                                                 int M, int K, int Nc) {
    __shared__ __align__(16) unsigned short As[128 * 64];  // [m][k], 16 KB
    __shared__ __align__(16) unsigned short Bs[128 * 64];  // [n][k], 16 KB
    const int tid = threadIdx.x;
    const int lane = tid & 63;
    const int wave = tid >> 6;
    const int wr = wave >> 1, wc = wave & 1;
    const int brow = blockIdx.y * 128;
    const int bcol = blockIdx.x * 128;

    f32x4 acc[4][4];
#pragma unroll
    for (int i = 0; i < 4; ++i)
#pragma unroll
        for (int j = 0; j < 4; ++j) acc[i][j] = (f32x4)0.f;

    const int lrow = lane >> 3;        // 0..7 (row within 8-row chunk)
    const int lcol = (lane & 7) * 8;   // k element offset (8 bf16 = 16B)
    const int arow0 = brow + wave * 32 + lrow;
    const int brow0 = bcol + wave * 32 + lrow;

    const int kb = (lane >> 4) * 8;
    const int rowa = wr * 64 + (lane & 15);
    const int rowb = wc * 64 + (lane & 15);

    for (int k0 = 0; k0 < K; k0 += 64) {
#pragma unroll
        for (int it = 0; it < 4; ++it) {
            const int c = wave * 4 + it;
            int ar = arow0 + it * 8;
            if (ar >= M) ar = M - 1;                       // clamp: rows >=M never stored
            gload16(A + (size_t)ar * K + k0 + lcol, &As[c * 512]);
            int br = brow0 + it * 8;
            gload16(BT + (size_t)br * K + k0 + lcol, &Bs[c * 512]);
        }
        __syncthreads();
#pragma unroll
        for (int kk = 0; kk < 64; kk += 32) {
            bf16x8 a[4], b[4];
#pragma unroll
            for (int m = 0; m < 4; ++m)
                a[m] = *(const bf16x8*)&As[(rowa + m * 16) * 64 + kk + kb];
#pragma unroll
            for (int nn = 0; nn < 4; ++nn)
                b[nn] = *(const bf16x8*)&Bs[(rowb + nn * 16) * 64 + kk + kb];
#pragma unroll
            for (int m = 0; m < 4; ++m)
#pragma unroll
                for (int nn = 0; nn < 4; ++nn)
                    acc[m][nn] = __builtin_amdgcn_mfma_f32_16x16x32_bf16(
                        a[m], b[nn], acc[m][nn], 0, 0, 0);
        }
        __syncthreads();
    }

    const int r0 = brow + wr * 64 + (lane >> 4) * 4;
    const int c0 = bcol + wc * 64 + (lane & 15);
#pragma unroll
    for (int m = 0; m < 4; ++m)
#pragma unroll
        for (int j = 0; j < 4; ++j) {
            int r = r0 + m * 16 + j;
            if (r < M) {
#pragma unroll
                for (int nn = 0; nn < 4; ++nn)
                    C[(size_t)r * Nc + c0 + nn * 16] = f2bf(acc[m][nn][j]);
            }
        }
}

// ---------------------------------------------------------------------------
// Attention coefficients. Lane owns 8 contiguous channels (16B vector load);
// head group = 8 consecutive lanes; 3-level shfl_xor reduce within group.
// ---------------------------------------------------------------------------
__global__ __launch_bounds__(256) void attn_coef(const unsigned short* __restrict__ h,
                                                 const float* __restrict__ as,
                                                 const float* __restrict__ ad,
                                                 float* __restrict__ a_src,
                                                 float* __restrict__ a_dst, int n) {
    int node = blockIdx.x * 4 + (threadIdx.x >> 6);
    int lane = threadIdx.x & 63;
    if (node >= n) return;
    const unsigned short* hp = h + (size_t)node * HC + lane * 8;
    uint4 hv = *reinterpret_cast<const uint4*>(hp);
    float4 a0 = *reinterpret_cast<const float4*>(as + lane * 8);
    float4 a1 = *reinterpret_cast<const float4*>(as + lane * 8 + 4);
    float4 d0 = *reinterpret_cast<const float4*>(ad + lane * 8);
    float4 d1 = *reinterpret_cast<const float4*>(ad + lane * 8 + 4);
    float hf[8];
    hf[0] = bflo(hv.x); hf[1] = bfhi(hv.x);
    hf[2] = bflo(hv.y); hf[3] = bfhi(hv.y);
    hf[4] = bflo(hv.z); hf[5] = bfhi(hv.z);
    hf[6] = bflo(hv.w); hf[7] = bfhi(hv.w);
    float ps = hf[0]*a0.x + hf[1]*a0.y + hf[2]*a0.z + hf[3]*a0.w
             + hf[4]*a1.x + hf[5]*a1.y + hf[6]*a1.z + hf[7]*a1.w;
    float pd = hf[0]*d0.x + hf[1]*d0.y + hf[2]*d0.z + hf[3]*d0.w
             + hf[4]*d1.x + hf[5]*d1.y + hf[6]*d1.z + hf[7]*d1.w;
    ps += __shfl_xor(ps, 1); pd += __shfl_xor(pd, 1);
    ps += __shfl_xor(ps, 2); pd += __shfl_xor(pd, 2);
    ps += __shfl_xor(ps, 4); pd += __shfl_xor(pd, 4);
    if ((lane & 7) == 0) {
        a_src[node * 8 + (lane >> 3)] = ps;
        a_dst[node * 8 + (lane >> 3)] = pd;
    }
}

// ---------------------------------------------------------------------------
// Aggregation. One wave per node. Softmax phases use (head=lane&7,
// eslot=lane>>3); alphas cached in per-wave LDS [MAXD][8]. Accumulate phase:
// lane owns channels lane*8..+7 (head lane>>3), h gathered as 16B vectors,
// weight read from LDS (broadcast) — zero shfl per edge.
// MODE 0: out bf16 [n][512] relu(acc+bias512); MODE 1: out fp32 [n][64].
// ---------------------------------------------------------------------------
template <int MODE>
__global__ __launch_bounds__(256) void agg_kernel(const unsigned short* __restrict__ h,
                                                  const float* __restrict__ a_src,
                                                  const float* __restrict__ a_dst,
                                                  const float* __restrict__ bias,
                                                  const int* __restrict__ row_start,
                                                  const int* __restrict__ src_sorted,
                                                  void* __restrict__ outv, int n) {
    __shared__ float alds[4][MAXD][8];
    int ws = threadIdx.x >> 6;
    int d = blockIdx.x * 4 + ws;
    int lane = threadIdx.x & 63;
    if (d >= n) return;
    int base = row_start[d];
    int end = row_start[d + 1];
    int deg = end - base;
    int head = lane & 7;
    int eslot = lane >> 3;
    float adh = a_dst[d * 8 + head];

    // phase 1: alpha + per-head max; cache alpha in LDS
    float mx = -1e30f;
    for (int idx = eslot; idx < deg; idx += 8) {
        int s = src_sorted[base + idx];
        float al = a_src[s * 8 + head] + adh;
        al = (al > 0.f) ? al : NEG_SLOPE * al;
        if (idx < MAXD) alds[ws][idx][head] = al;
        mx = fmaxf(mx, al);
    }
    mx = fmaxf(mx, __shfl_xor(mx, 8));
    mx = fmaxf(mx, __shfl_xor(mx, 16));
    mx = fmaxf(mx, __shfl_xor(mx, 32));

    // phase 2: exp + sum; overwrite LDS with exp values
    float sm = 0.f;
    for (int idx = eslot; idx < deg; idx += 8) {
        float e;
        if (idx < MAXD) {
            float al = alds[ws][idx][head];
            e = __expf(al - mx);
            alds[ws][idx][head] = e;
        } else {
            int s = src_sorted[base + idx];
            float al = a_src[s * 8 + head] + adh;
            al = (al > 0.f) ? al : NEG_SLOPE * al;
            e = __expf(al - mx);
        }
        sm += e;
    }
    sm += __shfl_xor(sm, 8);
    sm += __shfl_xor(sm, 16);
    sm += __shfl_xor(sm, 32);
    float inv = 1.0f / (sm + EPS_);

    // ensure this wave's LDS writes are visible before cross-lane reads
    asm volatile("s_waitcnt lgkmcnt(0)" ::: "memory");
    __builtin_amdgcn_wave_barrier();

    // phase 3: accumulate. lane owns channels [lane*8, lane*8+8), head hd2
    int hd2 = lane >> 3;
    float mx2 = __shfl(mx, hd2);
    float inv2 = __shfl(inv, hd2);
    float adh2 = a_dst[d * 8 + hd2];

    float acc[8] = {};
    for (int i = base; i < end; ++i) {
        int idx = i - base;
        int s = src_sorted[i];
        float w;
        if (idx < MAXD) {
            w = alds[ws][idx][hd2] * inv2;
        } else {
            float al = a_src[s * 8 + hd2] + adh2;
            al = (al > 0.f) ? al : NEG_SLOPE * al;
            w = __expf(al - mx2) * inv2;
        }
        uint4 hv = *reinterpret_cast<const uint4*>(h + (size_t)s * HC + lane * 8);
        acc[0] += w * bflo(hv.x); acc[1] += w * bfhi(hv.x);
        acc[2] += w * bflo(hv.y); acc[3] += w * bfhi(hv.y);
        acc[4] += w * bflo(hv.z); acc[5] += w * bfhi(hv.z);
        acc[6] += w * bflo(hv.w); acc[7] += w * bfhi(hv.w);
    }

    if (MODE == 0) {
        float4 b0 = *reinterpret_cast<const float4*>(bias + lane * 8);
        float4 b1 = *reinterpret_cast<const float4*>(bias + lane * 8 + 4);
        float v[8];
        v[0] = fmaxf(acc[0] + b0.x, 0.f); v[1] = fmaxf(acc[1] + b0.y, 0.f);
        v[2] = fmaxf(acc[2] + b0.z, 0.f); v[3] = fmaxf(acc[3] + b0.w, 0.f);
        v[4] = fmaxf(acc[4] + b1.x, 0.f); v[5] = fmaxf(acc[5] + b1.y, 0.f);
        v[6] = fmaxf(acc[6] + b1.z, 0.f); v[7] = fmaxf(acc[7] + b1.w, 0.f);
        uint4 o;
        o.x = (unsigned)f2bf(v[0]) | ((unsigned)f2bf(v[1]) << 16);
        o.y = (unsigned)f2bf(v[2]) | ((unsigned)f2bf(v[3]) << 16);
        o.z = (unsigned)f2bf(v[4]) | ((unsigned)f2bf(v[5]) << 16);
        o.w = (unsigned)f2bf(v[6]) | ((unsigned)f2bf(v[7]) << 16);
        *reinterpret_cast<uint4*>((unsigned short*)outv + (size_t)d * HC + lane * 8) = o;
    } else {
        // mean over heads: reduce across lanes with same (lane&7)
#pragma unroll
        for (int j = 0; j < 8; ++j) {
            acc[j] += __shfl_xor(acc[j], 8);
            acc[j] += __shfl_xor(acc[j], 16);
            acc[j] += __shfl_xor(acc[j], 32);
        }
        if (lane < 8) {
            float* op = (float*)outv + (size_t)d * 64 + lane * 8;
            float4 o0, o1;
            o0.x = fmaxf(acc[0] * 0.125f + bias[lane * 8 + 0], 0.f);
            o0.y = fmaxf(acc[1] * 0.125f + bias[lane * 8 + 1], 0.f);
            o0.z = fmaxf(acc[2] * 0.125f + bias[lane * 8 + 2], 0.f);
            o0.w = fmaxf(acc[3] * 0.125f + bias[lane * 8 + 3], 0.f);
            o1.x = fmaxf(acc[4] * 0.125f + bias[lane * 8 + 4], 0.f);
            o1.y = fmaxf(acc[5] * 0.125f + bias[lane * 8 + 5], 0.f);
            o1.z = fmaxf(acc[6] * 0.125f + bias[lane * 8 + 6], 0.f);
            o1.w = fmaxf(acc[7] * 0.125f + bias[lane * 8 + 7], 0.f);
            *reinterpret_cast<float4*>(op) = o0;
            *reinterpret_cast<float4*>(op + 4) = o1;
        }
    }
}

// ---------------------------------------------------------------------------
// Pool: batch is SORTED -> one block per graph, binary search boundaries,
// coalesced segment sum. No atomics.
// ---------------------------------------------------------------------------
__global__ __launch_bounds__(256) void pool_seg(const float* __restrict__ h3,
                                                const int* __restrict__ batch,
                                                float* __restrict__ pooled,
                                                int* __restrict__ cnt, int n) {
    int g = blockIdx.x;
    __shared__ int s_lo, s_hi;
    if (threadIdx.x == 0) {
        int lo = 0, hi = n;
        while (lo < hi) { int mid = (lo + hi) >> 1; if (batch[mid] < g) lo = mid + 1; else hi = mid; }
        s_lo = lo;
        int lo2 = lo, hi2 = n;
        while (lo2 < hi2) { int mid = (lo2 + hi2) >> 1; if (batch[mid] < g + 1) lo2 = mid + 1; else hi2 = mid; }
        s_hi = lo2;
    }
    __syncthreads();
    int lo = s_lo, hi = s_hi;
    int lane = threadIdx.x & 63;
    int slot = threadIdx.x >> 6;
    float acc = 0.f;
    for (int i = lo + slot; i < hi; i += 4)
        acc += h3[(size_t)i * 64 + lane];
    __shared__ float red[4][64];
    red[slot][lane] = acc;
    __syncthreads();
    if (slot == 0) {
        float v = red[0][lane] + red[1][lane] + red[2][lane] + red[3][lane];
        pooled[g * 64 + lane] = v;
        if (lane == 0) cnt[g] = hi - lo;
    }
}

__global__ void classify_kernel(const float* __restrict__ pooled,
                                const int* __restrict__ cnt,
                                const float* __restrict__ fcw,
                                const float* __restrict__ fcb,
                                float* __restrict__ out) {
    int g = blockIdx.x;
    int lane = threadIdx.x & 63;
    float c = (float)cnt[g];
    c = fmaxf(c, 1.0f);
    float p = pooled[g * 64 + lane] / c;
    float logit[NCLS];
#pragma unroll
    for (int j = 0; j < NCLS; ++j) {
        float t = p * fcw[lane * NCLS + j];
#pragma unroll
        for (int off = 1; off < 64; off <<= 1) t += __shfl_xor(t, off);
        logit[j] = t + fcb[j];
    }
    float m = logit[0];
#pragma unroll
    for (int j = 1; j < NCLS; ++j) m = fmaxf(m, logit[j]);
    float s = 0.f;
#pragma unroll
    for (int j = 0; j < NCLS; ++j) s += expf(logit[j] - m);
    float lse = logf(s);
    if (lane < NCLS) {
        float v = logit[0];
#pragma unroll
        for (int j = 1; j < NCLS; ++j)
            if (lane == j) v = logit[j];
        out[g * NCLS + lane] = v - m - lse;
    }
}

// ---------------------------------------------------------------------------
extern "C" void kernel_launch(void* const* d_in, const int* in_sizes, int n_in,
                              void* d_out, int out_size, void* d_ws, size_t ws_size,
                              hipStream_t stream) {
    const float* x    = (const float*)d_in[0];
    const int*   ei   = (const int*)d_in[1];
    const int*   batch = (const int*)d_in[2];
    const float* W1  = (const float*)d_in[3];
    const float* a1s = (const float*)d_in[4];
    const float* a1d = (const float*)d_in[5];
    const float* b1  = (const float*)d_in[6];
    const float* W2  = (const float*)d_in[7];
    const float* a2s = (const float*)d_in[8];
    const float* a2d = (const float*)d_in[9];
    const float* b2  = (const float*)d_in[10];
    const float* W3  = (const float*)d_in[11];
    const float* a3s = (const float*)d_in[12];
    const float* a3d = (const float*)d_in[13];
    const float* b3  = (const float*)d_in[14];
    const float* fcw = (const float*)d_in[15];
    const float* fcb = (const float*)d_in[16];

    const int n  = in_sizes[0] / F_IN;     // 50000
    const int E_ = in_sizes[1] / 2;        // 400000
    const int EP = E_ + n;                 // 450000

    // ---- workspace carve-up ----
    char* p = (char*)d_ws;
    unsigned short* xb   = (unsigned short*)p; p += (size_t)n * F_IN * 2;
    unsigned short* w1t  = (unsigned short*)p; p += (size_t)HC * F_IN * 2;
    unsigned short* w2t  = (unsigned short*)p; p += (size_t)HC * HC * 2;
    unsigned short* w3t  = (unsigned short*)p; p += (size_t)HC * HC * 2;
    unsigned short* hbuf = (unsigned short*)p; p += (size_t)n * HC * 2;
    unsigned short* buf2 = (unsigned short*)p; p += (size_t)n * HC * 2;
    float* asrc   = (float*)p; p += (size_t)n * 8 * 4;
    float* adst   = (float*)p; p += (size_t)n * 8 * 4;
    float* h3     = (float*)p; p += (size_t)n * 64 * 4;
    float* pooled = (float*)p; p += (size_t)GG * 64 * 4;
    int* cnt      = (int*)p;   p += (size_t)GG * 4;
    int* counts   = (int*)p;   p += (size_t)n * 4;
    int* row_start= (int*)p;   p += (size_t)(n + 1) * 4;
    int* perm     = (int*)p;   p += (size_t)EP * 4;
    int* src_sorted=(int*)p;   p += (size_t)EP * 4;
    int* partial  = (int*)p;   p += (size_t)n * 4;
    int* bsum     = (int*)p;   p += 1024 * 4;

    const int edge_blocks = (EP + 255) / 256;
    const int node_blocks = (n + 3) / 4;
    const int scan_blocks = (n + 255) / 256;

    // ---- CSR build ----
    hipMemsetAsync(counts, 0, (size_t)n * sizeof(int), stream);
    hist_kernel<<<edge_blocks, 256, 0, stream>>>(ei, counts, E_, EP);
    scan1<<<scan_blocks, 256, 0, stream>>>(counts, partial, bsum, n);
    scan2<<<1, 1024, 0, stream>>>(bsum, scan_blocks);
    scan3<<<scan_blocks, 256, 0, stream>>>(partial, bsum, row_start, n);
    hipMemsetAsync(counts, 0, (size_t)n * sizeof(int), stream);
    scatter_kernel<<<edge_blocks, 256, 0, stream>>>(ei, row_start, counts, perm, E_, EP);
    build_src<<<edge_blocks, 256, 0, stream>>>(ei, perm, src_sorted, E_, EP);

    // ---- conversions ----
    conv_bf16<<<((n * F_IN / 4) + 255) / 256, 256, 0, stream>>>(x, xb, n * F_IN / 4);
    transpose_w<<<dim3(HC / 32, F_IN / 32), dim3(32, 8), 0, stream>>>(W1, w1t, F_IN, HC);
    transpose_w<<<dim3(HC / 32, HC / 32), dim3(32, 8), 0, stream>>>(W2, w2t, HC, HC);
    transpose_w<<<dim3(HC / 32, HC / 32), dim3(32, 8), 0, stream>>>(W3, w3t, HC, HC);

    dim3 gemm_grid(HC / 128, (n + 127) / 128);

    // ---- Layer 1 ----
    gemm_bf16<<<gemm_grid, 256, 0, stream>>>(xb, w1t, hbuf, n, F_IN, HC);
    attn_coef<<<node_blocks, 256, 0, stream>>>(hbuf, a1s, a1d, asrc, adst, n);
    agg_kernel<0><<<node_blocks, 256, 0, stream>>>(hbuf, asrc, adst, b1, row_start, src_sorted, buf2, n);

    // ---- Layer 2 ----
    gemm_bf16<<<gemm_grid, 256, 0, stream>>>(buf2, w2t, hbuf, n, HC, HC);
    attn_coef<<<node_blocks, 256, 0, stream>>>(hbuf, a2s, a2d, asrc, adst, n);
    agg_kernel<0><<<node_blocks, 256, 0, stream>>>(hbuf, asrc, adst, b2, row_start, src_sorted, buf2, n);

    // ---- Layer 3 ----
    gemm_bf16<<<gemm_grid, 256, 0, stream>>>(buf2, w3t, hbuf, n, HC, HC);
    attn_coef<<<node_blocks, 256, 0, stream>>>(hbuf, a3s, a3d, asrc, adst, n);
    agg_kernel<1><<<node_blocks, 256, 0, stream>>>(hbuf, asrc, adst, b3, row_start, src_sorted, h3, n);

    // ---- Pool + classify ----
    pool_seg<<<GG, 256, 0, stream>>>(h3, batch, pooled, cnt, n);
    classify_kernel<<<GG, 64, 0, stream>>>(pooled, cnt, fcw, fcb, (float*)d_out);
}

// Round 5
// 518.194 us; speedup vs baseline: 3.5566x; 1.0155x over previous
//
#include <hip/hip_runtime.h>
#include <hip/hip_bf16.h>

#define HH 8
#define CC 64
#define HC 512
#define GG 64
#define NCLS 10
#define F_IN 128
#define NEG_SLOPE 0.2f
#define EPS_ 1e-16f
#define MAXD 32

typedef float f32x4 __attribute__((ext_vector_type(4)));
typedef __bf16 bf16x8 __attribute__((ext_vector_type(8)));

__device__ __forceinline__ unsigned short f2bf(float f) {
    unsigned u = __builtin_bit_cast(unsigned, f);
    u += 0x7fffu + ((u >> 16) & 1u);          // RNE
    return (unsigned short)(u >> 16);
}
__device__ __forceinline__ float bf2f(unsigned short s) {
    unsigned u = ((unsigned)s) << 16;
    return __builtin_bit_cast(float, u);
}
__device__ __forceinline__ float bflo(unsigned u) {   // low bf16 of a packed u32
    return __builtin_bit_cast(float, u << 16);
}
__device__ __forceinline__ float bfhi(unsigned u) {   // high bf16
    return __builtin_bit_cast(float, u & 0xffff0000u);
}

// async global->LDS, 16B per lane. lds ptr must be wave-uniform base.
__device__ __forceinline__ void gload16(const unsigned short* g, unsigned short* l) {
    __builtin_amdgcn_global_load_lds(
        (const __attribute__((address_space(1))) unsigned int*)g,
        (__attribute__((address_space(3))) unsigned int*)l,
        16, 0, 0);
}

// ---------------------------------------------------------------------------
// CSR build
// ---------------------------------------------------------------------------
__global__ void hist_kernel(const int* __restrict__ ei, int* __restrict__ counts,
                            int E_, int EP_) {
    int e = blockIdx.x * 256 + threadIdx.x;
    if (e >= EP_) return;
    int d = (e < E_) ? ei[E_ + e] : (e - E_);
    atomicAdd(&counts[d], 1);
}

__global__ void scan1(const int* __restrict__ counts, int* __restrict__ partial,
                      int* __restrict__ bsum, int n) {
    __shared__ int buf[256];
    int idx = blockIdx.x * 256 + threadIdx.x;
    int v = (idx < n) ? counts[idx] : 0;
    buf[threadIdx.x] = v;
    __syncthreads();
    for (int off = 1; off < 256; off <<= 1) {
        int t = (threadIdx.x >= off) ? buf[threadIdx.x - off] : 0;
        __syncthreads();
        buf[threadIdx.x] += t;
        __syncthreads();
    }
    if (idx < n) partial[idx] = buf[threadIdx.x];
    if (threadIdx.x == 255) bsum[blockIdx.x] = buf[255];
}

__global__ void scan2(int* __restrict__ bsum, int nb) {
    __shared__ int buf[1024];
    int t = threadIdx.x;
    buf[t] = (t < nb) ? bsum[t] : 0;
    __syncthreads();
    for (int off = 1; off < 1024; off <<= 1) {
        int v = (t >= off) ? buf[t - off] : 0;
        __syncthreads();
        buf[t] += v;
        __syncthreads();
    }
    if (t < nb) bsum[t] = buf[t];
}

__global__ void scan3(const int* __restrict__ partial, const int* __restrict__ bsum,
                      int* __restrict__ row_start, int n) {
    int idx = blockIdx.x * 256 + threadIdx.x;
    if (idx >= n) return;
    int add = (blockIdx.x > 0) ? bsum[blockIdx.x - 1] : 0;
    row_start[idx + 1] = partial[idx] + add;
    if (idx == 0) row_start[0] = 0;
}

__global__ void scatter_kernel(const int* __restrict__ ei, const int* __restrict__ row_start,
                               int* __restrict__ cursor, int* __restrict__ perm,
                               int E_, int EP_) {
    int e = blockIdx.x * 256 + threadIdx.x;
    if (e >= EP_) return;
    int d = (e < E_) ? ei[E_ + e] : (e - E_);
    int pos = row_start[d] + atomicAdd(&cursor[d], 1);
    perm[pos] = e;
}

__global__ void build_src(const int* __restrict__ ei, const int* __restrict__ perm,
                          int* __restrict__ src_sorted, int E_, int EP_) {
    int i = blockIdx.x * 256 + threadIdx.x;
    if (i >= EP_) return;
    int e = perm[i];
    src_sorted[i] = (e < E_) ? ei[e] : (e - E_);
}

// ---------------------------------------------------------------------------
// fp32 -> bf16 conversions
// ---------------------------------------------------------------------------
__global__ void conv_bf16(const float* __restrict__ in, unsigned short* __restrict__ out,
                          int n4) {
    int i = blockIdx.x * 256 + threadIdx.x;
    if (i >= n4) return;
    float4 v = reinterpret_cast<const float4*>(in)[i];
    reinterpret_cast<ushort4*>(out)[i] =
        make_ushort4(f2bf(v.x), f2bf(v.y), f2bf(v.z), f2bf(v.w));
}

// W [K][Nc] fp32 -> WT [Nc][K] bf16
__global__ void transpose_w(const float* __restrict__ W, unsigned short* __restrict__ WT,
                            int K, int Nc) {
    __shared__ float t[32][33];
    int bx = blockIdx.x * 32;   // n
    int by = blockIdx.y * 32;   // k
    int x = threadIdx.x, y = threadIdx.y;
    for (int i = y; i < 32; i += 8)
        t[i][x] = W[(size_t)(by + i) * Nc + bx + x];   // t[k_local][n_local]
    __syncthreads();
    for (int i = y; i < 32; i += 8)
        WT[(size_t)(bx + i) * K + by + x] = f2bf(t[x][i]);
}

// ---------------------------------------------------------------------------
// bf16 MFMA GEMM: C[M,Nc](bf16) = A[M,K](bf16) @ BT[Nc,K](bf16)^T
// BM=BN=128, BK=64, 256 threads = 4 waves (2x2), each wave 64x64 out.
// ---------------------------------------------------------------------------
__global__ __launch_bounds__(256) void gemm_bf16(const unsigned short* __restrict__ A,
                                                 const unsigned short* __restrict__ BT,
                                                 unsigned short* __restrict__ C,
                                                 int M, int K, int Nc) {
    __shared__ __align__(16) unsigned short As[128 * 64];  // [m][k], 16 KB
    __shared__ __align__(16) unsigned short Bs[128 * 64];  // [n][k], 16 KB
    const int tid = threadIdx.x;
    const int lane = tid & 63;
    const int wave = tid >> 6;
    const int wr = wave >> 1, wc = wave & 1;
    const int brow = blockIdx.y * 128;
    const int bcol = blockIdx.x * 128;

    f32x4 acc[4][4];
#pragma unroll
    for (int i = 0; i < 4; ++i)
#pragma unroll
        for (int j = 0; j < 4; ++j) acc[i][j] = (f32x4)0.f;

    const int lrow = lane >> 3;        // 0..7 (row within 8-row chunk)
    const int lcol = (lane & 7) * 8;   // k element offset (8 bf16 = 16B)
    const int arow0 = brow + wave * 32 + lrow;
    const int brow0 = bcol + wave * 32 + lrow;

    const int kb = (lane >> 4) * 8;
    const int rowa = wr * 64 + (lane & 15);
    const int rowb = wc * 64 + (lane & 15);

    for (int k0 = 0; k0 < K; k0 += 64) {
#pragma unroll
        for (int it = 0; it < 4; ++it) {
            const int c = wave * 4 + it;
            int ar = arow0 + it * 8;
            if (ar >= M) ar = M - 1;                       // clamp: rows >=M never stored
            gload16(A + (size_t)ar * K + k0 + lcol, &As[c * 512]);
            int br = brow0 + it * 8;
            gload16(BT + (size_t)br * K + k0 + lcol, &Bs[c * 512]);
        }
        __syncthreads();
#pragma unroll
        for (int kk = 0; kk < 64; kk += 32) {
            bf16x8 a[4], b[4];
#pragma unroll
            for (int m = 0; m < 4; ++m)
                a[m] = *(const bf16x8*)&As[(rowa + m * 16) * 64 + kk + kb];
#pragma unroll
            for (int nn = 0; nn < 4; ++nn)
                b[nn] = *(const bf16x8*)&Bs[(rowb + nn * 16) * 64 + kk + kb];
#pragma unroll
            for (int m = 0; m < 4; ++m)
#pragma unroll
                for (int nn = 0; nn < 4; ++nn)
                    acc[m][nn] = __builtin_amdgcn_mfma_f32_16x16x32_bf16(
                        a[m], b[nn], acc[m][nn], 0, 0, 0);
        }
        __syncthreads();
    }

    const int r0 = brow + wr * 64 + (lane >> 4) * 4;
    const int c0 = bcol + wc * 64 + (lane & 15);
#pragma unroll
    for (int m = 0; m < 4; ++m)
#pragma unroll
        for (int j = 0; j < 4; ++j) {
            int r = r0 + m * 16 + j;
            if (r < M) {
#pragma unroll
                for (int nn = 0; nn < 4; ++nn)
                    C[(size_t)r * Nc + c0 + nn * 16] = f2bf(acc[m][nn][j]);
            }
        }
}

// ---------------------------------------------------------------------------
// Attention coefficients. Lane owns 8 contiguous channels (16B vector load);
// head group = 8 consecutive lanes; 3-level shfl_xor reduce within group.
// ---------------------------------------------------------------------------
__global__ __launch_bounds__(256) void attn_coef(const unsigned short* __restrict__ h,
                                                 const float* __restrict__ as,
                                                 const float* __restrict__ ad,
                                                 float* __restrict__ a_src,
                                                 float* __restrict__ a_dst, int n) {
    int node = blockIdx.x * 4 + (threadIdx.x >> 6);
    int lane = threadIdx.x & 63;
    if (node >= n) return;
    const unsigned short* hp = h + (size_t)node * HC + lane * 8;
    uint4 hv = *reinterpret_cast<const uint4*>(hp);
    float4 a0 = *reinterpret_cast<const float4*>(as + lane * 8);
    float4 a1 = *reinterpret_cast<const float4*>(as + lane * 8 + 4);
    float4 d0 = *reinterpret_cast<const float4*>(ad + lane * 8);
    float4 d1 = *reinterpret_cast<const float4*>(ad + lane * 8 + 4);
    float hf[8];
    hf[0] = bflo(hv.x); hf[1] = bfhi(hv.x);
    hf[2] = bflo(hv.y); hf[3] = bfhi(hv.y);
    hf[4] = bflo(hv.z); hf[5] = bfhi(hv.z);
    hf[6] = bflo(hv.w); hf[7] = bfhi(hv.w);
    float ps = hf[0]*a0.x + hf[1]*a0.y + hf[2]*a0.z + hf[3]*a0.w
             + hf[4]*a1.x + hf[5]*a1.y + hf[6]*a1.z + hf[7]*a1.w;
    float pd = hf[0]*d0.x + hf[1]*d0.y + hf[2]*d0.z + hf[3]*d0.w
             + hf[4]*d1.x + hf[5]*d1.y + hf[6]*d1.z + hf[7]*d1.w;
    ps += __shfl_xor(ps, 1); pd += __shfl_xor(pd, 1);
    ps += __shfl_xor(ps, 2); pd += __shfl_xor(pd, 2);
    ps += __shfl_xor(ps, 4); pd += __shfl_xor(pd, 4);
    if ((lane & 7) == 0) {
        a_src[node * 8 + (lane >> 3)] = ps;
        a_dst[node * 8 + (lane >> 3)] = pd;
    }
}

// ---------------------------------------------------------------------------
// Aggregation. One wave per node. Phase 1/2: softmax with (head=lane&7,
// eslot=lane>>3); alpha/exp AND src ids cached in per-wave LDS. Phase 3:
// lane owns channels lane*8..+7, edges processed in clamped batches of 4
// (4 independent 16B gathers in flight). Tail (deg>MAXD) recomputed scalar.
// MODE 0: out bf16 [n][512] relu(acc+bias512); MODE 1: out fp32 [n][64].
// ---------------------------------------------------------------------------
template <int MODE>
__global__ __launch_bounds__(256) void agg_kernel(const unsigned short* __restrict__ h,
                                                  const float* __restrict__ a_src,
                                                  const float* __restrict__ a_dst,
                                                  const float* __restrict__ bias,
                                                  const int* __restrict__ row_start,
                                                  const int* __restrict__ src_sorted,
                                                  void* __restrict__ outv, int n) {
    __shared__ float alds[4][MAXD][8];
    __shared__ int   slds[4][MAXD];
    int ws = threadIdx.x >> 6;
    int d = blockIdx.x * 4 + ws;
    int lane = threadIdx.x & 63;
    if (d >= n) return;
    int base = row_start[d];
    int end = row_start[d + 1];
    int deg = end - base;
    int head = lane & 7;
    int eslot = lane >> 3;
    float adh = a_dst[d * 8 + head];

    // phase 1: alpha + per-head max; cache alpha and src id in LDS
    float mx = -1e30f;
    for (int idx = eslot; idx < deg; idx += 8) {
        int s = src_sorted[base + idx];
        float al = a_src[s * 8 + head] + adh;
        al = (al > 0.f) ? al : NEG_SLOPE * al;
        if (idx < MAXD) {
            alds[ws][idx][head] = al;
            if (head == 0) slds[ws][idx] = s;
        }
        mx = fmaxf(mx, al);
    }
    mx = fmaxf(mx, __shfl_xor(mx, 8));
    mx = fmaxf(mx, __shfl_xor(mx, 16));
    mx = fmaxf(mx, __shfl_xor(mx, 32));

    // phase 2: exp + sum; overwrite LDS alpha with exp values
    float sm = 0.f;
    for (int idx = eslot; idx < deg; idx += 8) {
        float e;
        if (idx < MAXD) {
            float al = alds[ws][idx][head];
            e = __expf(al - mx);
            alds[ws][idx][head] = e;
        } else {
            int s = src_sorted[base + idx];
            float al = a_src[s * 8 + head] + adh;
            al = (al > 0.f) ? al : NEG_SLOPE * al;
            e = __expf(al - mx);
        }
        sm += e;
    }
    sm += __shfl_xor(sm, 8);
    sm += __shfl_xor(sm, 16);
    sm += __shfl_xor(sm, 32);
    float inv = 1.0f / (sm + EPS_);

    // ensure this wave's LDS writes are visible before cross-lane reads
    asm volatile("s_waitcnt lgkmcnt(0)" ::: "memory");
    __builtin_amdgcn_wave_barrier();

    // phase 3: accumulate. lane owns channels [lane*8, lane*8+8), head hd2
    int hd2 = lane >> 3;
    float mx2 = __shfl(mx, hd2);
    float inv2 = __shfl(inv, hd2);
    float adh2 = a_dst[d * 8 + hd2];
    const unsigned short* hl = h + lane * 8;

    float acc[8] = {};
    int mdeg = (deg < MAXD) ? deg : MAXD;
    for (int i = 0; i < mdeg; i += 4) {
        int i0 = i;
        int i1 = (i + 1 < mdeg) ? i + 1 : mdeg - 1;
        int i2 = (i + 2 < mdeg) ? i + 2 : mdeg - 1;
        int i3 = (i + 3 < mdeg) ? i + 3 : mdeg - 1;
        int s0 = slds[ws][i0], s1 = slds[ws][i1];
        int s2 = slds[ws][i2], s3 = slds[ws][i3];
        uint4 h0 = *reinterpret_cast<const uint4*>(hl + (size_t)s0 * HC);
        uint4 h1 = *reinterpret_cast<const uint4*>(hl + (size_t)s1 * HC);
        uint4 h2 = *reinterpret_cast<const uint4*>(hl + (size_t)s2 * HC);
        uint4 h3 = *reinterpret_cast<const uint4*>(hl + (size_t)s3 * HC);
        float w0 = alds[ws][i0][hd2] * inv2;
        float w1 = (i + 1 < mdeg) ? alds[ws][i1][hd2] * inv2 : 0.f;
        float w2 = (i + 2 < mdeg) ? alds[ws][i2][hd2] * inv2 : 0.f;
        float w3 = (i + 3 < mdeg) ? alds[ws][i3][hd2] * inv2 : 0.f;
        acc[0] += w0 * bflo(h0.x); acc[1] += w0 * bfhi(h0.x);
        acc[2] += w0 * bflo(h0.y); acc[3] += w0 * bfhi(h0.y);
        acc[4] += w0 * bflo(h0.z); acc[5] += w0 * bfhi(h0.z);
        acc[6] += w0 * bflo(h0.w); acc[7] += w0 * bfhi(h0.w);
        acc[0] += w1 * bflo(h1.x); acc[1] += w1 * bfhi(h1.x);
        acc[2] += w1 * bflo(h1.y); acc[3] += w1 * bfhi(h1.y);
        acc[4] += w1 * bflo(h1.z); acc[5] += w1 * bfhi(h1.z);
        acc[6] += w1 * bflo(h1.w); acc[7] += w1 * bfhi(h1.w);
        acc[0] += w2 * bflo(h2.x); acc[1] += w2 * bfhi(h2.x);
        acc[2] += w2 * bflo(h2.y); acc[3] += w2 * bfhi(h2.y);
        acc[4] += w2 * bflo(h2.z); acc[5] += w2 * bfhi(h2.z);
        acc[6] += w2 * bflo(h2.w); acc[7] += w2 * bfhi(h2.w);
        acc[0] += w3 * bflo(h3.x); acc[1] += w3 * bfhi(h3.x);
        acc[2] += w3 * bflo(h3.y); acc[3] += w3 * bfhi(h3.y);
        acc[4] += w3 * bflo(h3.z); acc[5] += w3 * bfhi(h3.z);
        acc[6] += w3 * bflo(h3.w); acc[7] += w3 * bfhi(h3.w);
    }
    // tail: deg > MAXD (rare) — recompute weight from a_src
    for (int i = base + MAXD; i < end; ++i) {
        int s = src_sorted[i];
        float al = a_src[s * 8 + hd2] + adh2;
        al = (al > 0.f) ? al : NEG_SLOPE * al;
        float w = __expf(al - mx2) * inv2;
        uint4 hv = *reinterpret_cast<const uint4*>(hl + (size_t)s * HC);
        acc[0] += w * bflo(hv.x); acc[1] += w * bfhi(hv.x);
        acc[2] += w * bflo(hv.y); acc[3] += w * bfhi(hv.y);
        acc[4] += w * bflo(hv.z); acc[5] += w * bfhi(hv.z);
        acc[6] += w * bflo(hv.w); acc[7] += w * bfhi(hv.w);
    }

    if (MODE == 0) {
        float4 b0 = *reinterpret_cast<const float4*>(bias + lane * 8);
        float4 b1 = *reinterpret_cast<const float4*>(bias + lane * 8 + 4);
        float v[8];
        v[0] = fmaxf(acc[0] + b0.x, 0.f); v[1] = fmaxf(acc[1] + b0.y, 0.f);
        v[2] = fmaxf(acc[2] + b0.z, 0.f); v[3] = fmaxf(acc[3] + b0.w, 0.f);
        v[4] = fmaxf(acc[4] + b1.x, 0.f); v[5] = fmaxf(acc[5] + b1.y, 0.f);
        v[6] = fmaxf(acc[6] + b1.z, 0.f); v[7] = fmaxf(acc[7] + b1.w, 0.f);
        uint4 o;
        o.x = (unsigned)f2bf(v[0]) | ((unsigned)f2bf(v[1]) << 16);
        o.y = (unsigned)f2bf(v[2]) | ((unsigned)f2bf(v[3]) << 16);
        o.z = (unsigned)f2bf(v[4]) | ((unsigned)f2bf(v[5]) << 16);
        o.w = (unsigned)f2bf(v[6]) | ((unsigned)f2bf(v[7]) << 16);
        *reinterpret_cast<uint4*>((unsigned short*)outv + (size_t)d * HC + lane * 8) = o;
    } else {
        // mean over heads: reduce across lanes with same (lane&7)
#pragma unroll
        for (int j = 0; j < 8; ++j) {
            acc[j] += __shfl_xor(acc[j], 8);
            acc[j] += __shfl_xor(acc[j], 16);
            acc[j] += __shfl_xor(acc[j], 32);
        }
        if (lane < 8) {
            float* op = (float*)outv + (size_t)d * 64 + lane * 8;
            float4 o0, o1;
            o0.x = fmaxf(acc[0] * 0.125f + bias[lane * 8 + 0], 0.f);
            o0.y = fmaxf(acc[1] * 0.125f + bias[lane * 8 + 1], 0.f);
            o0.z = fmaxf(acc[2] * 0.125f + bias[lane * 8 + 2], 0.f);
            o0.w = fmaxf(acc[3] * 0.125f + bias[lane * 8 + 3], 0.f);
            o1.x = fmaxf(acc[4] * 0.125f + bias[lane * 8 + 4], 0.f);
            o1.y = fmaxf(acc[5] * 0.125f + bias[lane * 8 + 5], 0.f);
            o1.z = fmaxf(acc[6] * 0.125f + bias[lane * 8 + 6], 0.f);
            o1.w = fmaxf(acc[7] * 0.125f + bias[lane * 8 + 7], 0.f);
            *reinterpret_cast<float4*>(op) = o0;
            *reinterpret_cast<float4*>(op + 4) = o1;
        }
    }
}

// ---------------------------------------------------------------------------
// Pool: batch is SORTED -> one block per graph, binary search boundaries,
// coalesced segment sum. No atomics.
// ---------------------------------------------------------------------------
__global__ __launch_bounds__(256) void pool_seg(const float* __restrict__ h3,
                                                const int* __restrict__ batch,
                                                float* __restrict__ pooled,
                                                int* __restrict__ cnt, int n) {
    int g = blockIdx.x;
    __shared__ int s_lo, s_hi;
    if (threadIdx.x == 0) {
        int lo = 0, hi = n;
        while (lo < hi) { int mid = (lo + hi) >> 1; if (batch[mid] < g) lo = mid + 1; else hi = mid; }
        s_lo = lo;
        int lo2 = lo, hi2 = n;
        while (lo2 < hi2) { int mid = (lo2 + hi2) >> 1; if (batch[mid] < g + 1) lo2 = mid + 1; else hi2 = mid; }
        s_hi = lo2;
    }
    __syncthreads();
    int lo = s_lo, hi = s_hi;
    int lane = threadIdx.x & 63;
    int slot = threadIdx.x >> 6;
    float acc = 0.f;
    for (int i = lo + slot; i < hi; i += 4)
        acc += h3[(size_t)i * 64 + lane];
    __shared__ float red[4][64];
    red[slot][lane] = acc;
    __syncthreads();
    if (slot == 0) {
        float v = red[0][lane] + red[1][lane] + red[2][lane] + red[3][lane];
        pooled[g * 64 + lane] = v;
        if (lane == 0) cnt[g] = hi - lo;
    }
}

__global__ void classify_kernel(const float* __restrict__ pooled,
                                const int* __restrict__ cnt,
                                const float* __restrict__ fcw,
                                const float* __restrict__ fcb,
                                float* __restrict__ out) {
    int g = blockIdx.x;
    int lane = threadIdx.x & 63;
    float c = (float)cnt[g];
    c = fmaxf(c, 1.0f);
    float p = pooled[g * 64 + lane] / c;
    float logit[NCLS];
#pragma unroll
    for (int j = 0; j < NCLS; ++j) {
        float t = p * fcw[lane * NCLS + j];
#pragma unroll
        for (int off = 1; off < 64; off <<= 1) t += __shfl_xor(t, off);
        logit[j] = t + fcb[j];
    }
    float m = logit[0];
#pragma unroll
    for (int j = 1; j < NCLS; ++j) m = fmaxf(m, logit[j]);
    float s = 0.f;
#pragma unroll
    for (int j = 0; j < NCLS; ++j) s += expf(logit[j] - m);
    float lse = logf(s);
    if (lane < NCLS) {
        float v = logit[0];
#pragma unroll
        for (int j = 1; j < NCLS; ++j)
            if (lane == j) v = logit[j];
        out[g * NCLS + lane] = v - m - lse;
    }
}

// ---------------------------------------------------------------------------
extern "C" void kernel_launch(void* const* d_in, const int* in_sizes, int n_in,
                              void* d_out, int out_size, void* d_ws, size_t ws_size,
                              hipStream_t stream) {
    const float* x    = (const float*)d_in[0];
    const int*   ei   = (const int*)d_in[1];
    const int*   batch = (const int*)d_in[2];
    const float* W1  = (const float*)d_in[3];
    const float* a1s = (const float*)d_in[4];
    const float* a1d = (const float*)d_in[5];
    const float* b1  = (const float*)d_in[6];
    const float* W2  = (const float*)d_in[7];
    const float* a2s = (const float*)d_in[8];
    const float* a2d = (const float*)d_in[9];
    const float* b2  = (const float*)d_in[10];
    const float* W3  = (const float*)d_in[11];
    const float* a3s = (const float*)d_in[12];
    const float* a3d = (const float*)d_in[13];
    const float* b3  = (const float*)d_in[14];
    const float* fcw = (const float*)d_in[15];
    const float* fcb = (const float*)d_in[16];

    const int n  = in_sizes[0] / F_IN;     // 50000
    const int E_ = in_sizes[1] / 2;        // 400000
    const int EP = E_ + n;                 // 450000

    // ---- workspace carve-up ----
    char* p = (char*)d_ws;
    unsigned short* xb   = (unsigned short*)p; p += (size_t)n * F_IN * 2;
    unsigned short* w1t  = (unsigned short*)p; p += (size_t)HC * F_IN * 2;
    unsigned short* w2t  = (unsigned short*)p; p += (size_t)HC * HC * 2;
    unsigned short* w3t  = (unsigned short*)p; p += (size_t)HC * HC * 2;
    unsigned short* hbuf = (unsigned short*)p; p += (size_t)n * HC * 2;
    unsigned short* buf2 = (unsigned short*)p; p += (size_t)n * HC * 2;
    float* asrc   = (float*)p; p += (size_t)n * 8 * 4;
    float* adst   = (float*)p; p += (size_t)n * 8 * 4;
    float* h3     = (float*)p; p += (size_t)n * 64 * 4;
    float* pooled = (float*)p; p += (size_t)GG * 64 * 4;
    int* cnt      = (int*)p;   p += (size_t)GG * 4;
    int* counts   = (int*)p;   p += (size_t)n * 4;
    int* row_start= (int*)p;   p += (size_t)(n + 1) * 4;
    int* perm     = (int*)p;   p += (size_t)EP * 4;
    int* src_sorted=(int*)p;   p += (size_t)EP * 4;
    int* partial  = (int*)p;   p += (size_t)n * 4;
    int* bsum     = (int*)p;   p += 1024 * 4;

    const int edge_blocks = (EP + 255) / 256;
    const int node_blocks = (n + 3) / 4;
    const int scan_blocks = (n + 255) / 256;

    // ---- CSR build ----
    hipMemsetAsync(counts, 0, (size_t)n * sizeof(int), stream);
    hist_kernel<<<edge_blocks, 256, 0, stream>>>(ei, counts, E_, EP);
    scan1<<<scan_blocks, 256, 0, stream>>>(counts, partial, bsum, n);
    scan2<<<1, 1024, 0, stream>>>(bsum, scan_blocks);
    scan3<<<scan_blocks, 256, 0, stream>>>(partial, bsum, row_start, n);
    hipMemsetAsync(counts, 0, (size_t)n * sizeof(int), stream);
    scatter_kernel<<<edge_blocks, 256, 0, stream>>>(ei, row_start, counts, perm, E_, EP);
    build_src<<<edge_blocks, 256, 0, stream>>>(ei, perm, src_sorted, E_, EP);

    // ---- conversions ----
    conv_bf16<<<((n * F_IN / 4) + 255) / 256, 256, 0, stream>>>(x, xb, n * F_IN / 4);
    transpose_w<<<dim3(HC / 32, F_IN / 32), dim3(32, 8), 0, stream>>>(W1, w1t, F_IN, HC);
    transpose_w<<<dim3(HC / 32, HC / 32), dim3(32, 8), 0, stream>>>(W2, w2t, HC, HC);
    transpose_w<<<dim3(HC / 32, HC / 32), dim3(32, 8), 0, stream>>>(W3, w3t, HC, HC);

    dim3 gemm_grid(HC / 128, (n + 127) / 128);

    // ---- Layer 1 ----
    gemm_bf16<<<gemm_grid, 256, 0, stream>>>(xb, w1t, hbuf, n, F_IN, HC);
    attn_coef<<<node_blocks, 256, 0, stream>>>(hbuf, a1s, a1d, asrc, adst, n);
    agg_kernel<0><<<node_blocks, 256, 0, stream>>>(hbuf, asrc, adst, b1, row_start, src_sorted, buf2, n);

    // ---- Layer 2 ----
    gemm_bf16<<<gemm_grid, 256, 0, stream>>>(buf2, w2t, hbuf, n, HC, HC);
    attn_coef<<<node_blocks, 256, 0, stream>>>(hbuf, a2s, a2d, asrc, adst, n);
    agg_kernel<0><<<node_blocks, 256, 0, stream>>>(hbuf, asrc, adst, b2, row_start, src_sorted, buf2, n);

    // ---- Layer 3 ----
    gemm_bf16<<<gemm_grid, 256, 0, stream>>>(buf2, w3t, hbuf, n, HC, HC);
    attn_coef<<<node_blocks, 256, 0, stream>>>(hbuf, a3s, a3d, asrc, adst, n);
    agg_kernel<1><<<node_blocks, 256, 0, stream>>>(hbuf, asrc, adst, b3, row_start, src_sorted, h3, n);

    // ---- Pool + classify ----
    pool_seg<<<GG, 256, 0, stream>>>(h3, batch, pooled, cnt, n);
    classify_kernel<<<GG, 64, 0, stream>>>(pooled, cnt, fcw, fcb, (float*)d_out);
}

// Round 6
// 510.399 us; speedup vs baseline: 3.6109x; 1.0153x over previous
//
#include <hip/hip_runtime.h>
#include <hip/hip_bf16.h>

#define HH 8
#define CC 64
#define HC 512
#define GG 64
#define NCLS 10
#define F_IN 128
#define NEG_SLOPE 0.2f
#define EPS_ 1e-16f
#define MAXD 32

typedef float f32x4 __attribute__((ext_vector_type(4)));
typedef __bf16 bf16x8 __attribute__((ext_vector_type(8)));

__device__ __forceinline__ unsigned short f2bf(float f) {
    unsigned u = __builtin_bit_cast(unsigned, f);
    u += 0x7fffu + ((u >> 16) & 1u);          // RNE
    return (unsigned short)(u >> 16);
}
__device__ __forceinline__ float bflo(unsigned u) {
    return __builtin_bit_cast(float, u << 16);
}
__device__ __forceinline__ float bfhi(unsigned u) {
    return __builtin_bit_cast(float, u & 0xffff0000u);
}

// async global->LDS, 16B per lane. lds ptr must be wave-uniform base.
__device__ __forceinline__ void gload16(const unsigned short* g, unsigned short* l) {
    __builtin_amdgcn_global_load_lds(
        (const __attribute__((address_space(1))) unsigned int*)g,
        (__attribute__((address_space(3))) unsigned int*)l,
        16, 0, 0);
}

// ---------------------------------------------------------------------------
// CSR build
// ---------------------------------------------------------------------------
__global__ void hist_kernel(const int* __restrict__ ei, int* __restrict__ counts,
                            int E_, int EP_) {
    int e = blockIdx.x * 256 + threadIdx.x;
    if (e >= EP_) return;
    int d = (e < E_) ? ei[E_ + e] : (e - E_);
    atomicAdd(&counts[d], 1);
}

__global__ void scan1(const int* __restrict__ counts, int* __restrict__ partial,
                      int* __restrict__ bsum, int n) {
    __shared__ int buf[256];
    int idx = blockIdx.x * 256 + threadIdx.x;
    int v = (idx < n) ? counts[idx] : 0;
    buf[threadIdx.x] = v;
    __syncthreads();
    for (int off = 1; off < 256; off <<= 1) {
        int t = (threadIdx.x >= off) ? buf[threadIdx.x - off] : 0;
        __syncthreads();
        buf[threadIdx.x] += t;
        __syncthreads();
    }
    if (idx < n) partial[idx] = buf[threadIdx.x];
    if (threadIdx.x == 255) bsum[blockIdx.x] = buf[255];
}

__global__ void scan2(int* __restrict__ bsum, int nb) {
    __shared__ int buf[1024];
    int t = threadIdx.x;
    buf[t] = (t < nb) ? bsum[t] : 0;
    __syncthreads();
    for (int off = 1; off < 1024; off <<= 1) {
        int v = (t >= off) ? buf[t - off] : 0;
        __syncthreads();
        buf[t] += v;
        __syncthreads();
    }
    if (t < nb) bsum[t] = buf[t];
}

// also zeroes counts so scatter can reuse it as a cursor (saves a memset)
__global__ void scan3(const int* __restrict__ partial, const int* __restrict__ bsum,
                      int* __restrict__ row_start, int* __restrict__ counts, int n) {
    int idx = blockIdx.x * 256 + threadIdx.x;
    if (idx >= n) return;
    int add = (blockIdx.x > 0) ? bsum[blockIdx.x - 1] : 0;
    row_start[idx + 1] = partial[idx] + add;
    counts[idx] = 0;
    if (idx == 0) row_start[0] = 0;
}

// writes src_sorted directly (no perm indirection)
__global__ void scatter_kernel(const int* __restrict__ ei, const int* __restrict__ row_start,
                               int* __restrict__ cursor, int* __restrict__ src_sorted,
                               int E_, int EP_) {
    int e = blockIdx.x * 256 + threadIdx.x;
    if (e >= EP_) return;
    int s, d;
    if (e < E_) { s = ei[e]; d = ei[E_ + e]; }
    else        { s = e - E_; d = e - E_; }
    int pos = row_start[d] + atomicAdd(&cursor[d], 1);
    src_sorted[pos] = s;
}

// ---------------------------------------------------------------------------
// fp32 -> bf16 conversions
// ---------------------------------------------------------------------------
__global__ void conv_bf16(const float* __restrict__ in, unsigned short* __restrict__ out,
                          int n4) {
    int i = blockIdx.x * 256 + threadIdx.x;
    if (i >= n4) return;
    float4 v = reinterpret_cast<const float4*>(in)[i];
    reinterpret_cast<ushort4*>(out)[i] =
        make_ushort4(f2bf(v.x), f2bf(v.y), f2bf(v.z), f2bf(v.w));
}

// W [K][Nc] fp32 -> WT [Nc][K] bf16
__global__ void transpose_w(const float* __restrict__ W, unsigned short* __restrict__ WT,
                            int K, int Nc) {
    __shared__ float t[32][33];
    int bx = blockIdx.x * 32;   // n
    int by = blockIdx.y * 32;   // k
    int x = threadIdx.x, y = threadIdx.y;
    for (int i = y; i < 32; i += 8)
        t[i][x] = W[(size_t)(by + i) * Nc + bx + x];
    __syncthreads();
    for (int i = y; i < 32; i += 8)
        WT[(size_t)(bx + i) * K + by + x] = f2bf(t[x][i]);
}

// ---------------------------------------------------------------------------
// bf16 MFMA GEMM + fused attention coefficients.
// C[M,512](bf16) = A[M,K] @ BT[512,K]^T; per wave: 64 rows x 64 cols = 1 head.
// Epilogue computes a_src[r,head] = sum_c h[r,c]*as[c], same for a_dst.
// 1-D grid with bijective XCD-chunked swizzle (nbx=4 cols fastest).
// ---------------------------------------------------------------------------
__global__ __launch_bounds__(256) void gemm_attn(const unsigned short* __restrict__ A,
                                                 const unsigned short* __restrict__ BT,
                                                 unsigned short* __restrict__ C,
                                                 const float* __restrict__ asw,
                                                 const float* __restrict__ adw,
                                                 float* __restrict__ a_src,
                                                 float* __restrict__ a_dst,
                                                 int M, int K) {
    __shared__ __align__(16) unsigned short As[128 * 64];  // [m][k], 16 KB
    __shared__ __align__(16) unsigned short Bs[128 * 64];  // [n][k], 16 KB

    // XCD-chunked bijective swizzle (8 XCDs)
    const int nwg = gridDim.x;
    const int f = blockIdx.x;
    const int q = nwg >> 3, r = nwg & 7;
    const int xcd = f & 7, rank = f >> 3;
    const int swz = (xcd < r ? xcd * (q + 1) : r * (q + 1) + (xcd - r) * q) + rank;
    const int bcol = (swz & 3) * 128;     // Nc=512 -> 4 col-blocks
    const int brow = (swz >> 2) * 128;

    const int tid = threadIdx.x;
    const int lane = tid & 63;
    const int wave = tid >> 6;
    const int wr = wave >> 1, wc = wave & 1;

    f32x4 acc[4][4];
#pragma unroll
    for (int i = 0; i < 4; ++i)
#pragma unroll
        for (int j = 0; j < 4; ++j) acc[i][j] = (f32x4)0.f;

    const int lrow = lane >> 3;
    const int lcol = (lane & 7) * 8;
    const int arow0 = brow + wave * 32 + lrow;
    const int brow0 = bcol + wave * 32 + lrow;

    const int kb = (lane >> 4) * 8;
    const int rowa = wr * 64 + (lane & 15);
    const int rowb = wc * 64 + (lane & 15);

    for (int k0 = 0; k0 < K; k0 += 64) {
#pragma unroll
        for (int it = 0; it < 4; ++it) {
            const int c = wave * 4 + it;
            int ar = arow0 + it * 8;
            if (ar >= M) ar = M - 1;                   // clamp: rows >=M never stored
            gload16(A + (size_t)ar * K + k0 + lcol, &As[c * 512]);
            int br = brow0 + it * 8;
            gload16(BT + (size_t)br * K + k0 + lcol, &Bs[c * 512]);
        }
        __syncthreads();
#pragma unroll
        for (int kk = 0; kk < 64; kk += 32) {
            bf16x8 a[4], b[4];
#pragma unroll
            for (int m = 0; m < 4; ++m)
                a[m] = *(const bf16x8*)&As[(rowa + m * 16) * 64 + kk + kb];
#pragma unroll
            for (int nn = 0; nn < 4; ++nn)
                b[nn] = *(const bf16x8*)&Bs[(rowb + nn * 16) * 64 + kk + kb];
#pragma unroll
            for (int m = 0; m < 4; ++m)
#pragma unroll
                for (int nn = 0; nn < 4; ++nn)
                    acc[m][nn] = __builtin_amdgcn_mfma_f32_16x16x32_bf16(
                        a[m], b[nn], acc[m][nn], 0, 0, 0);
        }
        __syncthreads();
    }

    const int r0 = brow + wr * 64 + (lane >> 4) * 4;
    const int c0 = bcol + wc * 64 + (lane & 15);

    // ---- C store (bf16 h) ----
#pragma unroll
    for (int m = 0; m < 4; ++m)
#pragma unroll
        for (int j = 0; j < 4; ++j) {
            int rr = r0 + m * 16 + j;
            if (rr < M) {
#pragma unroll
                for (int nn = 0; nn < 4; ++nn)
                    C[(size_t)rr * HC + c0 + nn * 16] = f2bf(acc[m][nn][j]);
            }
        }

    // ---- fused attention coefficients ----
    // wave covers cols [bcol+wc*64, +64) == exactly one head
    const int head = (bcol + wc * 64) >> 6;
    float asv[4], adv[4];
#pragma unroll
    for (int nn = 0; nn < 4; ++nn) {
        int c = c0 + nn * 16;
        asv[nn] = asw[c];
        adv[nn] = adw[c];
    }
    float psrc[4][4], pdst[4][4];
#pragma unroll
    for (int m = 0; m < 4; ++m)
#pragma unroll
        for (int j = 0; j < 4; ++j) {
            float ps = 0.f, pd = 0.f;
#pragma unroll
            for (int nn = 0; nn < 4; ++nn) {
                float hv = acc[m][nn][j];
                ps += hv * asv[nn];
                pd += hv * adv[nn];
            }
            psrc[m][j] = ps;
            pdst[m][j] = pd;
        }
#pragma unroll
    for (int m = 0; m < 4; ++m)
#pragma unroll
        for (int j = 0; j < 4; ++j) {
#pragma unroll
            for (int mask = 1; mask < 16; mask <<= 1) {
                psrc[m][j] += __shfl_xor(psrc[m][j], mask);
                pdst[m][j] += __shfl_xor(pdst[m][j], mask);
            }
        }
    if ((lane & 15) == 0) {
#pragma unroll
        for (int m = 0; m < 4; ++m)
#pragma unroll
            for (int j = 0; j < 4; ++j) {
                int rr = r0 + m * 16 + j;
                if (rr < M) {
                    a_src[rr * 8 + head] = psrc[m][j];
                    a_dst[rr * 8 + head] = pdst[m][j];
                }
            }
    }
}

// ---------------------------------------------------------------------------
// Aggregation (unchanged from round 5 — at gather roofline).
// ---------------------------------------------------------------------------
template <int MODE>
__global__ __launch_bounds__(256) void agg_kernel(const unsigned short* __restrict__ h,
                                                  const float* __restrict__ a_src,
                                                  const float* __restrict__ a_dst,
                                                  const float* __restrict__ bias,
                                                  const int* __restrict__ row_start,
                                                  const int* __restrict__ src_sorted,
                                                  void* __restrict__ outv, int n) {
    __shared__ float alds[4][MAXD][8];
    __shared__ int   slds[4][MAXD];
    int ws = threadIdx.x >> 6;
    int d = blockIdx.x * 4 + ws;
    int lane = threadIdx.x & 63;
    if (d >= n) return;
    int base = row_start[d];
    int end = row_start[d + 1];
    int deg = end - base;
    int head = lane & 7;
    int eslot = lane >> 3;
    float adh = a_dst[d * 8 + head];

    float mx = -1e30f;
    for (int idx = eslot; idx < deg; idx += 8) {
        int s = src_sorted[base + idx];
        float al = a_src[s * 8 + head] + adh;
        al = (al > 0.f) ? al : NEG_SLOPE * al;
        if (idx < MAXD) {
            alds[ws][idx][head] = al;
            if (head == 0) slds[ws][idx] = s;
        }
        mx = fmaxf(mx, al);
    }
    mx = fmaxf(mx, __shfl_xor(mx, 8));
    mx = fmaxf(mx, __shfl_xor(mx, 16));
    mx = fmaxf(mx, __shfl_xor(mx, 32));

    float sm = 0.f;
    for (int idx = eslot; idx < deg; idx += 8) {
        float e;
        if (idx < MAXD) {
            float al = alds[ws][idx][head];
            e = __expf(al - mx);
            alds[ws][idx][head] = e;
        } else {
            int s = src_sorted[base + idx];
            float al = a_src[s * 8 + head] + adh;
            al = (al > 0.f) ? al : NEG_SLOPE * al;
            e = __expf(al - mx);
        }
        sm += e;
    }
    sm += __shfl_xor(sm, 8);
    sm += __shfl_xor(sm, 16);
    sm += __shfl_xor(sm, 32);
    float inv = 1.0f / (sm + EPS_);

    asm volatile("s_waitcnt lgkmcnt(0)" ::: "memory");
    __builtin_amdgcn_wave_barrier();

    int hd2 = lane >> 3;
    float mx2 = __shfl(mx, hd2);
    float inv2 = __shfl(inv, hd2);
    float adh2 = a_dst[d * 8 + hd2];
    const unsigned short* hl = h + lane * 8;

    float acc[8] = {};
    int mdeg = (deg < MAXD) ? deg : MAXD;
    for (int i = 0; i < mdeg; i += 4) {
        int i0 = i;
        int i1 = (i + 1 < mdeg) ? i + 1 : mdeg - 1;
        int i2 = (i + 2 < mdeg) ? i + 2 : mdeg - 1;
        int i3 = (i + 3 < mdeg) ? i + 3 : mdeg - 1;
        int s0 = slds[ws][i0], s1 = slds[ws][i1];
        int s2 = slds[ws][i2], s3 = slds[ws][i3];
        uint4 h0 = *reinterpret_cast<const uint4*>(hl + (size_t)s0 * HC);
        uint4 h1 = *reinterpret_cast<const uint4*>(hl + (size_t)s1 * HC);
        uint4 h2 = *reinterpret_cast<const uint4*>(hl + (size_t)s2 * HC);
        uint4 h3 = *reinterpret_cast<const uint4*>(hl + (size_t)s3 * HC);
        float w0 = alds[ws][i0][hd2] * inv2;
        float w1 = (i + 1 < mdeg) ? alds[ws][i1][hd2] * inv2 : 0.f;
        float w2 = (i + 2 < mdeg) ? alds[ws][i2][hd2] * inv2 : 0.f;
        float w3 = (i + 3 < mdeg) ? alds[ws][i3][hd2] * inv2 : 0.f;
        acc[0] += w0 * bflo(h0.x); acc[1] += w0 * bfhi(h0.x);
        acc[2] += w0 * bflo(h0.y); acc[3] += w0 * bfhi(h0.y);
        acc[4] += w0 * bflo(h0.z); acc[5] += w0 * bfhi(h0.z);
        acc[6] += w0 * bflo(h0.w); acc[7] += w0 * bfhi(h0.w);
        acc[0] += w1 * bflo(h1.x); acc[1] += w1 * bfhi(h1.x);
        acc[2] += w1 * bflo(h1.y); acc[3] += w1 * bfhi(h1.y);
        acc[4] += w1 * bflo(h1.z); acc[5] += w1 * bfhi(h1.z);
        acc[6] += w1 * bflo(h1.w); acc[7] += w1 * bfhi(h1.w);
        acc[0] += w2 * bflo(h2.x); acc[1] += w2 * bfhi(h2.x);
        acc[2] += w2 * bflo(h2.y); acc[3] += w2 * bfhi(h2.y);
        acc[4] += w2 * bflo(h2.z); acc[5] += w2 * bfhi(h2.z);
        acc[6] += w2 * bflo(h2.w); acc[7] += w2 * bfhi(h2.w);
        acc[0] += w3 * bflo(h3.x); acc[1] += w3 * bfhi(h3.x);
        acc[2] += w3 * bflo(h3.y); acc[3] += w3 * bfhi(h3.y);
        acc[4] += w3 * bflo(h3.z); acc[5] += w3 * bfhi(h3.z);
        acc[6] += w3 * bflo(h3.w); acc[7] += w3 * bfhi(h3.w);
    }
    for (int i = base + MAXD; i < end; ++i) {
        int s = src_sorted[i];
        float al = a_src[s * 8 + hd2] + adh2;
        al = (al > 0.f) ? al : NEG_SLOPE * al;
        float w = __expf(al - mx2) * inv2;
        uint4 hv = *reinterpret_cast<const uint4*>(hl + (size_t)s * HC);
        acc[0] += w * bflo(hv.x); acc[1] += w * bfhi(hv.x);
        acc[2] += w * bflo(hv.y); acc[3] += w * bfhi(hv.y);
        acc[4] += w * bflo(hv.z); acc[5] += w * bfhi(hv.z);
        acc[6] += w * bflo(hv.w); acc[7] += w * bfhi(hv.w);
    }

    if (MODE == 0) {
        float4 b0 = *reinterpret_cast<const float4*>(bias + lane * 8);
        float4 b1 = *reinterpret_cast<const float4*>(bias + lane * 8 + 4);
        float v[8];
        v[0] = fmaxf(acc[0] + b0.x, 0.f); v[1] = fmaxf(acc[1] + b0.y, 0.f);
        v[2] = fmaxf(acc[2] + b0.z, 0.f); v[3] = fmaxf(acc[3] + b0.w, 0.f);
        v[4] = fmaxf(acc[4] + b1.x, 0.f); v[5] = fmaxf(acc[5] + b1.y, 0.f);
        v[6] = fmaxf(acc[6] + b1.z, 0.f); v[7] = fmaxf(acc[7] + b1.w, 0.f);
        uint4 o;
        o.x = (unsigned)f2bf(v[0]) | ((unsigned)f2bf(v[1]) << 16);
        o.y = (unsigned)f2bf(v[2]) | ((unsigned)f2bf(v[3]) << 16);
        o.z = (unsigned)f2bf(v[4]) | ((unsigned)f2bf(v[5]) << 16);
        o.w = (unsigned)f2bf(v[6]) | ((unsigned)f2bf(v[7]) << 16);
        *reinterpret_cast<uint4*>((unsigned short*)outv + (size_t)d * HC + lane * 8) = o;
    } else {
#pragma unroll
        for (int j = 0; j < 8; ++j) {
            acc[j] += __shfl_xor(acc[j], 8);
            acc[j] += __shfl_xor(acc[j], 16);
            acc[j] += __shfl_xor(acc[j], 32);
        }
        if (lane < 8) {
            float* op = (float*)outv + (size_t)d * 64 + lane * 8;
            float4 o0, o1;
            o0.x = fmaxf(acc[0] * 0.125f + bias[lane * 8 + 0], 0.f);
            o0.y = fmaxf(acc[1] * 0.125f + bias[lane * 8 + 1], 0.f);
            o0.z = fmaxf(acc[2] * 0.125f + bias[lane * 8 + 2], 0.f);
            o0.w = fmaxf(acc[3] * 0.125f + bias[lane * 8 + 3], 0.f);
            o1.x = fmaxf(acc[4] * 0.125f + bias[lane * 8 + 4], 0.f);
            o1.y = fmaxf(acc[5] * 0.125f + bias[lane * 8 + 5], 0.f);
            o1.z = fmaxf(acc[6] * 0.125f + bias[lane * 8 + 6], 0.f);
            o1.w = fmaxf(acc[7] * 0.125f + bias[lane * 8 + 7], 0.f);
            *reinterpret_cast<float4*>(op) = o0;
            *reinterpret_cast<float4*>(op + 4) = o1;
        }
    }
}

// ---------------------------------------------------------------------------
// Pool + classify fused: one block per graph.
// ---------------------------------------------------------------------------
__global__ __launch_bounds__(256) void pool_classify(const float* __restrict__ h3,
                                                     const int* __restrict__ batch,
                                                     const float* __restrict__ fcw,
                                                     const float* __restrict__ fcb,
                                                     float* __restrict__ out, int n) {
    int g = blockIdx.x;
    __shared__ int s_lo, s_hi;
    if (threadIdx.x == 0) {
        int lo = 0, hi = n;
        while (lo < hi) { int mid = (lo + hi) >> 1; if (batch[mid] < g) lo = mid + 1; else hi = mid; }
        s_lo = lo;
        int lo2 = lo, hi2 = n;
        while (lo2 < hi2) { int mid = (lo2 + hi2) >> 1; if (batch[mid] < g + 1) lo2 = mid + 1; else hi2 = mid; }
        s_hi = lo2;
    }
    __syncthreads();
    int lo = s_lo, hi = s_hi;
    int lane = threadIdx.x & 63;
    int slot = threadIdx.x >> 6;
    float acc = 0.f;
    for (int i = lo + slot; i < hi; i += 4)
        acc += h3[(size_t)i * 64 + lane];
    __shared__ float red[4][64];
    red[slot][lane] = acc;
    __syncthreads();
    if (slot == 0) {
        float v = red[0][lane] + red[1][lane] + red[2][lane] + red[3][lane];
        float c = (float)(hi - lo);
        c = fmaxf(c, 1.0f);
        float p = v / c;
        float logit[NCLS];
#pragma unroll
        for (int j = 0; j < NCLS; ++j) {
            float t = p * fcw[lane * NCLS + j];
#pragma unroll
            for (int off = 1; off < 64; off <<= 1) t += __shfl_xor(t, off);
            logit[j] = t + fcb[j];
        }
        float m = logit[0];
#pragma unroll
        for (int j = 1; j < NCLS; ++j) m = fmaxf(m, logit[j]);
        float s = 0.f;
#pragma unroll
        for (int j = 0; j < NCLS; ++j) s += expf(logit[j] - m);
        float lse = logf(s);
        if (lane < NCLS) {
            float vv = logit[0];
#pragma unroll
            for (int j = 1; j < NCLS; ++j)
                if (lane == j) vv = logit[j];
            out[g * NCLS + lane] = vv - m - lse;
        }
    }
}

// ---------------------------------------------------------------------------
extern "C" void kernel_launch(void* const* d_in, const int* in_sizes, int n_in,
                              void* d_out, int out_size, void* d_ws, size_t ws_size,
                              hipStream_t stream) {
    const float* x    = (const float*)d_in[0];
    const int*   ei   = (const int*)d_in[1];
    const int*   batch = (const int*)d_in[2];
    const float* W1  = (const float*)d_in[3];
    const float* a1s = (const float*)d_in[4];
    const float* a1d = (const float*)d_in[5];
    const float* b1  = (const float*)d_in[6];
    const float* W2  = (const float*)d_in[7];
    const float* a2s = (const float*)d_in[8];
    const float* a2d = (const float*)d_in[9];
    const float* b2  = (const float*)d_in[10];
    const float* W3  = (const float*)d_in[11];
    const float* a3s = (const float*)d_in[12];
    const float* a3d = (const float*)d_in[13];
    const float* b3  = (const float*)d_in[14];
    const float* fcw = (const float*)d_in[15];
    const float* fcb = (const float*)d_in[16];

    const int n  = in_sizes[0] / F_IN;     // 50000
    const int E_ = in_sizes[1] / 2;        // 400000
    const int EP = E_ + n;                 // 450000

    // ---- workspace carve-up ----
    char* p = (char*)d_ws;
    unsigned short* xb   = (unsigned short*)p; p += (size_t)n * F_IN * 2;
    unsigned short* w1t  = (unsigned short*)p; p += (size_t)HC * F_IN * 2;
    unsigned short* w2t  = (unsigned short*)p; p += (size_t)HC * HC * 2;
    unsigned short* w3t  = (unsigned short*)p; p += (size_t)HC * HC * 2;
    unsigned short* hbuf = (unsigned short*)p; p += (size_t)n * HC * 2;
    unsigned short* buf2 = (unsigned short*)p; p += (size_t)n * HC * 2;
    float* asrc   = (float*)p; p += (size_t)n * 8 * 4;
    float* adst   = (float*)p; p += (size_t)n * 8 * 4;
    float* h3     = (float*)p; p += (size_t)n * 64 * 4;
    int* counts   = (int*)p;   p += (size_t)n * 4;
    int* row_start= (int*)p;   p += (size_t)(n + 1) * 4;
    int* src_sorted=(int*)p;   p += (size_t)EP * 4;
    int* partial  = (int*)p;   p += (size_t)n * 4;
    int* bsum     = (int*)p;   p += 1024 * 4;

    const int edge_blocks = (EP + 255) / 256;
    const int node_blocks = (n + 3) / 4;
    const int scan_blocks = (n + 255) / 256;

    // ---- CSR build ----
    hipMemsetAsync(counts, 0, (size_t)n * sizeof(int), stream);
    hist_kernel<<<edge_blocks, 256, 0, stream>>>(ei, counts, E_, EP);
    scan1<<<scan_blocks, 256, 0, stream>>>(counts, partial, bsum, n);
    scan2<<<1, 1024, 0, stream>>>(bsum, scan_blocks);
    scan3<<<scan_blocks, 256, 0, stream>>>(partial, bsum, row_start, counts, n);
    scatter_kernel<<<edge_blocks, 256, 0, stream>>>(ei, row_start, counts, src_sorted, E_, EP);

    // ---- conversions ----
    conv_bf16<<<((n * F_IN / 4) + 255) / 256, 256, 0, stream>>>(x, xb, n * F_IN / 4);
    transpose_w<<<dim3(HC / 32, F_IN / 32), dim3(32, 8), 0, stream>>>(W1, w1t, F_IN, HC);
    transpose_w<<<dim3(HC / 32, HC / 32), dim3(32, 8), 0, stream>>>(W2, w2t, HC, HC);
    transpose_w<<<dim3(HC / 32, HC / 32), dim3(32, 8), 0, stream>>>(W3, w3t, HC, HC);

    const int nby = (n + 127) / 128;
    const int nwg = 4 * nby;          // 4 col-blocks x row-blocks, 1-D swizzled grid

    // ---- Layer 1 ----
    gemm_attn<<<nwg, 256, 0, stream>>>(xb, w1t, hbuf, a1s, a1d, asrc, adst, n, F_IN);
    agg_kernel<0><<<node_blocks, 256, 0, stream>>>(hbuf, asrc, adst, b1, row_start, src_sorted, buf2, n);

    // ---- Layer 2 ----
    gemm_attn<<<nwg, 256, 0, stream>>>(buf2, w2t, hbuf, a2s, a2d, asrc, adst, n, HC);
    agg_kernel<0><<<node_blocks, 256, 0, stream>>>(hbuf, asrc, adst, b2, row_start, src_sorted, buf2, n);

    // ---- Layer 3 ----
    gemm_attn<<<nwg, 256, 0, stream>>>(buf2, w3t, hbuf, a3s, a3d, asrc, adst, n, HC);
    agg_kernel<1><<<node_blocks, 256, 0, stream>>>(hbuf, asrc, adst, b3, row_start, src_sorted, h3, n);

    // ---- Pool + classify (fused) ----
    pool_classify<<<GG, 256, 0, stream>>>(h3, batch, fcw, fcb, (float*)d_out, n);
}

// Round 8
// 424.438 us; speedup vs baseline: 4.3423x; 1.2025x over previous
//
#include <hip/hip_runtime.h>
#include <hip/hip_bf16.h>

#define HH 8
#define CC 64
#define HC 512
#define GG 64
#define NCLS 10
#define F_IN 128
#define NEG_SLOPE 0.2f
#define EPS_ 1e-16f
#define MAXD 32

typedef float f32x4 __attribute__((ext_vector_type(4)));
typedef __bf16 bf16x8 __attribute__((ext_vector_type(8)));

__device__ __forceinline__ unsigned short f2bf(float f) {
    unsigned u = __builtin_bit_cast(unsigned, f);
    u += 0x7fffu + ((u >> 16) & 1u);          // RNE
    return (unsigned short)(u >> 16);
}
__device__ __forceinline__ float bflo(unsigned u) {
    return __builtin_bit_cast(float, u << 16);
}
__device__ __forceinline__ float bfhi(unsigned u) {
    return __builtin_bit_cast(float, u & 0xffff0000u);
}
// fp8 e4m3 (OCP on gfx950) helpers — hardware cvt. sel must be ICE -> template.
__device__ __forceinline__ unsigned char f2fp8(float f) {
    unsigned pk = __builtin_amdgcn_cvt_pk_fp8_f32(f, f, 0u, false);
    return (unsigned char)(pk & 0xffu);
}
template <int SEL>
__device__ __forceinline__ float fp82f(unsigned w) {
    return __builtin_amdgcn_cvt_f32_fp8(w, SEL);
}
// dequant 8 fp8 channels (uint2) with weight w into acc[0..7]
#define ACC_FP8(hv, w)                                           \
    acc[0] += (w) * fp82f<0>(hv.x); acc[1] += (w) * fp82f<1>(hv.x); \
    acc[2] += (w) * fp82f<2>(hv.x); acc[3] += (w) * fp82f<3>(hv.x); \
    acc[4] += (w) * fp82f<0>(hv.y); acc[5] += (w) * fp82f<1>(hv.y); \
    acc[6] += (w) * fp82f<2>(hv.y); acc[7] += (w) * fp82f<3>(hv.y);

// async global->LDS, 16B per lane. lds ptr must be wave-uniform base.
__device__ __forceinline__ void gload16(const unsigned short* g, unsigned short* l) {
    __builtin_amdgcn_global_load_lds(
        (const __attribute__((address_space(1))) unsigned int*)g,
        (__attribute__((address_space(3))) unsigned int*)l,
        16, 0, 0);
}

// ---------------------------------------------------------------------------
// CSR build
// ---------------------------------------------------------------------------
__global__ void hist_kernel(const int* __restrict__ ei, int* __restrict__ counts,
                            int E_, int EP_) {
    int e = blockIdx.x * 256 + threadIdx.x;
    if (e >= EP_) return;
    int d = (e < E_) ? ei[E_ + e] : (e - E_);
    atomicAdd(&counts[d], 1);
}

__global__ void scan1(const int* __restrict__ counts, int* __restrict__ partial,
                      int* __restrict__ bsum, int n) {
    __shared__ int buf[256];
    int idx = blockIdx.x * 256 + threadIdx.x;
    int v = (idx < n) ? counts[idx] : 0;
    buf[threadIdx.x] = v;
    __syncthreads();
    for (int off = 1; off < 256; off <<= 1) {
        int t = (threadIdx.x >= off) ? buf[threadIdx.x - off] : 0;
        __syncthreads();
        buf[threadIdx.x] += t;
        __syncthreads();
    }
    if (idx < n) partial[idx] = buf[threadIdx.x];
    if (threadIdx.x == 255) bsum[blockIdx.x] = buf[255];
}

__global__ void scan2(int* __restrict__ bsum, int nb) {
    __shared__ int buf[1024];
    int t = threadIdx.x;
    buf[t] = (t < nb) ? bsum[t] : 0;
    __syncthreads();
    for (int off = 1; off < 1024; off <<= 1) {
        int v = (t >= off) ? buf[t - off] : 0;
        __syncthreads();
        buf[t] += v;
        __syncthreads();
    }
    if (t < nb) bsum[t] = buf[t];
}

// also zeroes counts so scatter can reuse it as a cursor (saves a memset)
__global__ void scan3(const int* __restrict__ partial, const int* __restrict__ bsum,
                      int* __restrict__ row_start, int* __restrict__ counts, int n) {
    int idx = blockIdx.x * 256 + threadIdx.x;
    if (idx >= n) return;
    int add = (blockIdx.x > 0) ? bsum[blockIdx.x - 1] : 0;
    row_start[idx + 1] = partial[idx] + add;
    counts[idx] = 0;
    if (idx == 0) row_start[0] = 0;
}

// writes src_sorted directly (no perm indirection)
__global__ void scatter_kernel(const int* __restrict__ ei, const int* __restrict__ row_start,
                               int* __restrict__ cursor, int* __restrict__ src_sorted,
                               int E_, int EP_) {
    int e = blockIdx.x * 256 + threadIdx.x;
    if (e >= EP_) return;
    int s, d;
    if (e < E_) { s = ei[e]; d = ei[E_ + e]; }
    else        { s = e - E_; d = e - E_; }
    int pos = row_start[d] + atomicAdd(&cursor[d], 1);
    src_sorted[pos] = s;
}

// ---------------------------------------------------------------------------
// fp32 -> bf16 conversions
// ---------------------------------------------------------------------------
__global__ void conv_bf16(const float* __restrict__ in, unsigned short* __restrict__ out,
                          int n4) {
    int i = blockIdx.x * 256 + threadIdx.x;
    if (i >= n4) return;
    float4 v = reinterpret_cast<const float4*>(in)[i];
    reinterpret_cast<ushort4*>(out)[i] =
        make_ushort4(f2bf(v.x), f2bf(v.y), f2bf(v.z), f2bf(v.w));
}

// W [K][Nc] fp32 -> WT [Nc][K] bf16
__global__ void transpose_w(const float* __restrict__ W, unsigned short* __restrict__ WT,
                            int K, int Nc) {
    __shared__ float t[32][33];
    int bx = blockIdx.x * 32;   // n
    int by = blockIdx.y * 32;   // k
    int x = threadIdx.x, y = threadIdx.y;
    for (int i = y; i < 32; i += 8)
        t[i][x] = W[(size_t)(by + i) * Nc + bx + x];
    __syncthreads();
    for (int i = y; i < 32; i += 8)
        WT[(size_t)(bx + i) * K + by + x] = f2bf(t[x][i]);
}

// ---------------------------------------------------------------------------
// bf16 MFMA GEMM + fused attention coefficients. h output stored as FP8 e4m3
// (only consumer is the agg gather; alpha computed here from fp32 acc).
// ---------------------------------------------------------------------------
__global__ __launch_bounds__(256) void gemm_attn(const unsigned short* __restrict__ A,
                                                 const unsigned short* __restrict__ BT,
                                                 unsigned char* __restrict__ C,
                                                 const float* __restrict__ asw,
                                                 const float* __restrict__ adw,
                                                 float* __restrict__ a_src,
                                                 float* __restrict__ a_dst,
                                                 int M, int K) {
    __shared__ __align__(16) unsigned short As[128 * 64];  // [m][k], 16 KB
    __shared__ __align__(16) unsigned short Bs[128 * 64];  // [n][k], 16 KB

    // XCD-chunked bijective swizzle (8 XCDs)
    const int nwg = gridDim.x;
    const int f = blockIdx.x;
    const int q = nwg >> 3, r = nwg & 7;
    const int xcd = f & 7, rank = f >> 3;
    const int swz = (xcd < r ? xcd * (q + 1) : r * (q + 1) + (xcd - r) * q) + rank;
    const int bcol = (swz & 3) * 128;     // Nc=512 -> 4 col-blocks
    const int brow = (swz >> 2) * 128;

    const int tid = threadIdx.x;
    const int lane = tid & 63;
    const int wave = tid >> 6;
    const int wr = wave >> 1, wc = wave & 1;

    f32x4 acc[4][4];
#pragma unroll
    for (int i = 0; i < 4; ++i)
#pragma unroll
        for (int j = 0; j < 4; ++j) acc[i][j] = (f32x4)0.f;

    const int lrow = lane >> 3;
    const int lcol = (lane & 7) * 8;
    const int arow0 = brow + wave * 32 + lrow;
    const int brow0 = bcol + wave * 32 + lrow;

    const int kb = (lane >> 4) * 8;
    const int rowa = wr * 64 + (lane & 15);
    const int rowb = wc * 64 + (lane & 15);

    for (int k0 = 0; k0 < K; k0 += 64) {
#pragma unroll
        for (int it = 0; it < 4; ++it) {
            const int c = wave * 4 + it;
            int ar = arow0 + it * 8;
            if (ar >= M) ar = M - 1;                   // clamp: rows >=M never stored
            gload16(A + (size_t)ar * K + k0 + lcol, &As[c * 512]);
            int br = brow0 + it * 8;
            gload16(BT + (size_t)br * K + k0 + lcol, &Bs[c * 512]);
        }
        __syncthreads();
#pragma unroll
        for (int kk = 0; kk < 64; kk += 32) {
            bf16x8 a[4], b[4];
#pragma unroll
            for (int m = 0; m < 4; ++m)
                a[m] = *(const bf16x8*)&As[(rowa + m * 16) * 64 + kk + kb];
#pragma unroll
            for (int nn = 0; nn < 4; ++nn)
                b[nn] = *(const bf16x8*)&Bs[(rowb + nn * 16) * 64 + kk + kb];
#pragma unroll
            for (int m = 0; m < 4; ++m)
#pragma unroll
                for (int nn = 0; nn < 4; ++nn)
                    acc[m][nn] = __builtin_amdgcn_mfma_f32_16x16x32_bf16(
                        a[m], b[nn], acc[m][nn], 0, 0, 0);
        }
        __syncthreads();
    }

    const int r0 = brow + wr * 64 + (lane >> 4) * 4;
    const int c0 = bcol + wc * 64 + (lane & 15);

    // ---- C store (fp8 h) ----
#pragma unroll
    for (int m = 0; m < 4; ++m)
#pragma unroll
        for (int j = 0; j < 4; ++j) {
            int rr = r0 + m * 16 + j;
            if (rr < M) {
#pragma unroll
                for (int nn = 0; nn < 4; ++nn)
                    C[(size_t)rr * HC + c0 + nn * 16] = f2fp8(acc[m][nn][j]);
            }
        }

    // ---- fused attention coefficients (from fp32 acc) ----
    const int head = (bcol + wc * 64) >> 6;
    float asv[4], adv[4];
#pragma unroll
    for (int nn = 0; nn < 4; ++nn) {
        int c = c0 + nn * 16;
        asv[nn] = asw[c];
        adv[nn] = adw[c];
    }
    float psrc[4][4], pdst[4][4];
#pragma unroll
    for (int m = 0; m < 4; ++m)
#pragma unroll
        for (int j = 0; j < 4; ++j) {
            float ps = 0.f, pd = 0.f;
#pragma unroll
            for (int nn = 0; nn < 4; ++nn) {
                float hv = acc[m][nn][j];
                ps += hv * asv[nn];
                pd += hv * adv[nn];
            }
            psrc[m][j] = ps;
            pdst[m][j] = pd;
        }
#pragma unroll
    for (int m = 0; m < 4; ++m)
#pragma unroll
        for (int j = 0; j < 4; ++j) {
#pragma unroll
            for (int mask = 1; mask < 16; mask <<= 1) {
                psrc[m][j] += __shfl_xor(psrc[m][j], mask);
                pdst[m][j] += __shfl_xor(pdst[m][j], mask);
            }
        }
    if ((lane & 15) == 0) {
#pragma unroll
        for (int m = 0; m < 4; ++m)
#pragma unroll
            for (int j = 0; j < 4; ++j) {
                int rr = r0 + m * 16 + j;
                if (rr < M) {
                    a_src[rr * 8 + head] = psrc[m][j];
                    a_dst[rr * 8 + head] = pdst[m][j];
                }
            }
    }
}

// ---------------------------------------------------------------------------
// Aggregation. h is FP8 e4m3 [n][512] (1B/channel). Softmax weights fp32.
// Phase 3: lane owns channels lane*8..+7, 8B (uint2) gather per edge.
// MODE 0: out bf16 [n][512] relu(acc+bias512); MODE 1: out fp32 [n][64].
// ---------------------------------------------------------------------------
template <int MODE>
__global__ __launch_bounds__(256) void agg_kernel(const unsigned char* __restrict__ h,
                                                  const float* __restrict__ a_src,
                                                  const float* __restrict__ a_dst,
                                                  const float* __restrict__ bias,
                                                  const int* __restrict__ row_start,
                                                  const int* __restrict__ src_sorted,
                                                  void* __restrict__ outv, int n) {
    __shared__ float alds[4][MAXD][8];
    __shared__ int   slds[4][MAXD];
    int ws = threadIdx.x >> 6;
    int d = blockIdx.x * 4 + ws;
    int lane = threadIdx.x & 63;
    if (d >= n) return;
    int base = row_start[d];
    int end = row_start[d + 1];
    int deg = end - base;
    int head = lane & 7;
    int eslot = lane >> 3;
    float adh = a_dst[d * 8 + head];

    float mx = -1e30f;
    for (int idx = eslot; idx < deg; idx += 8) {
        int s = src_sorted[base + idx];
        float al = a_src[s * 8 + head] + adh;
        al = (al > 0.f) ? al : NEG_SLOPE * al;
        if (idx < MAXD) {
            alds[ws][idx][head] = al;
            if (head == 0) slds[ws][idx] = s;
        }
        mx = fmaxf(mx, al);
    }
    mx = fmaxf(mx, __shfl_xor(mx, 8));
    mx = fmaxf(mx, __shfl_xor(mx, 16));
    mx = fmaxf(mx, __shfl_xor(mx, 32));

    float sm = 0.f;
    for (int idx = eslot; idx < deg; idx += 8) {
        float e;
        if (idx < MAXD) {
            float al = alds[ws][idx][head];
            e = __expf(al - mx);
            alds[ws][idx][head] = e;
        } else {
            int s = src_sorted[base + idx];
            float al = a_src[s * 8 + head] + adh;
            al = (al > 0.f) ? al : NEG_SLOPE * al;
            e = __expf(al - mx);
        }
        sm += e;
    }
    sm += __shfl_xor(sm, 8);
    sm += __shfl_xor(sm, 16);
    sm += __shfl_xor(sm, 32);
    float inv = 1.0f / (sm + EPS_);

    asm volatile("s_waitcnt lgkmcnt(0)" ::: "memory");
    __builtin_amdgcn_wave_barrier();

    int hd2 = lane >> 3;
    float mx2 = __shfl(mx, hd2);
    float inv2 = __shfl(inv, hd2);
    float adh2 = a_dst[d * 8 + hd2];
    const unsigned char* hl = h + lane * 8;

    float acc[8] = {};
    int mdeg = (deg < MAXD) ? deg : MAXD;
    for (int i = 0; i < mdeg; i += 4) {
        int i0 = i;
        int i1 = (i + 1 < mdeg) ? i + 1 : mdeg - 1;
        int i2 = (i + 2 < mdeg) ? i + 2 : mdeg - 1;
        int i3 = (i + 3 < mdeg) ? i + 3 : mdeg - 1;
        int s0 = slds[ws][i0], s1 = slds[ws][i1];
        int s2 = slds[ws][i2], s3 = slds[ws][i3];
        uint2 h0 = *reinterpret_cast<const uint2*>(hl + (size_t)s0 * HC);
        uint2 h1 = *reinterpret_cast<const uint2*>(hl + (size_t)s1 * HC);
        uint2 h2 = *reinterpret_cast<const uint2*>(hl + (size_t)s2 * HC);
        uint2 h3 = *reinterpret_cast<const uint2*>(hl + (size_t)s3 * HC);
        float w0 = alds[ws][i0][hd2] * inv2;
        float w1 = (i + 1 < mdeg) ? alds[ws][i1][hd2] * inv2 : 0.f;
        float w2 = (i + 2 < mdeg) ? alds[ws][i2][hd2] * inv2 : 0.f;
        float w3 = (i + 3 < mdeg) ? alds[ws][i3][hd2] * inv2 : 0.f;
        ACC_FP8(h0, w0)
        ACC_FP8(h1, w1)
        ACC_FP8(h2, w2)
        ACC_FP8(h3, w3)
    }
    for (int i = base + MAXD; i < end; ++i) {
        int s = src_sorted[i];
        float al = a_src[s * 8 + hd2] + adh2;
        al = (al > 0.f) ? al : NEG_SLOPE * al;
        float w = __expf(al - mx2) * inv2;
        uint2 hv = *reinterpret_cast<const uint2*>(hl + (size_t)s * HC);
        ACC_FP8(hv, w)
    }

    if (MODE == 0) {
        float4 b0 = *reinterpret_cast<const float4*>(bias + lane * 8);
        float4 b1 = *reinterpret_cast<const float4*>(bias + lane * 8 + 4);
        float v[8];
        v[0] = fmaxf(acc[0] + b0.x, 0.f); v[1] = fmaxf(acc[1] + b0.y, 0.f);
        v[2] = fmaxf(acc[2] + b0.z, 0.f); v[3] = fmaxf(acc[3] + b0.w, 0.f);
        v[4] = fmaxf(acc[4] + b1.x, 0.f); v[5] = fmaxf(acc[5] + b1.y, 0.f);
        v[6] = fmaxf(acc[6] + b1.z, 0.f); v[7] = fmaxf(acc[7] + b1.w, 0.f);
        uint4 o;
        o.x = (unsigned)f2bf(v[0]) | ((unsigned)f2bf(v[1]) << 16);
        o.y = (unsigned)f2bf(v[2]) | ((unsigned)f2bf(v[3]) << 16);
        o.z = (unsigned)f2bf(v[4]) | ((unsigned)f2bf(v[5]) << 16);
        o.w = (unsigned)f2bf(v[6]) | ((unsigned)f2bf(v[7]) << 16);
        *reinterpret_cast<uint4*>((unsigned short*)outv + (size_t)d * HC + lane * 8) = o;
    } else {
#pragma unroll
        for (int j = 0; j < 8; ++j) {
            acc[j] += __shfl_xor(acc[j], 8);
            acc[j] += __shfl_xor(acc[j], 16);
            acc[j] += __shfl_xor(acc[j], 32);
        }
        if (lane < 8) {
            float* op = (float*)outv + (size_t)d * 64 + lane * 8;
            float4 o0, o1;
            o0.x = fmaxf(acc[0] * 0.125f + bias[lane * 8 + 0], 0.f);
            o0.y = fmaxf(acc[1] * 0.125f + bias[lane * 8 + 1], 0.f);
            o0.z = fmaxf(acc[2] * 0.125f + bias[lane * 8 + 2], 0.f);
            o0.w = fmaxf(acc[3] * 0.125f + bias[lane * 8 + 3], 0.f);
            o1.x = fmaxf(acc[4] * 0.125f + bias[lane * 8 + 4], 0.f);
            o1.y = fmaxf(acc[5] * 0.125f + bias[lane * 8 + 5], 0.f);
            o1.z = fmaxf(acc[6] * 0.125f + bias[lane * 8 + 6], 0.f);
            o1.w = fmaxf(acc[7] * 0.125f + bias[lane * 8 + 7], 0.f);
            *reinterpret_cast<float4*>(op) = o0;
            *reinterpret_cast<float4*>(op + 4) = o1;
        }
    }
}

// ---------------------------------------------------------------------------
// Pool + classify fused: one block per graph.
// ---------------------------------------------------------------------------
__global__ __launch_bounds__(256) void pool_classify(const float* __restrict__ h3,
                                                     const int* __restrict__ batch,
                                                     const float* __restrict__ fcw,
                                                     const float* __restrict__ fcb,
                                                     float* __restrict__ out, int n) {
    int g = blockIdx.x;
    __shared__ int s_lo, s_hi;
    if (threadIdx.x == 0) {
        int lo = 0, hi = n;
        while (lo < hi) { int mid = (lo + hi) >> 1; if (batch[mid] < g) lo = mid + 1; else hi = mid; }
        s_lo = lo;
        int lo2 = lo, hi2 = n;
        while (lo2 < hi2) { int mid = (lo2 + hi2) >> 1; if (batch[mid] < g + 1) lo2 = mid + 1; else hi2 = mid; }
        s_hi = lo2;
    }
    __syncthreads();
    int lo = s_lo, hi = s_hi;
    int lane = threadIdx.x & 63;
    int slot = threadIdx.x >> 6;
    float acc = 0.f;
    for (int i = lo + slot; i < hi; i += 4)
        acc += h3[(size_t)i * 64 + lane];
    __shared__ float red[4][64];
    red[slot][lane] = acc;
    __syncthreads();
    if (slot == 0) {
        float v = red[0][lane] + red[1][lane] + red[2][lane] + red[3][lane];
        float c = (float)(hi - lo);
        c = fmaxf(c, 1.0f);
        float p = v / c;
        float logit[NCLS];
#pragma unroll
        for (int j = 0; j < NCLS; ++j) {
            float t = p * fcw[lane * NCLS + j];
#pragma unroll
            for (int off = 1; off < 64; off <<= 1) t += __shfl_xor(t, off);
            logit[j] = t + fcb[j];
        }
        float m = logit[0];
#pragma unroll
        for (int j = 1; j < NCLS; ++j) m = fmaxf(m, logit[j]);
        float s = 0.f;
#pragma unroll
        for (int j = 0; j < NCLS; ++j) s += expf(logit[j] - m);
        float lse = logf(s);
        if (lane < NCLS) {
            float vv = logit[0];
#pragma unroll
            for (int j = 1; j < NCLS; ++j)
                if (lane == j) vv = logit[j];
            out[g * NCLS + lane] = vv - m - lse;
        }
    }
}

// ---------------------------------------------------------------------------
extern "C" void kernel_launch(void* const* d_in, const int* in_sizes, int n_in,
                              void* d_out, int out_size, void* d_ws, size_t ws_size,
                              hipStream_t stream) {
    const float* x    = (const float*)d_in[0];
    const int*   ei   = (const int*)d_in[1];
    const int*   batch = (const int*)d_in[2];
    const float* W1  = (const float*)d_in[3];
    const float* a1s = (const float*)d_in[4];
    const float* a1d = (const float*)d_in[5];
    const float* b1  = (const float*)d_in[6];
    const float* W2  = (const float*)d_in[7];
    const float* a2s = (const float*)d_in[8];
    const float* a2d = (const float*)d_in[9];
    const float* b2  = (const float*)d_in[10];
    const float* W3  = (const float*)d_in[11];
    const float* a3s = (const float*)d_in[12];
    const float* a3d = (const float*)d_in[13];
    const float* b3  = (const float*)d_in[14];
    const float* fcw = (const float*)d_in[15];
    const float* fcb = (const float*)d_in[16];

    const int n  = in_sizes[0] / F_IN;     // 50000
    const int E_ = in_sizes[1] / 2;        // 400000
    const int EP = E_ + n;                 // 450000

    // ---- workspace carve-up ----
    char* p = (char*)d_ws;
    unsigned short* xb   = (unsigned short*)p; p += (size_t)n * F_IN * 2;
    unsigned short* w1t  = (unsigned short*)p; p += (size_t)HC * F_IN * 2;
    unsigned short* w2t  = (unsigned short*)p; p += (size_t)HC * HC * 2;
    unsigned short* w3t  = (unsigned short*)p; p += (size_t)HC * HC * 2;
    unsigned char*  hbuf = (unsigned char*)p;  p += (size_t)n * HC;       // fp8 h
    unsigned short* buf2 = (unsigned short*)p; p += (size_t)n * HC * 2;   // bf16 layer input
    float* asrc   = (float*)p; p += (size_t)n * 8 * 4;
    float* adst   = (float*)p; p += (size_t)n * 8 * 4;
    float* h3     = (float*)p; p += (size_t)n * 64 * 4;
    int* counts   = (int*)p;   p += (size_t)n * 4;
    int* row_start= (int*)p;   p += (size_t)(n + 1) * 4;
    int* src_sorted=(int*)p;   p += (size_t)EP * 4;
    int* partial  = (int*)p;   p += (size_t)n * 4;
    int* bsum     = (int*)p;   p += 1024 * 4;

    const int edge_blocks = (EP + 255) / 256;
    const int node_blocks = (n + 3) / 4;
    const int scan_blocks = (n + 255) / 256;

    // ---- CSR build ----
    hipMemsetAsync(counts, 0, (size_t)n * sizeof(int), stream);
    hist_kernel<<<edge_blocks, 256, 0, stream>>>(ei, counts, E_, EP);
    scan1<<<scan_blocks, 256, 0, stream>>>(counts, partial, bsum, n);
    scan2<<<1, 1024, 0, stream>>>(bsum, scan_blocks);
    scan3<<<scan_blocks, 256, 0, stream>>>(partial, bsum, row_start, counts, n);
    scatter_kernel<<<edge_blocks, 256, 0, stream>>>(ei, row_start, counts, src_sorted, E_, EP);

    // ---- conversions ----
    conv_bf16<<<((n * F_IN / 4) + 255) / 256, 256, 0, stream>>>(x, xb, n * F_IN / 4);
    transpose_w<<<dim3(HC / 32, F_IN / 32), dim3(32, 8), 0, stream>>>(W1, w1t, F_IN, HC);
    transpose_w<<<dim3(HC / 32, HC / 32), dim3(32, 8), 0, stream>>>(W2, w2t, HC, HC);
    transpose_w<<<dim3(HC / 32, HC / 32), dim3(32, 8), 0, stream>>>(W3, w3t, HC, HC);

    const int nby = (n + 127) / 128;
    const int nwg = 4 * nby;          // 4 col-blocks x row-blocks, 1-D swizzled grid

    // ---- Layer 1 ----
    gemm_attn<<<nwg, 256, 0, stream>>>(xb, w1t, hbuf, a1s, a1d, asrc, adst, n, F_IN);
    agg_kernel<0><<<node_blocks, 256, 0, stream>>>(hbuf, asrc, adst, b1, row_start, src_sorted, buf2, n);

    // ---- Layer 2 ----
    gemm_attn<<<nwg, 256, 0, stream>>>(buf2, w2t, hbuf, a2s, a2d, asrc, adst, n, HC);
    agg_kernel<0><<<node_blocks, 256, 0, stream>>>(hbuf, asrc, adst, b2, row_start, src_sorted, buf2, n);

    // ---- Layer 3 ----
    gemm_attn<<<nwg, 256, 0, stream>>>(buf2, w3t, hbuf, a3s, a3d, asrc, adst, n, HC);
    agg_kernel<1><<<node_blocks, 256, 0, stream>>>(hbuf, asrc, adst, b3, row_start, src_sorted, h3, n);

    // ---- Pool + classify (fused) ----
    pool_classify<<<GG, 256, 0, stream>>>(h3, batch, fcw, fcb, (float*)d_out, n);
}

// Round 9
// 413.241 us; speedup vs baseline: 4.4599x; 1.0271x over previous
//
#include <hip/hip_runtime.h>
#include <hip/hip_bf16.h>

#define HH 8
#define CC 64
#define HC 512
#define GG 64
#define NCLS 10
#define F_IN 128
#define NEG_SLOPE 0.2f
#define EPS_ 1e-16f
#define MAXD 32

typedef float f32x4 __attribute__((ext_vector_type(4)));
typedef __bf16 bf16x8 __attribute__((ext_vector_type(8)));

__device__ __forceinline__ unsigned short f2bf(float f) {
    unsigned u = __builtin_bit_cast(unsigned, f);
    u += 0x7fffu + ((u >> 16) & 1u);          // RNE
    return (unsigned short)(u >> 16);
}
__device__ __forceinline__ float bflo(unsigned u) {
    return __builtin_bit_cast(float, u << 16);
}
__device__ __forceinline__ float bfhi(unsigned u) {
    return __builtin_bit_cast(float, u & 0xffff0000u);
}
// fp8 e4m3 (OCP on gfx950) helpers — hardware cvt. sel must be ICE -> template.
__device__ __forceinline__ unsigned char f2fp8(float f) {
    unsigned pk = __builtin_amdgcn_cvt_pk_fp8_f32(f, f, 0u, false);
    return (unsigned char)(pk & 0xffu);
}
template <int SEL>
__device__ __forceinline__ float fp82f(unsigned w) {
    return __builtin_amdgcn_cvt_f32_fp8(w, SEL);
}
// dequant 8 fp8 channels (uint2) with weight w into acc[0..7]
#define ACC_FP8(hv, w)                                           \
    acc[0] += (w) * fp82f<0>(hv.x); acc[1] += (w) * fp82f<1>(hv.x); \
    acc[2] += (w) * fp82f<2>(hv.x); acc[3] += (w) * fp82f<3>(hv.x); \
    acc[4] += (w) * fp82f<0>(hv.y); acc[5] += (w) * fp82f<1>(hv.y); \
    acc[6] += (w) * fp82f<2>(hv.y); acc[7] += (w) * fp82f<3>(hv.y);

// async global->LDS, 16B per lane. lds ptr must be wave-uniform base.
__device__ __forceinline__ void gload16(const unsigned short* g, unsigned short* l) {
    __builtin_amdgcn_global_load_lds(
        (const __attribute__((address_space(1))) unsigned int*)g,
        (__attribute__((address_space(3))) unsigned int*)l,
        16, 0, 0);
}

// ---------------------------------------------------------------------------
// CSR build
// ---------------------------------------------------------------------------
__global__ void hist_kernel(const int* __restrict__ ei, int* __restrict__ counts,
                            int E_, int EP_) {
    int e = blockIdx.x * 256 + threadIdx.x;
    if (e >= EP_) return;
    int d = (e < E_) ? ei[E_ + e] : (e - E_);
    atomicAdd(&counts[d], 1);
}

__global__ void scan1(const int* __restrict__ counts, int* __restrict__ partial,
                      int* __restrict__ bsum, int n) {
    __shared__ int buf[256];
    int idx = blockIdx.x * 256 + threadIdx.x;
    int v = (idx < n) ? counts[idx] : 0;
    buf[threadIdx.x] = v;
    __syncthreads();
    for (int off = 1; off < 256; off <<= 1) {
        int t = (threadIdx.x >= off) ? buf[threadIdx.x - off] : 0;
        __syncthreads();
        buf[threadIdx.x] += t;
        __syncthreads();
    }
    if (idx < n) partial[idx] = buf[threadIdx.x];
    if (threadIdx.x == 255) bsum[blockIdx.x] = buf[255];
}

__global__ void scan2(int* __restrict__ bsum, int nb) {
    __shared__ int buf[1024];
    int t = threadIdx.x;
    buf[t] = (t < nb) ? bsum[t] : 0;
    __syncthreads();
    for (int off = 1; off < 1024; off <<= 1) {
        int v = (t >= off) ? buf[t - off] : 0;
        __syncthreads();
        buf[t] += v;
        __syncthreads();
    }
    if (t < nb) bsum[t] = buf[t];
}

// also zeroes counts so scatter can reuse it as a cursor (saves a memset)
__global__ void scan3(const int* __restrict__ partial, const int* __restrict__ bsum,
                      int* __restrict__ row_start, int* __restrict__ counts, int n) {
    int idx = blockIdx.x * 256 + threadIdx.x;
    if (idx >= n) return;
    int add = (blockIdx.x > 0) ? bsum[blockIdx.x - 1] : 0;
    row_start[idx + 1] = partial[idx] + add;
    counts[idx] = 0;
    if (idx == 0) row_start[0] = 0;
}

// writes src_sorted directly (no perm indirection)
__global__ void scatter_kernel(const int* __restrict__ ei, const int* __restrict__ row_start,
                               int* __restrict__ cursor, int* __restrict__ src_sorted,
                               int E_, int EP_) {
    int e = blockIdx.x * 256 + threadIdx.x;
    if (e >= EP_) return;
    int s, d;
    if (e < E_) { s = ei[e]; d = ei[E_ + e]; }
    else        { s = e - E_; d = e - E_; }
    int pos = row_start[d] + atomicAdd(&cursor[d], 1);
    src_sorted[pos] = s;
}

// ---------------------------------------------------------------------------
// fp32 -> bf16 conversions
// ---------------------------------------------------------------------------
__global__ void conv_bf16(const float* __restrict__ in, unsigned short* __restrict__ out,
                          int n4) {
    int i = blockIdx.x * 256 + threadIdx.x;
    if (i >= n4) return;
    float4 v = reinterpret_cast<const float4*>(in)[i];
    reinterpret_cast<ushort4*>(out)[i] =
        make_ushort4(f2bf(v.x), f2bf(v.y), f2bf(v.z), f2bf(v.w));
}

// W [K][Nc] fp32 -> WT [Nc][K] bf16
__global__ void transpose_w(const float* __restrict__ W, unsigned short* __restrict__ WT,
                            int K, int Nc) {
    __shared__ float t[32][33];
    int bx = blockIdx.x * 32;   // n
    int by = blockIdx.y * 32;   // k
    int x = threadIdx.x, y = threadIdx.y;
    for (int i = y; i < 32; i += 8)
        t[i][x] = W[(size_t)(by + i) * Nc + bx + x];
    __syncthreads();
    for (int i = y; i < 32; i += 8)
        WT[(size_t)(bx + i) * K + by + x] = f2bf(t[x][i]);
}

// ---------------------------------------------------------------------------
// bf16 MFMA GEMM + fused attention coefficients. h output stored as FP8 e4m3.
// LDS tiles XOR-swizzled (T2, both-sides): global source chunk pre-swizzled
// to match linear global_load_lds dest; ds_read applies the same XOR.
// ---------------------------------------------------------------------------
__global__ __launch_bounds__(256) void gemm_attn(const unsigned short* __restrict__ A,
                                                 const unsigned short* __restrict__ BT,
                                                 unsigned char* __restrict__ C,
                                                 const float* __restrict__ asw,
                                                 const float* __restrict__ adw,
                                                 float* __restrict__ a_src,
                                                 float* __restrict__ a_dst,
                                                 int M, int K) {
    __shared__ __align__(16) unsigned short As[128 * 64];  // [m][k], 16 KB
    __shared__ __align__(16) unsigned short Bs[128 * 64];  // [n][k], 16 KB

    // XCD-chunked bijective swizzle (8 XCDs)
    const int nwg = gridDim.x;
    const int f = blockIdx.x;
    const int q = nwg >> 3, r = nwg & 7;
    const int xcd = f & 7, rank = f >> 3;
    const int swz = (xcd < r ? xcd * (q + 1) : r * (q + 1) + (xcd - r) * q) + rank;
    const int bcol = (swz & 3) * 128;     // Nc=512 -> 4 col-blocks
    const int brow = (swz >> 2) * 128;

    const int tid = threadIdx.x;
    const int lane = tid & 63;
    const int wave = tid >> 6;
    const int wr = wave >> 1, wc = wave & 1;

    f32x4 acc[4][4];
#pragma unroll
    for (int i = 0; i < 4; ++i)
#pragma unroll
        for (int j = 0; j < 4; ++j) acc[i][j] = (f32x4)0.f;

    const int lrow = lane >> 3;                     // 0..7 = LDS row & 7
    const int lcolsw = (((lane & 7) ^ lrow)) * 8;   // pre-swizzled k-chunk (T2 source side)
    const int arow0 = brow + wave * 32 + lrow;
    const int brow0 = bcol + wave * 32 + lrow;

    const int kb = (lane >> 4) * 8;
    const int rowa = wr * 64 + (lane & 15);
    const int rowb = wc * 64 + (lane & 15);
    const int rxor = lane & 7;                      // (row & 7) of fragment rows

    for (int k0 = 0; k0 < K; k0 += 64) {
#pragma unroll
        for (int it = 0; it < 4; ++it) {
            const int c = wave * 4 + it;
            int ar = arow0 + it * 8;
            if (ar >= M) ar = M - 1;                // clamp: rows >=M never stored
            gload16(A + (size_t)ar * K + k0 + lcolsw, &As[c * 512]);
            int br = brow0 + it * 8;
            gload16(BT + (size_t)br * K + k0 + lcolsw, &Bs[c * 512]);
        }
        __syncthreads();
#pragma unroll
        for (int kk = 0; kk < 64; kk += 32) {
            const int chunk = (kk + kb) >> 3;
            const int koff = (chunk ^ rxor) * 8;    // T2 read-side XOR
            bf16x8 a[4], b[4];
#pragma unroll
            for (int m = 0; m < 4; ++m)
                a[m] = *(const bf16x8*)&As[(rowa + m * 16) * 64 + koff];
#pragma unroll
            for (int nn = 0; nn < 4; ++nn)
                b[nn] = *(const bf16x8*)&Bs[(rowb + nn * 16) * 64 + koff];
#pragma unroll
            for (int m = 0; m < 4; ++m)
#pragma unroll
                for (int nn = 0; nn < 4; ++nn)
                    acc[m][nn] = __builtin_amdgcn_mfma_f32_16x16x32_bf16(
                        a[m], b[nn], acc[m][nn], 0, 0, 0);
        }
        __syncthreads();
    }

    const int r0 = brow + wr * 64 + (lane >> 4) * 4;
    const int c0 = bcol + wc * 64 + (lane & 15);

    // ---- C store (fp8 h) ----
#pragma unroll
    for (int m = 0; m < 4; ++m)
#pragma unroll
        for (int j = 0; j < 4; ++j) {
            int rr = r0 + m * 16 + j;
            if (rr < M) {
#pragma unroll
                for (int nn = 0; nn < 4; ++nn)
                    C[(size_t)rr * HC + c0 + nn * 16] = f2fp8(acc[m][nn][j]);
            }
        }

    // ---- fused attention coefficients (from fp32 acc) ----
    const int head = (bcol + wc * 64) >> 6;
    float asv[4], adv[4];
#pragma unroll
    for (int nn = 0; nn < 4; ++nn) {
        int c = c0 + nn * 16;
        asv[nn] = asw[c];
        adv[nn] = adw[c];
    }
    float psrc[4][4], pdst[4][4];
#pragma unroll
    for (int m = 0; m < 4; ++m)
#pragma unroll
        for (int j = 0; j < 4; ++j) {
            float ps = 0.f, pd = 0.f;
#pragma unroll
            for (int nn = 0; nn < 4; ++nn) {
                float hv = acc[m][nn][j];
                ps += hv * asv[nn];
                pd += hv * adv[nn];
            }
            psrc[m][j] = ps;
            pdst[m][j] = pd;
        }
#pragma unroll
    for (int m = 0; m < 4; ++m)
#pragma unroll
        for (int j = 0; j < 4; ++j) {
#pragma unroll
            for (int mask = 1; mask < 16; mask <<= 1) {
                psrc[m][j] += __shfl_xor(psrc[m][j], mask);
                pdst[m][j] += __shfl_xor(pdst[m][j], mask);
            }
        }
    if ((lane & 15) == 0) {
#pragma unroll
        for (int m = 0; m < 4; ++m)
#pragma unroll
            for (int j = 0; j < 4; ++j) {
                int rr = r0 + m * 16 + j;
                if (rr < M) {
                    a_src[rr * 8 + head] = psrc[m][j];
                    a_dst[rr * 8 + head] = pdst[m][j];
                }
            }
    }
}

// ---------------------------------------------------------------------------
// Aggregation. h is FP8 e4m3 [n][512] (1B/channel). Softmax weights fp32.
// ---------------------------------------------------------------------------
template <int MODE>
__global__ __launch_bounds__(256) void agg_kernel(const unsigned char* __restrict__ h,
                                                  const float* __restrict__ a_src,
                                                  const float* __restrict__ a_dst,
                                                  const float* __restrict__ bias,
                                                  const int* __restrict__ row_start,
                                                  const int* __restrict__ src_sorted,
                                                  void* __restrict__ outv, int n) {
    __shared__ float alds[4][MAXD][8];
    __shared__ int   slds[4][MAXD];
    int ws = threadIdx.x >> 6;
    int d = blockIdx.x * 4 + ws;
    int lane = threadIdx.x & 63;
    if (d >= n) return;
    int base = row_start[d];
    int end = row_start[d + 1];
    int deg = end - base;
    int head = lane & 7;
    int eslot = lane >> 3;
    float adh = a_dst[d * 8 + head];

    float mx = -1e30f;
    for (int idx = eslot; idx < deg; idx += 8) {
        int s = src_sorted[base + idx];
        float al = a_src[s * 8 + head] + adh;
        al = (al > 0.f) ? al : NEG_SLOPE * al;
        if (idx < MAXD) {
            alds[ws][idx][head] = al;
            if (head == 0) slds[ws][idx] = s;
        }
        mx = fmaxf(mx, al);
    }
    mx = fmaxf(mx, __shfl_xor(mx, 8));
    mx = fmaxf(mx, __shfl_xor(mx, 16));
    mx = fmaxf(mx, __shfl_xor(mx, 32));

    float sm = 0.f;
    for (int idx = eslot; idx < deg; idx += 8) {
        float e;
        if (idx < MAXD) {
            float al = alds[ws][idx][head];
            e = __expf(al - mx);
            alds[ws][idx][head] = e;
        } else {
            int s = src_sorted[base + idx];
            float al = a_src[s * 8 + head] + adh;
            al = (al > 0.f) ? al : NEG_SLOPE * al;
            e = __expf(al - mx);
        }
        sm += e;
    }
    sm += __shfl_xor(sm, 8);
    sm += __shfl_xor(sm, 16);
    sm += __shfl_xor(sm, 32);
    float inv = 1.0f / (sm + EPS_);

    asm volatile("s_waitcnt lgkmcnt(0)" ::: "memory");
    __builtin_amdgcn_wave_barrier();

    int hd2 = lane >> 3;
    float mx2 = __shfl(mx, hd2);
    float inv2 = __shfl(inv, hd2);
    float adh2 = a_dst[d * 8 + hd2];
    const unsigned char* hl = h + lane * 8;

    float acc[8] = {};
    int mdeg = (deg < MAXD) ? deg : MAXD;
    for (int i = 0; i < mdeg; i += 4) {
        int i0 = i;
        int i1 = (i + 1 < mdeg) ? i + 1 : mdeg - 1;
        int i2 = (i + 2 < mdeg) ? i + 2 : mdeg - 1;
        int i3 = (i + 3 < mdeg) ? i + 3 : mdeg - 1;
        int s0 = slds[ws][i0], s1 = slds[ws][i1];
        int s2 = slds[ws][i2], s3 = slds[ws][i3];
        uint2 h0 = *reinterpret_cast<const uint2*>(hl + (size_t)s0 * HC);
        uint2 h1 = *reinterpret_cast<const uint2*>(hl + (size_t)s1 * HC);
        uint2 h2 = *reinterpret_cast<const uint2*>(hl + (size_t)s2 * HC);
        uint2 h3 = *reinterpret_cast<const uint2*>(hl + (size_t)s3 * HC);
        float w0 = alds[ws][i0][hd2] * inv2;
        float w1 = (i + 1 < mdeg) ? alds[ws][i1][hd2] * inv2 : 0.f;
        float w2 = (i + 2 < mdeg) ? alds[ws][i2][hd2] * inv2 : 0.f;
        float w3 = (i + 3 < mdeg) ? alds[ws][i3][hd2] * inv2 : 0.f;
        ACC_FP8(h0, w0)
        ACC_FP8(h1, w1)
        ACC_FP8(h2, w2)
        ACC_FP8(h3, w3)
    }
    for (int i = base + MAXD; i < end; ++i) {
        int s = src_sorted[i];
        float al = a_src[s * 8 + hd2] + adh2;
        al = (al > 0.f) ? al : NEG_SLOPE * al;
        float w = __expf(al - mx2) * inv2;
        uint2 hv = *reinterpret_cast<const uint2*>(hl + (size_t)s * HC);
        ACC_FP8(hv, w)
    }

    if (MODE == 0) {
        float4 b0 = *reinterpret_cast<const float4*>(bias + lane * 8);
        float4 b1 = *reinterpret_cast<const float4*>(bias + lane * 8 + 4);
        float v[8];
        v[0] = fmaxf(acc[0] + b0.x, 0.f); v[1] = fmaxf(acc[1] + b0.y, 0.f);
        v[2] = fmaxf(acc[2] + b0.z, 0.f); v[3] = fmaxf(acc[3] + b0.w, 0.f);
        v[4] = fmaxf(acc[4] + b1.x, 0.f); v[5] = fmaxf(acc[5] + b1.y, 0.f);
        v[6] = fmaxf(acc[6] + b1.z, 0.f); v[7] = fmaxf(acc[7] + b1.w, 0.f);
        uint4 o;
        o.x = (unsigned)f2bf(v[0]) | ((unsigned)f2bf(v[1]) << 16);
        o.y = (unsigned)f2bf(v[2]) | ((unsigned)f2bf(v[3]) << 16);
        o.z = (unsigned)f2bf(v[4]) | ((unsigned)f2bf(v[5]) << 16);
        o.w = (unsigned)f2bf(v[6]) | ((unsigned)f2bf(v[7]) << 16);
        *reinterpret_cast<uint4*>((unsigned short*)outv + (size_t)d * HC + lane * 8) = o;
    } else {
#pragma unroll
        for (int j = 0; j < 8; ++j) {
            acc[j] += __shfl_xor(acc[j], 8);
            acc[j] += __shfl_xor(acc[j], 16);
            acc[j] += __shfl_xor(acc[j], 32);
        }
        if (lane < 8) {
            float* op = (float*)outv + (size_t)d * 64 + lane * 8;
            float4 o0, o1;
            o0.x = fmaxf(acc[0] * 0.125f + bias[lane * 8 + 0], 0.f);
            o0.y = fmaxf(acc[1] * 0.125f + bias[lane * 8 + 1], 0.f);
            o0.z = fmaxf(acc[2] * 0.125f + bias[lane * 8 + 2], 0.f);
            o0.w = fmaxf(acc[3] * 0.125f + bias[lane * 8 + 3], 0.f);
            o1.x = fmaxf(acc[4] * 0.125f + bias[lane * 8 + 4], 0.f);
            o1.y = fmaxf(acc[5] * 0.125f + bias[lane * 8 + 5], 0.f);
            o1.z = fmaxf(acc[6] * 0.125f + bias[lane * 8 + 6], 0.f);
            o1.w = fmaxf(acc[7] * 0.125f + bias[lane * 8 + 7], 0.f);
            *reinterpret_cast<float4*>(op) = o0;
            *reinterpret_cast<float4*>(op + 4) = o1;
        }
    }
}

// ---------------------------------------------------------------------------
// Pool + classify fused: one block per graph.
// ---------------------------------------------------------------------------
__global__ __launch_bounds__(256) void pool_classify(const float* __restrict__ h3,
                                                     const int* __restrict__ batch,
                                                     const float* __restrict__ fcw,
                                                     const float* __restrict__ fcb,
                                                     float* __restrict__ out, int n) {
    int g = blockIdx.x;
    __shared__ int s_lo, s_hi;
    if (threadIdx.x == 0) {
        int lo = 0, hi = n;
        while (lo < hi) { int mid = (lo + hi) >> 1; if (batch[mid] < g) lo = mid + 1; else hi = mid; }
        s_lo = lo;
        int lo2 = lo, hi2 = n;
        while (lo2 < hi2) { int mid = (lo2 + hi2) >> 1; if (batch[mid] < g + 1) lo2 = mid + 1; else hi2 = mid; }
        s_hi = lo2;
    }
    __syncthreads();
    int lo = s_lo, hi = s_hi;
    int lane = threadIdx.x & 63;
    int slot = threadIdx.x >> 6;
    float acc = 0.f;
    for (int i = lo + slot; i < hi; i += 4)
        acc += h3[(size_t)i * 64 + lane];
    __shared__ float red[4][64];
    red[slot][lane] = acc;
    __syncthreads();
    if (slot == 0) {
        float v = red[0][lane] + red[1][lane] + red[2][lane] + red[3][lane];
        float c = (float)(hi - lo);
        c = fmaxf(c, 1.0f);
        float p = v / c;
        float logit[NCLS];
#pragma unroll
        for (int j = 0; j < NCLS; ++j) {
            float t = p * fcw[lane * NCLS + j];
#pragma unroll
            for (int off = 1; off < 64; off <<= 1) t += __shfl_xor(t, off);
            logit[j] = t + fcb[j];
        }
        float m = logit[0];
#pragma unroll
        for (int j = 1; j < NCLS; ++j) m = fmaxf(m, logit[j]);
        float s = 0.f;
#pragma unroll
        for (int j = 0; j < NCLS; ++j) s += expf(logit[j] - m);
        float lse = logf(s);
        if (lane < NCLS) {
            float vv = logit[0];
#pragma unroll
            for (int j = 1; j < NCLS; ++j)
                if (lane == j) vv = logit[j];
            out[g * NCLS + lane] = vv - m - lse;
        }
    }
}

// ---------------------------------------------------------------------------
extern "C" void kernel_launch(void* const* d_in, const int* in_sizes, int n_in,
                              void* d_out, int out_size, void* d_ws, size_t ws_size,
                              hipStream_t stream) {
    const float* x    = (const float*)d_in[0];
    const int*   ei   = (const int*)d_in[1];
    const int*   batch = (const int*)d_in[2];
    const float* W1  = (const float*)d_in[3];
    const float* a1s = (const float*)d_in[4];
    const float* a1d = (const float*)d_in[5];
    const float* b1  = (const float*)d_in[6];
    const float* W2  = (const float*)d_in[7];
    const float* a2s = (const float*)d_in[8];
    const float* a2d = (const float*)d_in[9];
    const float* b2  = (const float*)d_in[10];
    const float* W3  = (const float*)d_in[11];
    const float* a3s = (const float*)d_in[12];
    const float* a3d = (const float*)d_in[13];
    const float* b3  = (const float*)d_in[14];
    const float* fcw = (const float*)d_in[15];
    const float* fcb = (const float*)d_in[16];

    const int n  = in_sizes[0] / F_IN;     // 50000
    const int E_ = in_sizes[1] / 2;        // 400000
    const int EP = E_ + n;                 // 450000

    // ---- workspace carve-up ----
    char* p = (char*)d_ws;
    unsigned short* xb   = (unsigned short*)p; p += (size_t)n * F_IN * 2;
    unsigned short* w1t  = (unsigned short*)p; p += (size_t)HC * F_IN * 2;
    unsigned short* w2t  = (unsigned short*)p; p += (size_t)HC * HC * 2;
    unsigned short* w3t  = (unsigned short*)p; p += (size_t)HC * HC * 2;
    unsigned char*  hbuf = (unsigned char*)p;  p += (size_t)n * HC;       // fp8 h
    unsigned short* buf2 = (unsigned short*)p; p += (size_t)n * HC * 2;   // bf16 layer input
    float* asrc   = (float*)p; p += (size_t)n * 8 * 4;
    float* adst   = (float*)p; p += (size_t)n * 8 * 4;
    float* h3     = (float*)p; p += (size_t)n * 64 * 4;
    int* counts   = (int*)p;   p += (size_t)n * 4;
    int* row_start= (int*)p;   p += (size_t)(n + 1) * 4;
    int* src_sorted=(int*)p;   p += (size_t)EP * 4;
    int* partial  = (int*)p;   p += (size_t)n * 4;
    int* bsum     = (int*)p;   p += 1024 * 4;

    const int edge_blocks = (EP + 255) / 256;
    const int node_blocks = (n + 3) / 4;
    const int scan_blocks = (n + 255) / 256;

    // ---- CSR build ----
    hipMemsetAsync(counts, 0, (size_t)n * sizeof(int), stream);
    hist_kernel<<<edge_blocks, 256, 0, stream>>>(ei, counts, E_, EP);
    scan1<<<scan_blocks, 256, 0, stream>>>(counts, partial, bsum, n);
    scan2<<<1, 1024, 0, stream>>>(bsum, scan_blocks);
    scan3<<<scan_blocks, 256, 0, stream>>>(partial, bsum, row_start, counts, n);
    scatter_kernel<<<edge_blocks, 256, 0, stream>>>(ei, row_start, counts, src_sorted, E_, EP);

    // ---- conversions ----
    conv_bf16<<<((n * F_IN / 4) + 255) / 256, 256, 0, stream>>>(x, xb, n * F_IN / 4);
    transpose_w<<<dim3(HC / 32, F_IN / 32), dim3(32, 8), 0, stream>>>(W1, w1t, F_IN, HC);
    transpose_w<<<dim3(HC / 32, HC / 32), dim3(32, 8), 0, stream>>>(W2, w2t, HC, HC);
    transpose_w<<<dim3(HC / 32, HC / 32), dim3(32, 8), 0, stream>>>(W3, w3t, HC, HC);

    const int nby = (n + 127) / 128;
    const int nwg = 4 * nby;          // 4 col-blocks x row-blocks, 1-D swizzled grid

    // ---- Layer 1 ----
    gemm_attn<<<nwg, 256, 0, stream>>>(xb, w1t, hbuf, a1s, a1d, asrc, adst, n, F_IN);
    agg_kernel<0><<<node_blocks, 256, 0, stream>>>(hbuf, asrc, adst, b1, row_start, src_sorted, buf2, n);

    // ---- Layer 2 ----
    gemm_attn<<<nwg, 256, 0, stream>>>(buf2, w2t, hbuf, a2s, a2d, asrc, adst, n, HC);
    agg_kernel<0><<<node_blocks, 256, 0, stream>>>(hbuf, asrc, adst, b2, row_start, src_sorted, buf2, n);

    // ---- Layer 3 ----
    gemm_attn<<<nwg, 256, 0, stream>>>(buf2, w3t, hbuf, a3s, a3d, asrc, adst, n, HC);
    agg_kernel<1><<<node_blocks, 256, 0, stream>>>(hbuf, asrc, adst, b3, row_start, src_sorted, h3, n);

    // ---- Pool + classify (fused) ----
    pool_classify<<<GG, 256, 0, stream>>>(h3, batch, fcw, fcb, (float*)d_out, n);
}

// Round 10
// 389.367 us; speedup vs baseline: 4.7334x; 1.0613x over previous
//
#include <hip/hip_runtime.h>
#include <hip/hip_bf16.h>

#define HH 8
#define CC 64
#define HC 512
#define GG 64
#define NCLS 10
#define F_IN 128
#define NEG_SLOPE 0.2f
#define EPS_ 1e-16f
#define MAXD 32

typedef float f32x4 __attribute__((ext_vector_type(4)));
typedef __bf16 bf16x8 __attribute__((ext_vector_type(8)));

__device__ __forceinline__ unsigned short f2bf(float f) {
    unsigned u = __builtin_bit_cast(unsigned, f);
    u += 0x7fffu + ((u >> 16) & 1u);          // RNE
    return (unsigned short)(u >> 16);
}
__device__ __forceinline__ float bflo(unsigned u) {
    return __builtin_bit_cast(float, u << 16);
}
__device__ __forceinline__ float bfhi(unsigned u) {
    return __builtin_bit_cast(float, u & 0xffff0000u);
}
// fp8 e4m3 (OCP on gfx950) helpers — hardware cvt. sel must be ICE -> template.
__device__ __forceinline__ unsigned char f2fp8(float f) {
    unsigned pk = __builtin_amdgcn_cvt_pk_fp8_f32(f, f, 0u, false);
    return (unsigned char)(pk & 0xffu);
}
template <int SEL>
__device__ __forceinline__ float fp82f(unsigned w) {
    return __builtin_amdgcn_cvt_f32_fp8(w, SEL);
}
// dequant 8 fp8 channels (uint2) with weight w into acc[0..7]
#define ACC_FP8(hv, w)                                           \
    acc[0] += (w) * fp82f<0>(hv.x); acc[1] += (w) * fp82f<1>(hv.x); \
    acc[2] += (w) * fp82f<2>(hv.x); acc[3] += (w) * fp82f<3>(hv.x); \
    acc[4] += (w) * fp82f<0>(hv.y); acc[5] += (w) * fp82f<1>(hv.y); \
    acc[6] += (w) * fp82f<2>(hv.y); acc[7] += (w) * fp82f<3>(hv.y);

// async global->LDS, 16B per lane. lds ptr must be wave-uniform base.
__device__ __forceinline__ void gload16(const unsigned short* g, unsigned short* l) {
    __builtin_amdgcn_global_load_lds(
        (const __attribute__((address_space(1))) unsigned int*)g,
        (__attribute__((address_space(3))) unsigned int*)l,
        16, 0, 0);
}

// ---------------------------------------------------------------------------
// CSR build
// ---------------------------------------------------------------------------
__global__ void hist_kernel(const int* __restrict__ ei, int* __restrict__ counts,
                            int E_, int EP_) {
    int e = blockIdx.x * 256 + threadIdx.x;
    if (e >= EP_) return;
    int d = (e < E_) ? ei[E_ + e] : (e - E_);
    atomicAdd(&counts[d], 1);
}

__global__ void scan1(const int* __restrict__ counts, int* __restrict__ partial,
                      int* __restrict__ bsum, int n) {
    __shared__ int buf[256];
    int idx = blockIdx.x * 256 + threadIdx.x;
    int v = (idx < n) ? counts[idx] : 0;
    buf[threadIdx.x] = v;
    __syncthreads();
    for (int off = 1; off < 256; off <<= 1) {
        int t = (threadIdx.x >= off) ? buf[threadIdx.x - off] : 0;
        __syncthreads();
        buf[threadIdx.x] += t;
        __syncthreads();
    }
    if (idx < n) partial[idx] = buf[threadIdx.x];
    if (threadIdx.x == 255) bsum[blockIdx.x] = buf[255];
}

__global__ void scan2(int* __restrict__ bsum, int nb) {
    __shared__ int buf[1024];
    int t = threadIdx.x;
    buf[t] = (t < nb) ? bsum[t] : 0;
    __syncthreads();
    for (int off = 1; off < 1024; off <<= 1) {
        int v = (t >= off) ? buf[t - off] : 0;
        __syncthreads();
        buf[t] += v;
        __syncthreads();
    }
    if (t < nb) bsum[t] = buf[t];
}

// also zeroes counts so scatter can reuse it as a cursor (saves a memset)
__global__ void scan3(const int* __restrict__ partial, const int* __restrict__ bsum,
                      int* __restrict__ row_start, int* __restrict__ counts, int n) {
    int idx = blockIdx.x * 256 + threadIdx.x;
    if (idx >= n) return;
    int add = (blockIdx.x > 0) ? bsum[blockIdx.x - 1] : 0;
    row_start[idx + 1] = partial[idx] + add;
    counts[idx] = 0;
    if (idx == 0) row_start[0] = 0;
}

// writes src_sorted directly (no perm indirection)
__global__ void scatter_kernel(const int* __restrict__ ei, const int* __restrict__ row_start,
                               int* __restrict__ cursor, int* __restrict__ src_sorted,
                               int E_, int EP_) {
    int e = blockIdx.x * 256 + threadIdx.x;
    if (e >= EP_) return;
    int s, d;
    if (e < E_) { s = ei[e]; d = ei[E_ + e]; }
    else        { s = e - E_; d = e - E_; }
    int pos = row_start[d] + atomicAdd(&cursor[d], 1);
    src_sorted[pos] = s;
}

// ---------------------------------------------------------------------------
// fp32 -> bf16 conversions
// ---------------------------------------------------------------------------
__global__ void conv_bf16(const float* __restrict__ in, unsigned short* __restrict__ out,
                          int n4) {
    int i = blockIdx.x * 256 + threadIdx.x;
    if (i >= n4) return;
    float4 v = reinterpret_cast<const float4*>(in)[i];
    reinterpret_cast<ushort4*>(out)[i] =
        make_ushort4(f2bf(v.x), f2bf(v.y), f2bf(v.z), f2bf(v.w));
}

// W [K][Nc] fp32 -> WT [Nc][K] bf16
__global__ void transpose_w(const float* __restrict__ W, unsigned short* __restrict__ WT,
                            int K, int Nc) {
    __shared__ float t[32][33];
    int bx = blockIdx.x * 32;   // n
    int by = blockIdx.y * 32;   // k
    int x = threadIdx.x, y = threadIdx.y;
    for (int i = y; i < 32; i += 8)
        t[i][x] = W[(size_t)(by + i) * Nc + bx + x];
    __syncthreads();
    for (int i = y; i < 32; i += 8)
        WT[(size_t)(bx + i) * K + by + x] = f2bf(t[x][i]);
}

// ---------------------------------------------------------------------------
// Ws/Wd fold: BX[16][K] bf16; rows 0..7 = Ws (a_src), 8..15 = Wd (a_dst).
// Ws[h][k] = sum_{c<64} W[k][h*64+c] * as[h][c]. One 64-lane block per k.
// ---------------------------------------------------------------------------
__global__ void make_wsd(const float* __restrict__ W, const float* __restrict__ as_,
                         const float* __restrict__ ad_, unsigned short* __restrict__ BX,
                         int K) {
    int k = blockIdx.x;
    int lane = threadIdx.x & 63;
    int head = lane >> 3;
    int coff = (lane & 7) * 8;               // 8 channels within head
    const float* wr = W + (size_t)k * HC + head * 64 + coff;
    const float* asp = as_ + head * 64 + coff;
    const float* adp = ad_ + head * 64 + coff;
    float ps = 0.f, pd = 0.f;
#pragma unroll
    for (int i = 0; i < 8; ++i) {
        float wv = wr[i];
        ps += wv * asp[i];
        pd += wv * adp[i];
    }
    ps += __shfl_xor(ps, 1); pd += __shfl_xor(pd, 1);
    ps += __shfl_xor(ps, 2); pd += __shfl_xor(pd, 2);
    ps += __shfl_xor(ps, 4); pd += __shfl_xor(pd, 4);
    if ((lane & 7) == 0) {
        BX[(size_t)head * K + k] = f2bf(ps);
        BX[(size_t)(8 + head) * K + k] = f2bf(pd);
    }
}

// ---------------------------------------------------------------------------
// bf16 MFMA GEMM; h stored FP8 e4m3. a_src/a_dst computed BY MFMA via the
// 16-row augmented Bx tile (wc==0 waves of bcol==0 blocks) — no shuffle
// epilogue. LDS XOR-swizzled (T2 both-sides).
// ---------------------------------------------------------------------------
__global__ __launch_bounds__(256) void gemm_attn(const unsigned short* __restrict__ A,
                                                 const unsigned short* __restrict__ BT,
                                                 const unsigned short* __restrict__ BX,
                                                 unsigned char* __restrict__ C,
                                                 float* __restrict__ a_src,
                                                 float* __restrict__ a_dst,
                                                 int M, int K) {
    __shared__ __align__(16) unsigned short As[128 * 64];   // 16 KB
    __shared__ __align__(16) unsigned short Bs[128 * 64];   // 16 KB
    __shared__ __align__(16) unsigned short Bxs[16 * 64];   // 2 KB

    // XCD-chunked bijective swizzle (8 XCDs)
    const int nwg = gridDim.x;
    const int f = blockIdx.x;
    const int q = nwg >> 3, r = nwg & 7;
    const int xcd = f & 7, rank = f >> 3;
    const int swz = (xcd < r ? xcd * (q + 1) : r * (q + 1) + (xcd - r) * q) + rank;
    const int bcol = (swz & 3) * 128;     // Nc=512 -> 4 col-blocks
    const int brow = (swz >> 2) * 128;

    const int tid = threadIdx.x;
    const int lane = tid & 63;
    const int wave = tid >> 6;
    const int wr = wave >> 1, wc = wave & 1;
    const bool do_x = (wc == 0) && (bcol == 0);   // waves 0,2 of col-block 0

    f32x4 acc[4][4];
#pragma unroll
    for (int i = 0; i < 4; ++i)
#pragma unroll
        for (int j = 0; j < 4; ++j) acc[i][j] = (f32x4)0.f;
    f32x4 accx[4];
#pragma unroll
    for (int i = 0; i < 4; ++i) accx[i] = (f32x4)0.f;

    const int lrow = lane >> 3;                     // LDS row & 7
    const int lcolsw = (((lane & 7) ^ lrow)) * 8;   // pre-swizzled k-chunk (source side)
    const int arow0 = brow + wave * 32 + lrow;
    const int brow0 = bcol + wave * 32 + lrow;

    const int kb = (lane >> 4) * 8;
    const int rowa = wr * 64 + (lane & 15);
    const int rowb = wc * 64 + (lane & 15);
    const int rxor = lane & 7;

    for (int k0 = 0; k0 < K; k0 += 64) {
#pragma unroll
        for (int it = 0; it < 4; ++it) {
            const int c = wave * 4 + it;
            int ar = arow0 + it * 8;
            if (ar >= M) ar = M - 1;                // clamp: rows >=M never stored
            gload16(A + (size_t)ar * K + k0 + lcolsw, &As[c * 512]);
            int br = brow0 + it * 8;
            gload16(BT + (size_t)br * K + k0 + lcolsw, &Bs[c * 512]);
        }
        if (bcol == 0 && wave < 2)
            gload16(BX + (size_t)(wave * 8 + lrow) * K + k0 + lcolsw, &Bxs[wave * 512]);
        __syncthreads();
#pragma unroll
        for (int kk = 0; kk < 64; kk += 32) {
            const int chunk = (kk + kb) >> 3;
            const int koff = (chunk ^ rxor) * 8;
            bf16x8 a[4], b[4];
#pragma unroll
            for (int m = 0; m < 4; ++m)
                a[m] = *(const bf16x8*)&As[(rowa + m * 16) * 64 + koff];
#pragma unroll
            for (int nn = 0; nn < 4; ++nn)
                b[nn] = *(const bf16x8*)&Bs[(rowb + nn * 16) * 64 + koff];
#pragma unroll
            for (int m = 0; m < 4; ++m)
#pragma unroll
                for (int nn = 0; nn < 4; ++nn)
                    acc[m][nn] = __builtin_amdgcn_mfma_f32_16x16x32_bf16(
                        a[m], b[nn], acc[m][nn], 0, 0, 0);
            if (do_x) {
                bf16x8 bx = *(const bf16x8*)&Bxs[(lane & 15) * 64 + koff];
#pragma unroll
                for (int m = 0; m < 4; ++m)
                    accx[m] = __builtin_amdgcn_mfma_f32_16x16x32_bf16(
                        a[m], bx, accx[m], 0, 0, 0);
            }
        }
        __syncthreads();
    }

    const int r0 = brow + wr * 64 + (lane >> 4) * 4;
    const int c0 = bcol + wc * 64 + (lane & 15);

    // ---- C store (fp8 h) ----
#pragma unroll
    for (int m = 0; m < 4; ++m)
#pragma unroll
        for (int j = 0; j < 4; ++j) {
            int rr = r0 + m * 16 + j;
            if (rr < M) {
#pragma unroll
                for (int nn = 0; nn < 4; ++nn)
                    C[(size_t)rr * HC + c0 + nn * 16] = f2fp8(acc[m][nn][j]);
            }
        }

    // ---- a_src/a_dst from MFMA accumulators (direct stores, no shuffles) ----
    if (do_x) {
        const int col16 = lane & 15;
        float* dst = (col16 < 8) ? a_src : a_dst;
        const int head = col16 & 7;
#pragma unroll
        for (int m = 0; m < 4; ++m)
#pragma unroll
            for (int j = 0; j < 4; ++j) {
                int rr = r0 + m * 16 + j;
                if (rr < M) dst[rr * 8 + head] = accx[m][j];
            }
    }
}

// ---------------------------------------------------------------------------
// Aggregation. h is FP8 e4m3 [n][512]. Softmax weights fp32.
// ---------------------------------------------------------------------------
template <int MODE>
__global__ __launch_bounds__(256) void agg_kernel(const unsigned char* __restrict__ h,
                                                  const float* __restrict__ a_src,
                                                  const float* __restrict__ a_dst,
                                                  const float* __restrict__ bias,
                                                  const int* __restrict__ row_start,
                                                  const int* __restrict__ src_sorted,
                                                  void* __restrict__ outv, int n) {
    __shared__ float alds[4][MAXD][8];
    __shared__ int   slds[4][MAXD];
    int ws = threadIdx.x >> 6;
    int d = blockIdx.x * 4 + ws;
    int lane = threadIdx.x & 63;
    if (d >= n) return;
    int base = row_start[d];
    int end = row_start[d + 1];
    int deg = end - base;
    int head = lane & 7;
    int eslot = lane >> 3;
    float adh = a_dst[d * 8 + head];

    float mx = -1e30f;
    for (int idx = eslot; idx < deg; idx += 8) {
        int s = src_sorted[base + idx];
        float al = a_src[s * 8 + head] + adh;
        al = (al > 0.f) ? al : NEG_SLOPE * al;
        if (idx < MAXD) {
            alds[ws][idx][head] = al;
            if (head == 0) slds[ws][idx] = s;
        }
        mx = fmaxf(mx, al);
    }
    mx = fmaxf(mx, __shfl_xor(mx, 8));
    mx = fmaxf(mx, __shfl_xor(mx, 16));
    mx = fmaxf(mx, __shfl_xor(mx, 32));

    float sm = 0.f;
    for (int idx = eslot; idx < deg; idx += 8) {
        float e;
        if (idx < MAXD) {
            float al = alds[ws][idx][head];
            e = __expf(al - mx);
            alds[ws][idx][head] = e;
        } else {
            int s = src_sorted[base + idx];
            float al = a_src[s * 8 + head] + adh;
            al = (al > 0.f) ? al : NEG_SLOPE * al;
            e = __expf(al - mx);
        }
        sm += e;
    }
    sm += __shfl_xor(sm, 8);
    sm += __shfl_xor(sm, 16);
    sm += __shfl_xor(sm, 32);
    float inv = 1.0f / (sm + EPS_);

    asm volatile("s_waitcnt lgkmcnt(0)" ::: "memory");
    __builtin_amdgcn_wave_barrier();

    int hd2 = lane >> 3;
    float mx2 = __shfl(mx, hd2);
    float inv2 = __shfl(inv, hd2);
    float adh2 = a_dst[d * 8 + hd2];
    const unsigned char* hl = h + lane * 8;

    float acc[8] = {};
    int mdeg = (deg < MAXD) ? deg : MAXD;
    for (int i = 0; i < mdeg; i += 4) {
        int i0 = i;
        int i1 = (i + 1 < mdeg) ? i + 1 : mdeg - 1;
        int i2 = (i + 2 < mdeg) ? i + 2 : mdeg - 1;
        int i3 = (i + 3 < mdeg) ? i + 3 : mdeg - 1;
        int s0 = slds[ws][i0], s1 = slds[ws][i1];
        int s2 = slds[ws][i2], s3 = slds[ws][i3];
        uint2 h0 = *reinterpret_cast<const uint2*>(hl + (size_t)s0 * HC);
        uint2 h1 = *reinterpret_cast<const uint2*>(hl + (size_t)s1 * HC);
        uint2 h2 = *reinterpret_cast<const uint2*>(hl + (size_t)s2 * HC);
        uint2 h3 = *reinterpret_cast<const uint2*>(hl + (size_t)s3 * HC);
        float w0 = alds[ws][i0][hd2] * inv2;
        float w1 = (i + 1 < mdeg) ? alds[ws][i1][hd2] * inv2 : 0.f;
        float w2 = (i + 2 < mdeg) ? alds[ws][i2][hd2] * inv2 : 0.f;
        float w3 = (i + 3 < mdeg) ? alds[ws][i3][hd2] * inv2 : 0.f;
        ACC_FP8(h0, w0)
        ACC_FP8(h1, w1)
        ACC_FP8(h2, w2)
        ACC_FP8(h3, w3)
    }
    for (int i = base + MAXD; i < end; ++i) {
        int s = src_sorted[i];
        float al = a_src[s * 8 + hd2] + adh2;
        al = (al > 0.f) ? al : NEG_SLOPE * al;
        float w = __expf(al - mx2) * inv2;
        uint2 hv = *reinterpret_cast<const uint2*>(hl + (size_t)s * HC);
        ACC_FP8(hv, w)
    }

    if (MODE == 0) {
        float4 b0 = *reinterpret_cast<const float4*>(bias + lane * 8);
        float4 b1 = *reinterpret_cast<const float4*>(bias + lane * 8 + 4);
        float v[8];
        v[0] = fmaxf(acc[0] + b0.x, 0.f); v[1] = fmaxf(acc[1] + b0.y, 0.f);
        v[2] = fmaxf(acc[2] + b0.z, 0.f); v[3] = fmaxf(acc[3] + b0.w, 0.f);
        v[4] = fmaxf(acc[4] + b1.x, 0.f); v[5] = fmaxf(acc[5] + b1.y, 0.f);
        v[6] = fmaxf(acc[6] + b1.z, 0.f); v[7] = fmaxf(acc[7] + b1.w, 0.f);
        uint4 o;
        o.x = (unsigned)f2bf(v[0]) | ((unsigned)f2bf(v[1]) << 16);
        o.y = (unsigned)f2bf(v[2]) | ((unsigned)f2bf(v[3]) << 16);
        o.z = (unsigned)f2bf(v[4]) | ((unsigned)f2bf(v[5]) << 16);
        o.w = (unsigned)f2bf(v[6]) | ((unsigned)f2bf(v[7]) << 16);
        *reinterpret_cast<uint4*>((unsigned short*)outv + (size_t)d * HC + lane * 8) = o;
    } else {
#pragma unroll
        for (int j = 0; j < 8; ++j) {
            acc[j] += __shfl_xor(acc[j], 8);
            acc[j] += __shfl_xor(acc[j], 16);
            acc[j] += __shfl_xor(acc[j], 32);
        }
        if (lane < 8) {
            float* op = (float*)outv + (size_t)d * 64 + lane * 8;
            float4 o0, o1;
            o0.x = fmaxf(acc[0] * 0.125f + bias[lane * 8 + 0], 0.f);
            o0.y = fmaxf(acc[1] * 0.125f + bias[lane * 8 + 1], 0.f);
            o0.z = fmaxf(acc[2] * 0.125f + bias[lane * 8 + 2], 0.f);
            o0.w = fmaxf(acc[3] * 0.125f + bias[lane * 8 + 3], 0.f);
            o1.x = fmaxf(acc[4] * 0.125f + bias[lane * 8 + 4], 0.f);
            o1.y = fmaxf(acc[5] * 0.125f + bias[lane * 8 + 5], 0.f);
            o1.z = fmaxf(acc[6] * 0.125f + bias[lane * 8 + 6], 0.f);
            o1.w = fmaxf(acc[7] * 0.125f + bias[lane * 8 + 7], 0.f);
            *reinterpret_cast<float4*>(op) = o0;
            *reinterpret_cast<float4*>(op + 4) = o1;
        }
    }
}

// ---------------------------------------------------------------------------
// Pool + classify fused: one block per graph.
// ---------------------------------------------------------------------------
__global__ __launch_bounds__(256) void pool_classify(const float* __restrict__ h3,
                                                     const int* __restrict__ batch,
                                                     const float* __restrict__ fcw,
                                                     const float* __restrict__ fcb,
                                                     float* __restrict__ out, int n) {
    int g = blockIdx.x;
    __shared__ int s_lo, s_hi;
    if (threadIdx.x == 0) {
        int lo = 0, hi = n;
        while (lo < hi) { int mid = (lo + hi) >> 1; if (batch[mid] < g) lo = mid + 1; else hi = mid; }
        s_lo = lo;
        int lo2 = lo, hi2 = n;
        while (lo2 < hi2) { int mid = (lo2 + hi2) >> 1; if (batch[mid] < g + 1) lo2 = mid + 1; else hi2 = mid; }
        s_hi = lo2;
    }
    __syncthreads();
    int lo = s_lo, hi = s_hi;
    int lane = threadIdx.x & 63;
    int slot = threadIdx.x >> 6;
    float acc = 0.f;
    for (int i = lo + slot; i < hi; i += 4)
        acc += h3[(size_t)i * 64 + lane];
    __shared__ float red[4][64];
    red[slot][lane] = acc;
    __syncthreads();
    if (slot == 0) {
        float v = red[0][lane] + red[1][lane] + red[2][lane] + red[3][lane];
        float c = (float)(hi - lo);
        c = fmaxf(c, 1.0f);
        float p = v / c;
        float logit[NCLS];
#pragma unroll
        for (int j = 0; j < NCLS; ++j) {
            float t = p * fcw[lane * NCLS + j];
#pragma unroll
            for (int off = 1; off < 64; off <<= 1) t += __shfl_xor(t, off);
            logit[j] = t + fcb[j];
        }
        float m = logit[0];
#pragma unroll
        for (int j = 1; j < NCLS; ++j) m = fmaxf(m, logit[j]);
        float s = 0.f;
#pragma unroll
        for (int j = 0; j < NCLS; ++j) s += expf(logit[j] - m);
        float lse = logf(s);
        if (lane < NCLS) {
            float vv = logit[0];
#pragma unroll
            for (int j = 1; j < NCLS; ++j)
                if (lane == j) vv = logit[j];
            out[g * NCLS + lane] = vv - m - lse;
        }
    }
}

// ---------------------------------------------------------------------------
extern "C" void kernel_launch(void* const* d_in, const int* in_sizes, int n_in,
                              void* d_out, int out_size, void* d_ws, size_t ws_size,
                              hipStream_t stream) {
    const float* x    = (const float*)d_in[0];
    const int*   ei   = (const int*)d_in[1];
    const int*   batch = (const int*)d_in[2];
    const float* W1  = (const float*)d_in[3];
    const float* a1s = (const float*)d_in[4];
    const float* a1d = (const float*)d_in[5];
    const float* b1  = (const float*)d_in[6];
    const float* W2  = (const float*)d_in[7];
    const float* a2s = (const float*)d_in[8];
    const float* a2d = (const float*)d_in[9];
    const float* b2  = (const float*)d_in[10];
    const float* W3  = (const float*)d_in[11];
    const float* a3s = (const float*)d_in[12];
    const float* a3d = (const float*)d_in[13];
    const float* b3  = (const float*)d_in[14];
    const float* fcw = (const float*)d_in[15];
    const float* fcb = (const float*)d_in[16];

    const int n  = in_sizes[0] / F_IN;     // 50000
    const int E_ = in_sizes[1] / 2;        // 400000
    const int EP = E_ + n;                 // 450000

    // ---- workspace carve-up ----
    char* p = (char*)d_ws;
    unsigned short* xb   = (unsigned short*)p; p += (size_t)n * F_IN * 2;
    unsigned short* w1t  = (unsigned short*)p; p += (size_t)HC * F_IN * 2;
    unsigned short* w2t  = (unsigned short*)p; p += (size_t)HC * HC * 2;
    unsigned short* w3t  = (unsigned short*)p; p += (size_t)HC * HC * 2;
    unsigned short* bx1  = (unsigned short*)p; p += (size_t)16 * F_IN * 2;
    unsigned short* bx2  = (unsigned short*)p; p += (size_t)16 * HC * 2;
    unsigned short* bx3  = (unsigned short*)p; p += (size_t)16 * HC * 2;
    unsigned char*  hbuf = (unsigned char*)p;  p += (size_t)n * HC;       // fp8 h
    unsigned short* buf2 = (unsigned short*)p; p += (size_t)n * HC * 2;   // bf16 layer input
    float* asrc   = (float*)p; p += (size_t)n * 8 * 4;
    float* adst   = (float*)p; p += (size_t)n * 8 * 4;
    float* h3     = (float*)p; p += (size_t)n * 64 * 4;
    int* counts   = (int*)p;   p += (size_t)n * 4;
    int* row_start= (int*)p;   p += (size_t)(n + 1) * 4;
    int* src_sorted=(int*)p;   p += (size_t)EP * 4;
    int* partial  = (int*)p;   p += (size_t)n * 4;
    int* bsum     = (int*)p;   p += 1024 * 4;

    const int edge_blocks = (EP + 255) / 256;
    const int node_blocks = (n + 3) / 4;
    const int scan_blocks = (n + 255) / 256;

    // ---- CSR build ----
    hipMemsetAsync(counts, 0, (size_t)n * sizeof(int), stream);
    hist_kernel<<<edge_blocks, 256, 0, stream>>>(ei, counts, E_, EP);
    scan1<<<scan_blocks, 256, 0, stream>>>(counts, partial, bsum, n);
    scan2<<<1, 1024, 0, stream>>>(bsum, scan_blocks);
    scan3<<<scan_blocks, 256, 0, stream>>>(partial, bsum, row_start, counts, n);
    scatter_kernel<<<edge_blocks, 256, 0, stream>>>(ei, row_start, counts, src_sorted, E_, EP);

    // ---- conversions ----
    conv_bf16<<<((n * F_IN / 4) + 255) / 256, 256, 0, stream>>>(x, xb, n * F_IN / 4);
    transpose_w<<<dim3(HC / 32, F_IN / 32), dim3(32, 8), 0, stream>>>(W1, w1t, F_IN, HC);
    transpose_w<<<dim3(HC / 32, HC / 32), dim3(32, 8), 0, stream>>>(W2, w2t, HC, HC);
    transpose_w<<<dim3(HC / 32, HC / 32), dim3(32, 8), 0, stream>>>(W3, w3t, HC, HC);
    make_wsd<<<F_IN, 64, 0, stream>>>(W1, a1s, a1d, bx1, F_IN);
    make_wsd<<<HC, 64, 0, stream>>>(W2, a2s, a2d, bx2, HC);
    make_wsd<<<HC, 64, 0, stream>>>(W3, a3s, a3d, bx3, HC);

    const int nby = (n + 127) / 128;
    const int nwg = 4 * nby;          // 4 col-blocks x row-blocks, 1-D swizzled grid

    // ---- Layer 1 ----
    gemm_attn<<<nwg, 256, 0, stream>>>(xb, w1t, bx1, hbuf, asrc, adst, n, F_IN);
    agg_kernel<0><<<node_blocks, 256, 0, stream>>>(hbuf, asrc, adst, b1, row_start, src_sorted, buf2, n);

    // ---- Layer 2 ----
    gemm_attn<<<nwg, 256, 0, stream>>>(buf2, w2t, bx2, hbuf, asrc, adst, n, HC);
    agg_kernel<0><<<node_blocks, 256, 0, stream>>>(hbuf, asrc, adst, b2, row_start, src_sorted, buf2, n);

    // ---- Layer 3 ----
    gemm_attn<<<nwg, 256, 0, stream>>>(buf2, w3t, bx3, hbuf, asrc, adst, n, HC);
    agg_kernel<1><<<node_blocks, 256, 0, stream>>>(hbuf, asrc, adst, b3, row_start, src_sorted, h3, n);

    // ---- Pool + classify (fused) ----
    pool_classify<<<GG, 256, 0, stream>>>(h3, batch, fcw, fcb, (float*)d_out, n);
}

// Round 11
// 349.921 us; speedup vs baseline: 5.2670x; 1.1127x over previous
//
#include <hip/hip_runtime.h>
#include <hip/hip_bf16.h>

#define HH 8
#define CC 64
#define HC 512
#define GG 64
#define NCLS 10
#define F_IN 128
#define NEG_SLOPE 0.2f
#define EPS_ 1e-16f
#define MAXD 32

typedef float f32x4 __attribute__((ext_vector_type(4)));
typedef __bf16 bf16x8 __attribute__((ext_vector_type(8)));

__device__ __forceinline__ unsigned short f2bf(float f) {
    unsigned u = __builtin_bit_cast(unsigned, f);
    u += 0x7fffu + ((u >> 16) & 1u);          // RNE
    return (unsigned short)(u >> 16);
}
__device__ __forceinline__ float bflo(unsigned u) {
    return __builtin_bit_cast(float, u << 16);
}
__device__ __forceinline__ float bfhi(unsigned u) {
    return __builtin_bit_cast(float, u & 0xffff0000u);
}
// fp8 e4m3 (OCP on gfx950) helpers — hardware cvt. sel must be ICE -> template.
__device__ __forceinline__ unsigned char f2fp8(float f) {
    unsigned pk = __builtin_amdgcn_cvt_pk_fp8_f32(f, f, 0u, false);
    return (unsigned char)(pk & 0xffu);
}
template <int SEL>
__device__ __forceinline__ float fp82f(unsigned w) {
    return __builtin_amdgcn_cvt_f32_fp8(w, SEL);
}
// dequant 8 fp8 channels (uint2) with weight w into acc[0..7]
#define ACC_FP8(hv, w)                                           \
    acc[0] += (w) * fp82f<0>(hv.x); acc[1] += (w) * fp82f<1>(hv.x); \
    acc[2] += (w) * fp82f<2>(hv.x); acc[3] += (w) * fp82f<3>(hv.x); \
    acc[4] += (w) * fp82f<0>(hv.y); acc[5] += (w) * fp82f<1>(hv.y); \
    acc[6] += (w) * fp82f<2>(hv.y); acc[7] += (w) * fp82f<3>(hv.y);

// async global->LDS, 16B per lane. lds ptr must be wave-uniform base.
__device__ __forceinline__ void gload16(const unsigned short* g, unsigned short* l) {
    __builtin_amdgcn_global_load_lds(
        (const __attribute__((address_space(1))) unsigned int*)g,
        (__attribute__((address_space(3))) unsigned int*)l,
        16, 0, 0);
}

// ---------------------------------------------------------------------------
// CSR build
// ---------------------------------------------------------------------------
__global__ void hist_kernel(const int* __restrict__ ei, int* __restrict__ counts,
                            int E_, int EP_) {
    int e = blockIdx.x * 256 + threadIdx.x;
    if (e >= EP_) return;
    int d = (e < E_) ? ei[E_ + e] : (e - E_);
    atomicAdd(&counts[d], 1);
}

__global__ void scan1(const int* __restrict__ counts, int* __restrict__ partial,
                      int* __restrict__ bsum, int n) {
    __shared__ int buf[256];
    int idx = blockIdx.x * 256 + threadIdx.x;
    int v = (idx < n) ? counts[idx] : 0;
    buf[threadIdx.x] = v;
    __syncthreads();
    for (int off = 1; off < 256; off <<= 1) {
        int t = (threadIdx.x >= off) ? buf[threadIdx.x - off] : 0;
        __syncthreads();
        buf[threadIdx.x] += t;
        __syncthreads();
    }
    if (idx < n) partial[idx] = buf[threadIdx.x];
    if (threadIdx.x == 255) bsum[blockIdx.x] = buf[255];
}

__global__ void scan2(int* __restrict__ bsum, int nb) {
    __shared__ int buf[1024];
    int t = threadIdx.x;
    buf[t] = (t < nb) ? bsum[t] : 0;
    __syncthreads();
    for (int off = 1; off < 1024; off <<= 1) {
        int v = (t >= off) ? buf[t - off] : 0;
        __syncthreads();
        buf[t] += v;
        __syncthreads();
    }
    if (t < nb) bsum[t] = buf[t];
}

// also zeroes counts so scatter can reuse it as a cursor (saves a memset)
__global__ void scan3(const int* __restrict__ partial, const int* __restrict__ bsum,
                      int* __restrict__ row_start, int* __restrict__ counts, int n) {
    int idx = blockIdx.x * 256 + threadIdx.x;
    if (idx >= n) return;
    int add = (blockIdx.x > 0) ? bsum[blockIdx.x - 1] : 0;
    row_start[idx + 1] = partial[idx] + add;
    counts[idx] = 0;
    if (idx == 0) row_start[0] = 0;
}

// writes src_sorted directly (no perm indirection)
__global__ void scatter_kernel(const int* __restrict__ ei, const int* __restrict__ row_start,
                               int* __restrict__ cursor, int* __restrict__ src_sorted,
                               int E_, int EP_) {
    int e = blockIdx.x * 256 + threadIdx.x;
    if (e >= EP_) return;
    int s, d;
    if (e < E_) { s = ei[e]; d = ei[E_ + e]; }
    else        { s = e - E_; d = e - E_; }
    int pos = row_start[d] + atomicAdd(&cursor[d], 1);
    src_sorted[pos] = s;
}

// ---------------------------------------------------------------------------
// fp32 -> bf16 conversions
// ---------------------------------------------------------------------------
__global__ void conv_bf16(const float* __restrict__ in, unsigned short* __restrict__ out,
                          int n4) {
    int i = blockIdx.x * 256 + threadIdx.x;
    if (i >= n4) return;
    float4 v = reinterpret_cast<const float4*>(in)[i];
    reinterpret_cast<ushort4*>(out)[i] =
        make_ushort4(f2bf(v.x), f2bf(v.y), f2bf(v.z), f2bf(v.w));
}

// W [K][Nc] fp32 -> WT [Nc][K] bf16
__global__ void transpose_w(const float* __restrict__ W, unsigned short* __restrict__ WT,
                            int K, int Nc) {
    __shared__ float t[32][33];
    int bx = blockIdx.x * 32;   // n
    int by = blockIdx.y * 32;   // k
    int x = threadIdx.x, y = threadIdx.y;
    for (int i = y; i < 32; i += 8)
        t[i][x] = W[(size_t)(by + i) * Nc + bx + x];
    __syncthreads();
    for (int i = y; i < 32; i += 8)
        WT[(size_t)(bx + i) * K + by + x] = f2bf(t[x][i]);
}

// ---------------------------------------------------------------------------
// Ws/Wd fold: BX[16][K] bf16; rows 0..7 = Ws (a_src), 8..15 = Wd (a_dst).
// ---------------------------------------------------------------------------
__global__ void make_wsd(const float* __restrict__ W, const float* __restrict__ as_,
                         const float* __restrict__ ad_, unsigned short* __restrict__ BX,
                         int K) {
    int k = blockIdx.x;
    int lane = threadIdx.x & 63;
    int head = lane >> 3;
    int coff = (lane & 7) * 8;               // 8 channels within head
    const float* wr = W + (size_t)k * HC + head * 64 + coff;
    const float* asp = as_ + head * 64 + coff;
    const float* adp = ad_ + head * 64 + coff;
    float ps = 0.f, pd = 0.f;
#pragma unroll
    for (int i = 0; i < 8; ++i) {
        float wv = wr[i];
        ps += wv * asp[i];
        pd += wv * adp[i];
    }
    ps += __shfl_xor(ps, 1); pd += __shfl_xor(pd, 1);
    ps += __shfl_xor(ps, 2); pd += __shfl_xor(pd, 2);
    ps += __shfl_xor(ps, 4); pd += __shfl_xor(pd, 4);
    if ((lane & 7) == 0) {
        BX[(size_t)head * K + k] = f2bf(ps);
        BX[(size_t)(8 + head) * K + k] = f2bf(pd);
    }
}

// ---------------------------------------------------------------------------
// bf16 MFMA GEMM; h stored FP8 e4m3. a_src/a_dst computed BY MFMA via the
// 16-row augmented Bx tile. LDS XOR-swizzled (T2 both-sides).
// ---------------------------------------------------------------------------
__global__ __launch_bounds__(256) void gemm_attn(const unsigned short* __restrict__ A,
                                                 const unsigned short* __restrict__ BT,
                                                 const unsigned short* __restrict__ BX,
                                                 unsigned char* __restrict__ C,
                                                 float* __restrict__ a_src,
                                                 float* __restrict__ a_dst,
                                                 int M, int K) {
    __shared__ __align__(16) unsigned short As[128 * 64];   // 16 KB
    __shared__ __align__(16) unsigned short Bs[128 * 64];   // 16 KB
    __shared__ __align__(16) unsigned short Bxs[16 * 64];   // 2 KB

    // XCD-chunked bijective swizzle (8 XCDs)
    const int nwg = gridDim.x;
    const int f = blockIdx.x;
    const int q = nwg >> 3, r = nwg & 7;
    const int xcd = f & 7, rank = f >> 3;
    const int swz = (xcd < r ? xcd * (q + 1) : r * (q + 1) + (xcd - r) * q) + rank;
    const int bcol = (swz & 3) * 128;     // Nc=512 -> 4 col-blocks
    const int brow = (swz >> 2) * 128;

    const int tid = threadIdx.x;
    const int lane = tid & 63;
    const int wave = tid >> 6;
    const int wr = wave >> 1, wc = wave & 1;
    const bool do_x = (wc == 0) && (bcol == 0);   // waves 0,2 of col-block 0

    f32x4 acc[4][4];
#pragma unroll
    for (int i = 0; i < 4; ++i)
#pragma unroll
        for (int j = 0; j < 4; ++j) acc[i][j] = (f32x4)0.f;
    f32x4 accx[4];
#pragma unroll
    for (int i = 0; i < 4; ++i) accx[i] = (f32x4)0.f;

    const int lrow = lane >> 3;                     // LDS row & 7
    const int lcolsw = (((lane & 7) ^ lrow)) * 8;   // pre-swizzled k-chunk (source side)
    const int arow0 = brow + wave * 32 + lrow;
    const int brow0 = bcol + wave * 32 + lrow;

    const int kb = (lane >> 4) * 8;
    const int rowa = wr * 64 + (lane & 15);
    const int rowb = wc * 64 + (lane & 15);
    const int rxor = lane & 7;

    for (int k0 = 0; k0 < K; k0 += 64) {
#pragma unroll
        for (int it = 0; it < 4; ++it) {
            const int c = wave * 4 + it;
            int ar = arow0 + it * 8;
            if (ar >= M) ar = M - 1;                // clamp: rows >=M never stored
            gload16(A + (size_t)ar * K + k0 + lcolsw, &As[c * 512]);
            int br = brow0 + it * 8;
            gload16(BT + (size_t)br * K + k0 + lcolsw, &Bs[c * 512]);
        }
        if (bcol == 0 && wave < 2)
            gload16(BX + (size_t)(wave * 8 + lrow) * K + k0 + lcolsw, &Bxs[wave * 512]);
        __syncthreads();
#pragma unroll
        for (int kk = 0; kk < 64; kk += 32) {
            const int chunk = (kk + kb) >> 3;
            const int koff = (chunk ^ rxor) * 8;
            bf16x8 a[4], b[4];
#pragma unroll
            for (int m = 0; m < 4; ++m)
                a[m] = *(const bf16x8*)&As[(rowa + m * 16) * 64 + koff];
#pragma unroll
            for (int nn = 0; nn < 4; ++nn)
                b[nn] = *(const bf16x8*)&Bs[(rowb + nn * 16) * 64 + koff];
#pragma unroll
            for (int m = 0; m < 4; ++m)
#pragma unroll
                for (int nn = 0; nn < 4; ++nn)
                    acc[m][nn] = __builtin_amdgcn_mfma_f32_16x16x32_bf16(
                        a[m], b[nn], acc[m][nn], 0, 0, 0);
            if (do_x) {
                bf16x8 bx = *(const bf16x8*)&Bxs[(lane & 15) * 64 + koff];
#pragma unroll
                for (int m = 0; m < 4; ++m)
                    accx[m] = __builtin_amdgcn_mfma_f32_16x16x32_bf16(
                        a[m], bx, accx[m], 0, 0, 0);
            }
        }
        __syncthreads();
    }

    const int r0 = brow + wr * 64 + (lane >> 4) * 4;
    const int c0 = bcol + wc * 64 + (lane & 15);

    // ---- C store (fp8 h) ----
#pragma unroll
    for (int m = 0; m < 4; ++m)
#pragma unroll
        for (int j = 0; j < 4; ++j) {
            int rr = r0 + m * 16 + j;
            if (rr < M) {
#pragma unroll
                for (int nn = 0; nn < 4; ++nn)
                    C[(size_t)rr * HC + c0 + nn * 16] = f2fp8(acc[m][nn][j]);
            }
        }

    // ---- a_src/a_dst from MFMA accumulators (direct stores, no shuffles) ----
    if (do_x) {
        const int col16 = lane & 15;
        float* dst = (col16 < 8) ? a_src : a_dst;
        const int head = col16 & 7;
#pragma unroll
        for (int m = 0; m < 4; ++m)
#pragma unroll
            for (int j = 0; j < 4; ++j) {
                int rr = r0 + m * 16 + j;
                if (rr < M) dst[rr * 8 + head] = accx[m][j];
            }
    }
}

// ---------------------------------------------------------------------------
// Aggregation. h is FP8 e4m3 [n][512]. Softmax weights fp32.
// ---------------------------------------------------------------------------
template <int MODE>
__global__ __launch_bounds__(256) void agg_kernel(const unsigned char* __restrict__ h,
                                                  const float* __restrict__ a_src,
                                                  const float* __restrict__ a_dst,
                                                  const float* __restrict__ bias,
                                                  const int* __restrict__ row_start,
                                                  const int* __restrict__ src_sorted,
                                                  void* __restrict__ outv, int n) {
    __shared__ float alds[4][MAXD][8];
    __shared__ int   slds[4][MAXD];
    int ws = threadIdx.x >> 6;
    int d = blockIdx.x * 4 + ws;
    int lane = threadIdx.x & 63;
    if (d >= n) return;
    int base = row_start[d];
    int end = row_start[d + 1];
    int deg = end - base;
    int head = lane & 7;
    int eslot = lane >> 3;
    float adh = a_dst[d * 8 + head];

    float mx = -1e30f;
    for (int idx = eslot; idx < deg; idx += 8) {
        int s = src_sorted[base + idx];
        float al = a_src[s * 8 + head] + adh;
        al = (al > 0.f) ? al : NEG_SLOPE * al;
        if (idx < MAXD) {
            alds[ws][idx][head] = al;
            if (head == 0) slds[ws][idx] = s;
        }
        mx = fmaxf(mx, al);
    }
    mx = fmaxf(mx, __shfl_xor(mx, 8));
    mx = fmaxf(mx, __shfl_xor(mx, 16));
    mx = fmaxf(mx, __shfl_xor(mx, 32));

    float sm = 0.f;
    for (int idx = eslot; idx < deg; idx += 8) {
        float e;
        if (idx < MAXD) {
            float al = alds[ws][idx][head];
            e = __expf(al - mx);
            alds[ws][idx][head] = e;
        } else {
            int s = src_sorted[base + idx];
            float al = a_src[s * 8 + head] + adh;
            al = (al > 0.f) ? al : NEG_SLOPE * al;
            e = __expf(al - mx);
        }
        sm += e;
    }
    sm += __shfl_xor(sm, 8);
    sm += __shfl_xor(sm, 16);
    sm += __shfl_xor(sm, 32);
    float inv = 1.0f / (sm + EPS_);

    asm volatile("s_waitcnt lgkmcnt(0)" ::: "memory");
    __builtin_amdgcn_wave_barrier();

    int hd2 = lane >> 3;
    float mx2 = __shfl(mx, hd2);
    float inv2 = __shfl(inv, hd2);
    float adh2 = a_dst[d * 8 + hd2];
    const unsigned char* hl = h + lane * 8;

    float acc[8] = {};
    int mdeg = (deg < MAXD) ? deg : MAXD;
    for (int i = 0; i < mdeg; i += 4) {
        int i0 = i;
        int i1 = (i + 1 < mdeg) ? i + 1 : mdeg - 1;
        int i2 = (i + 2 < mdeg) ? i + 2 : mdeg - 1;
        int i3 = (i + 3 < mdeg) ? i + 3 : mdeg - 1;
        int s0 = slds[ws][i0], s1 = slds[ws][i1];
        int s2 = slds[ws][i2], s3 = slds[ws][i3];
        uint2 h0 = *reinterpret_cast<const uint2*>(hl + (size_t)s0 * HC);
        uint2 h1 = *reinterpret_cast<const uint2*>(hl + (size_t)s1 * HC);
        uint2 h2 = *reinterpret_cast<const uint2*>(hl + (size_t)s2 * HC);
        uint2 h3 = *reinterpret_cast<const uint2*>(hl + (size_t)s3 * HC);
        float w0 = alds[ws][i0][hd2] * inv2;
        float w1 = (i + 1 < mdeg) ? alds[ws][i1][hd2] * inv2 : 0.f;
        float w2 = (i + 2 < mdeg) ? alds[ws][i2][hd2] * inv2 : 0.f;
        float w3 = (i + 3 < mdeg) ? alds[ws][i3][hd2] * inv2 : 0.f;
        ACC_FP8(h0, w0)
        ACC_FP8(h1, w1)
        ACC_FP8(h2, w2)
        ACC_FP8(h3, w3)
    }
    for (int i = base + MAXD; i < end; ++i) {
        int s = src_sorted[i];
        float al = a_src[s * 8 + hd2] + adh2;
        al = (al > 0.f) ? al : NEG_SLOPE * al;
        float w = __expf(al - mx2) * inv2;
        uint2 hv = *reinterpret_cast<const uint2*>(hl + (size_t)s * HC);
        ACC_FP8(hv, w)
    }

    if (MODE == 0) {
        float4 b0 = *reinterpret_cast<const float4*>(bias + lane * 8);
        float4 b1 = *reinterpret_cast<const float4*>(bias + lane * 8 + 4);
        float v[8];
        v[0] = fmaxf(acc[0] + b0.x, 0.f); v[1] = fmaxf(acc[1] + b0.y, 0.f);
        v[2] = fmaxf(acc[2] + b0.z, 0.f); v[3] = fmaxf(acc[3] + b0.w, 0.f);
        v[4] = fmaxf(acc[4] + b1.x, 0.f); v[5] = fmaxf(acc[5] + b1.y, 0.f);
        v[6] = fmaxf(acc[6] + b1.z, 0.f); v[7] = fmaxf(acc[7] + b1.w, 0.f);
        uint4 o;
        o.x = (unsigned)f2bf(v[0]) | ((unsigned)f2bf(v[1]) << 16);
        o.y = (unsigned)f2bf(v[2]) | ((unsigned)f2bf(v[3]) << 16);
        o.z = (unsigned)f2bf(v[4]) | ((unsigned)f2bf(v[5]) << 16);
        o.w = (unsigned)f2bf(v[6]) | ((unsigned)f2bf(v[7]) << 16);
        *reinterpret_cast<uint4*>((unsigned short*)outv + (size_t)d * HC + lane * 8) = o;
    } else {
#pragma unroll
        for (int j = 0; j < 8; ++j) {
            acc[j] += __shfl_xor(acc[j], 8);
            acc[j] += __shfl_xor(acc[j], 16);
            acc[j] += __shfl_xor(acc[j], 32);
        }
        if (lane < 8) {
            float* op = (float*)outv + (size_t)d * 64 + lane * 8;
            float4 o0, o1;
            o0.x = fmaxf(acc[0] * 0.125f + bias[lane * 8 + 0], 0.f);
            o0.y = fmaxf(acc[1] * 0.125f + bias[lane * 8 + 1], 0.f);
            o0.z = fmaxf(acc[2] * 0.125f + bias[lane * 8 + 2], 0.f);
            o0.w = fmaxf(acc[3] * 0.125f + bias[lane * 8 + 3], 0.f);
            o1.x = fmaxf(acc[4] * 0.125f + bias[lane * 8 + 4], 0.f);
            o1.y = fmaxf(acc[5] * 0.125f + bias[lane * 8 + 5], 0.f);
            o1.z = fmaxf(acc[6] * 0.125f + bias[lane * 8 + 6], 0.f);
            o1.w = fmaxf(acc[7] * 0.125f + bias[lane * 8 + 7], 0.f);
            *reinterpret_cast<float4*>(op) = o0;
            *reinterpret_cast<float4*>(op + 4) = o1;
        }
    }
}

// ---------------------------------------------------------------------------
// Pool stage 1: 8 blocks per graph; each sums a slice, one atomicAdd per lane.
// ---------------------------------------------------------------------------
__global__ __launch_bounds__(256) void pool_partial(const float* __restrict__ h3,
                                                    const int* __restrict__ batch,
                                                    float* __restrict__ pooled,
                                                    int* __restrict__ cnt, int n) {
    int g = blockIdx.x >> 3;
    int part = blockIdx.x & 7;
    __shared__ int s_lo, s_hi;
    if (threadIdx.x == 0) {
        int lo = 0, hi = n;
        while (lo < hi) { int mid = (lo + hi) >> 1; if (batch[mid] < g) lo = mid + 1; else hi = mid; }
        s_lo = lo;
        int lo2 = lo, hi2 = n;
        while (lo2 < hi2) { int mid = (lo2 + hi2) >> 1; if (batch[mid] < g + 1) lo2 = mid + 1; else hi2 = mid; }
        s_hi = lo2;
    }
    __syncthreads();
    int lo = s_lo, hi = s_hi;
    int len = hi - lo;
    if (part == 0 && threadIdx.x == 0) cnt[g] = len;
    int start = lo + (part * len) / 8;
    int stop  = lo + ((part + 1) * len) / 8;
    int lane = threadIdx.x & 63;
    int slot = threadIdx.x >> 6;
    float acc = 0.f;
    for (int i = start + slot; i < stop; i += 4)
        acc += h3[(size_t)i * 64 + lane];
    __shared__ float red[4][64];
    red[slot][lane] = acc;
    __syncthreads();
    if (slot == 0) {
        float v = red[0][lane] + red[1][lane] + red[2][lane] + red[3][lane];
        atomicAdd(&pooled[g * 64 + lane], v);
    }
}

__global__ void classify_kernel(const float* __restrict__ pooled,
                                const int* __restrict__ cnt,
                                const float* __restrict__ fcw,
                                const float* __restrict__ fcb,
                                float* __restrict__ out) {
    int g = blockIdx.x;
    int lane = threadIdx.x & 63;
    float c = (float)cnt[g];
    c = fmaxf(c, 1.0f);
    float p = pooled[g * 64 + lane] / c;
    float logit[NCLS];
#pragma unroll
    for (int j = 0; j < NCLS; ++j) {
        float t = p * fcw[lane * NCLS + j];
#pragma unroll
        for (int off = 1; off < 64; off <<= 1) t += __shfl_xor(t, off);
        logit[j] = t + fcb[j];
    }
    float m = logit[0];
#pragma unroll
    for (int j = 1; j < NCLS; ++j) m = fmaxf(m, logit[j]);
    float s = 0.f;
#pragma unroll
    for (int j = 0; j < NCLS; ++j) s += expf(logit[j] - m);
    float lse = logf(s);
    if (lane < NCLS) {
        float v = logit[0];
#pragma unroll
        for (int j = 1; j < NCLS; ++j)
            if (lane == j) v = logit[j];
        out[g * NCLS + lane] = v - m - lse;
    }
}

// ---------------------------------------------------------------------------
extern "C" void kernel_launch(void* const* d_in, const int* in_sizes, int n_in,
                              void* d_out, int out_size, void* d_ws, size_t ws_size,
                              hipStream_t stream) {
    const float* x    = (const float*)d_in[0];
    const int*   ei   = (const int*)d_in[1];
    const int*   batch = (const int*)d_in[2];
    const float* W1  = (const float*)d_in[3];
    const float* a1s = (const float*)d_in[4];
    const float* a1d = (const float*)d_in[5];
    const float* b1  = (const float*)d_in[6];
    const float* W2  = (const float*)d_in[7];
    const float* a2s = (const float*)d_in[8];
    const float* a2d = (const float*)d_in[9];
    const float* b2  = (const float*)d_in[10];
    const float* W3  = (const float*)d_in[11];
    const float* a3s = (const float*)d_in[12];
    const float* a3d = (const float*)d_in[13];
    const float* b3  = (const float*)d_in[14];
    const float* fcw = (const float*)d_in[15];
    const float* fcb = (const float*)d_in[16];

    const int n  = in_sizes[0] / F_IN;     // 50000
    const int E_ = in_sizes[1] / 2;        // 400000
    const int EP = E_ + n;                 // 450000

    // ---- workspace carve-up ----
    char* p = (char*)d_ws;
    unsigned short* xb   = (unsigned short*)p; p += (size_t)n * F_IN * 2;
    unsigned short* w1t  = (unsigned short*)p; p += (size_t)HC * F_IN * 2;
    unsigned short* w2t  = (unsigned short*)p; p += (size_t)HC * HC * 2;
    unsigned short* w3t  = (unsigned short*)p; p += (size_t)HC * HC * 2;
    unsigned short* bx1  = (unsigned short*)p; p += (size_t)16 * F_IN * 2;
    unsigned short* bx2  = (unsigned short*)p; p += (size_t)16 * HC * 2;
    unsigned short* bx3  = (unsigned short*)p; p += (size_t)16 * HC * 2;
    unsigned char*  hbuf = (unsigned char*)p;  p += (size_t)n * HC;       // fp8 h
    unsigned short* buf2 = (unsigned short*)p; p += (size_t)n * HC * 2;   // bf16 layer input
    float* asrc   = (float*)p; p += (size_t)n * 8 * 4;
    float* adst   = (float*)p; p += (size_t)n * 8 * 4;
    float* h3     = (float*)p; p += (size_t)n * 64 * 4;
    float* pooled = (float*)p; p += (size_t)GG * 64 * 4;
    int* cnt      = (int*)p;   p += (size_t)GG * 4;
    int* counts   = (int*)p;   p += (size_t)n * 4;
    int* row_start= (int*)p;   p += (size_t)(n + 1) * 4;
    int* src_sorted=(int*)p;   p += (size_t)EP * 4;
    int* partial  = (int*)p;   p += (size_t)n * 4;
    int* bsum     = (int*)p;   p += 1024 * 4;

    const int edge_blocks = (EP + 255) / 256;
    const int node_blocks = (n + 3) / 4;
    const int scan_blocks = (n + 255) / 256;

    // ---- CSR build ----
    hipMemsetAsync(counts, 0, (size_t)n * sizeof(int), stream);
    hist_kernel<<<edge_blocks, 256, 0, stream>>>(ei, counts, E_, EP);
    scan1<<<scan_blocks, 256, 0, stream>>>(counts, partial, bsum, n);
    scan2<<<1, 1024, 0, stream>>>(bsum, scan_blocks);
    scan3<<<scan_blocks, 256, 0, stream>>>(partial, bsum, row_start, counts, n);
    scatter_kernel<<<edge_blocks, 256, 0, stream>>>(ei, row_start, counts, src_sorted, E_, EP);

    // ---- conversions ----
    conv_bf16<<<((n * F_IN / 4) + 255) / 256, 256, 0, stream>>>(x, xb, n * F_IN / 4);
    transpose_w<<<dim3(HC / 32, F_IN / 32), dim3(32, 8), 0, stream>>>(W1, w1t, F_IN, HC);
    transpose_w<<<dim3(HC / 32, HC / 32), dim3(32, 8), 0, stream>>>(W2, w2t, HC, HC);
    transpose_w<<<dim3(HC / 32, HC / 32), dim3(32, 8), 0, stream>>>(W3, w3t, HC, HC);
    make_wsd<<<F_IN, 64, 0, stream>>>(W1, a1s, a1d, bx1, F_IN);
    make_wsd<<<HC, 64, 0, stream>>>(W2, a2s, a2d, bx2, HC);
    make_wsd<<<HC, 64, 0, stream>>>(W3, a3s, a3d, bx3, HC);

    const int nby = (n + 127) / 128;
    const int nwg = 4 * nby;          // 4 col-blocks x row-blocks, 1-D swizzled grid

    // ---- Layer 1 ----
    gemm_attn<<<nwg, 256, 0, stream>>>(xb, w1t, bx1, hbuf, asrc, adst, n, F_IN);
    agg_kernel<0><<<node_blocks, 256, 0, stream>>>(hbuf, asrc, adst, b1, row_start, src_sorted, buf2, n);

    // ---- Layer 2 ----
    gemm_attn<<<nwg, 256, 0, stream>>>(buf2, w2t, bx2, hbuf, asrc, adst, n, HC);
    agg_kernel<0><<<node_blocks, 256, 0, stream>>>(hbuf, asrc, adst, b2, row_start, src_sorted, buf2, n);

    // ---- Layer 3 ----
    gemm_attn<<<nwg, 256, 0, stream>>>(buf2, w3t, bx3, hbuf, asrc, adst, n, HC);
    agg_kernel<1><<<node_blocks, 256, 0, stream>>>(hbuf, asrc, adst, b3, row_start, src_sorted, h3, n);

    // ---- Pool (parallel, 8 blocks/graph) + classify ----
    hipMemsetAsync(pooled, 0, (size_t)(GG * 64) * sizeof(float), stream);
    pool_partial<<<GG * 8, 256, 0, stream>>>(h3, batch, pooled, cnt, n);
    classify_kernel<<<GG, 64, 0, stream>>>(pooled, cnt, fcw, fcb, (float*)d_out);
}